// Round 16
// baseline (399.765 us; speedup 1.0000x reference)
//
#include <hip/hip_runtime.h>
#include <hip/hip_bf16.h>
#include <math.h>

#define BT 16384
#define DDIM 1024
#define NEXP 16
#define HDIM 2048
#define CAP 1280
#define APITCH 72
#define LBP 262  // bf16 LDS slab pitch (4-way max conflicts on gather)

typedef __bf16 bf16x8 __attribute__((ext_vector_type(8)));
typedef float f32x4 __attribute__((ext_vector_type(4)));

__device__ __forceinline__ unsigned short f2bf(float f) {
  unsigned u = __float_as_uint(f);
  u += 0x7FFFu + ((u >> 16) & 1u);
  return (unsigned short)(u >> 16);
}

// HW packed fp32->bf16 (RNE, identical to f2bf): dst.lo=cvt(a), dst.hi=cvt(b)
__device__ __forceinline__ unsigned cvt_pk_bf16(float a, float b) {
  unsigned r;
  asm("v_cvt_pk_bf16_f32 %0, %1, %2" : "=v"(r) : "v"(a), "v"(b));
  return r;
}

// gelu(tanh approx) == v * sigmoid(2z); hardware v_exp_f32 path.
__device__ __forceinline__ float fast_gelu(float v) {
  float z = 0.7978845608028654f * (v + 0.044715f * v * v * v);
  return v / (1.0f + __expf(-2.0f * z));
}

#define GLD16(g, l)                                                        \
  __builtin_amdgcn_global_load_lds(                                        \
      (const __attribute__((address_space(1))) unsigned int*)(g),          \
      (__attribute__((address_space(3))) unsigned int*)(l), 16, 0, 0)

// Raw barrier without the vmcnt(0) drain __syncthreads would emit.
#define RAW_BARRIER()                          \
  {                                            \
    __builtin_amdgcn_sched_barrier(0);         \
    __builtin_amdgcn_s_barrier();              \
    __builtin_amdgcn_sched_barrier(0);         \
  }

__global__ void zero_meta_kernel(int* p) {
  int i = threadIdx.x;
  if (i < 32) p[i] = 0;  // counts[16] + m_sel[16]
}

// ======== fused prep ========================================================
// blocks [0,256): gate (streamed Wg chunks).
// blocks [256,..): slab transpose 64 rows x 256 cols per block:
//   phase 1: per-row 1KB CONTIGUOUS reads (wave-wide float4), cvt->bf16 LDS
//   phase 2: write 4 tiles of the 64x64 tiled layout, each as 2x4KB
//            contiguous bursts. (R14/R15 lesson: 128-256B scattered HBM
//            bursts run at ~1TB/s/stream; this widens BOTH streams.)
// Tiled weight layout (consumed by FFNs, identical to R15):
//   w1t: tile (i_h,i_d) at (n*512 + i_h*16 + i_d)*8192 bytes, [h'][k] inside
//   w2t: tile (i_d,i_h) at (n*512 + i_d*32 + i_h)*8192 bytes, [d'][k] inside
__global__ __launch_bounds__(256) void prep_kernel(
    const float* __restrict__ x, const float* __restrict__ Wg,
    int* __restrict__ e, float* __restrict__ v, int* __restrict__ counts,
    unsigned short* __restrict__ xb, int* __restrict__ flags,
    const float* __restrict__ W1, const float* __restrict__ W2,
    unsigned short* __restrict__ w1t, unsigned short* __restrict__ w2t) {
  __shared__ __align__(16) char smem[64 * LBP * 2];  // 33536B
  int bid = blockIdx.x;
  int tid = threadIdx.x;
  if (bid < 256) {
    // ---------------- gate: 64 tokens/block ----------------
    float* xt = (float*)smem;                       // [64][68]  17408B
    double* lg = (double*)(smem + 17408);           // [64][16]   8192B
    float* wgt_c = (float*)(smem + 25600);          // [16][68]   4352B
    int* hcnt = (int*)(smem + 29952);               // [16]
    int t0 = bid * 64;
    if (tid < NEXP) hcnt[tid] = 0;
    if (tid < 64) flags[t0 + tid] = 0;
    int t = tid & 63, g = tid >> 6;
    double acc[4] = {0.0, 0.0, 0.0, 0.0};
    int sr = tid >> 4;
    int sc = (tid & 15) * 4;
    int wd = tid >> 2, wn = (tid & 3) * 4;
    for (int ch = 0; ch < 16; ++ch) {
      __syncthreads();
#pragma unroll
      for (int i = 0; i < 4; ++i) {
        int r = sr + i * 16;
        float4 xv = *(const float4*)(x + (size_t)(t0 + r) * DDIM + ch * 64 + sc);
        xt[r * 68 + sc + 0] = xv.x; xt[r * 68 + sc + 1] = xv.y;
        xt[r * 68 + sc + 2] = xv.z; xt[r * 68 + sc + 3] = xv.w;
        unsigned p0 = cvt_pk_bf16(xv.x, xv.y);
        unsigned p1 = cvt_pk_bf16(xv.z, xv.w);
        *(uint2*)(xb + (size_t)(t0 + r) * DDIM + ch * 64 + sc) = make_uint2(p0, p1);
      }
      {
        float4 w = *(const float4*)(Wg + ch * 1024 + tid * 4);
        wgt_c[(wn + 0) * 68 + wd] = w.x;
        wgt_c[(wn + 1) * 68 + wd] = w.y;
        wgt_c[(wn + 2) * 68 + wd] = w.z;
        wgt_c[(wn + 3) * 68 + wd] = w.w;
      }
      __syncthreads();
#pragma unroll
      for (int d4 = 0; d4 < 16; ++d4) {
        float4 xv = *(const float4*)(&xt[t * 68 + d4 * 4]);
#pragma unroll
        for (int j = 0; j < 4; ++j) {
          float4 wv = *(const float4*)(&wgt_c[(4 * g + j) * 68 + d4 * 4]);
          acc[j] += (double)xv.x * (double)wv.x + (double)xv.y * (double)wv.y +
                    (double)xv.z * (double)wv.z + (double)xv.w * (double)wv.w;
        }
      }
    }
#pragma unroll
    for (int j = 0; j < 4; ++j) lg[t * 16 + 4 * g + j] = acc[j];
    __syncthreads();
    if (tid < 64) {
      double mx = lg[tid * 16]; int bi = 0;
#pragma unroll
      for (int n = 1; n < NEXP; ++n)
        if (lg[tid * 16 + n] > mx) { mx = lg[tid * 16 + n]; bi = n; }
      double s = 0.0;
#pragma unroll
      for (int n = 0; n < NEXP; ++n) s += exp(lg[tid * 16 + n] - mx);
      e[t0 + tid] = bi;
      v[t0 + tid] = (float)(1.0 / s);
      atomicAdd(&hcnt[bi], 1);
    }
    __syncthreads();
    if (tid < NEXP && hcnt[tid] > 0) atomicAdd(&counts[tid], hcnt[tid]);
    return;
  }
  // ---------------- slab transpose + cvt ----------------
  unsigned short* Lb = (unsigned short*)smem;  // [64][LBP] bf16
  int b = bid - 256;
  const float* in;
  unsigned short* outp;
  int C, n, by, bxq, tmul;
  if (b < 2048) {  // W1: 16 d-tiles x 8 col-quads per expert
    in = W1; outp = w1t; C = HDIM; tmul = 16;
    n = b >> 7; int rem = b & 127; by = rem >> 3; bxq = rem & 7;
  } else {         // W2: 32 h-tiles x 4 col-quads per expert
    b -= 2048;
    in = W2; outp = w2t; C = DDIM; tmul = 32;
    n = b >> 7; int rem = b & 127; by = rem >> 2; bxq = rem & 3;
  }
  const float* src = in + (size_t)n * DDIM * HDIM + (size_t)by * 64 * C + bxq * 256;
  int w = tid >> 6, lane = tid & 63;
  // phase 1: rows w+4k, 1KB contiguous per wave-instruction
#pragma unroll
  for (int k = 0; k < 16; ++k) {
    int row = w + k * 4;
    float4 vv = *(const float4*)(src + (size_t)row * C + lane * 4);
    unsigned p0 = cvt_pk_bf16(vv.x, vv.y);
    unsigned p1 = cvt_pk_bf16(vv.z, vv.w);
    *(uint2*)(&Lb[row * LBP + lane * 4]) = make_uint2(p0, p1);
  }
  __syncthreads();
  // phase 2: 4 tiles, each 8KB contiguous (2 x 4KB bursts)
  int oc_lo = tid >> 3;        // 0..31
  int rb = (tid & 7) * 8;      // 0..56
#pragma unroll
  for (int p2 = 0; p2 < 4; ++p2) {
    int bx = bxq * 4 + p2;
    char* dstT = (char*)outp + ((size_t)n * 512 + (size_t)bx * tmul + by) * 8192;
#pragma unroll
    for (int p = 0; p < 2; ++p) {
      int oc = p * 32 + oc_lo;
      const unsigned short* col = &Lb[rb * LBP + p2 * 64 + oc];
      unsigned short u[8];
#pragma unroll
      for (int j = 0; j < 8; ++j) u[j] = col[j * LBP];
      uint4 pk;
      pk.x = (unsigned)u[0] | ((unsigned)u[1] << 16);
      pk.y = (unsigned)u[2] | ((unsigned)u[3] << 16);
      pk.z = (unsigned)u[4] | ((unsigned)u[5] << 16);
      pk.w = (unsigned)u[6] | ((unsigned)u[7] << 16);
      *(uint4*)(dstT + p * 4096 + tid * 16) = pk;
    }
  }
}

// ---------------- select: per-expert token set under capacity ---------------
__global__ void select_kernel(const int* __restrict__ e, const float* __restrict__ v,
                              const int* __restrict__ counts, int* __restrict__ m_sel,
                              int* __restrict__ lists, int* __restrict__ flags) {
  int n = blockIdx.x;
  int tid = threadIdx.x;
  int cnt = counts[n];
  __shared__ int pos;
  if (tid == 0) pos = 0;
  __syncthreads();
  if (cnt <= CAP) {
    for (int t = tid; t < BT; t += 256) {
      if (e[t] == n) {
        int p = atomicAdd(&pos, 1);
        lists[n * CAP + p] = t;
        flags[t] = 1;
      }
    }
    __syncthreads();
    if (tid == 0) m_sel[n] = pos;
  } else {
    __shared__ int scnt;
    unsigned lo = 0u, hi = 0x7F800000u;
    while (hi - lo > 1u) {
      unsigned mid = lo + ((hi - lo) >> 1);
      if (tid == 0) scnt = 0;
      __syncthreads();
      int c = 0;
      for (int t = tid; t < BT; t += 256)
        if (e[t] == n && __float_as_uint(v[t]) >= mid) c++;
      atomicAdd(&scnt, c);
      __syncthreads();
      int tot = scnt;
      __syncthreads();
      if (tot >= CAP) lo = mid; else hi = mid;
    }
    for (int t = tid; t < BT; t += 256) {
      if (e[t] == n && __float_as_uint(v[t]) > lo) {
        int p = atomicAdd(&pos, 1);
        lists[n * CAP + p] = t;
        flags[t] = 1;
      }
    }
    __syncthreads();
    if (tid == 0) {
      int p = pos;
      for (int t = 0; t < BT && p < CAP; ++t) {
        if (e[t] == n && __float_as_uint(v[t]) == lo) {
          lists[n * CAP + p] = t; flags[t] = 1; ++p;
        }
      }
      m_sel[n] = p;
    }
  }
}

// ---------------- gate (slow path only, resident Wg table) ------------------
__global__ __launch_bounds__(256) void gate_kernel(
    const float* __restrict__ x, const float* __restrict__ Wg,
    int* __restrict__ e, float* __restrict__ v, int* __restrict__ counts,
    unsigned short* __restrict__ xb, int* __restrict__ flags) {
  __shared__ float wgt[NEXP][DDIM];
  __shared__ float xt[64][68];
  __shared__ double lg[64][NEXP];
  __shared__ int hcnt[NEXP];
  int tid = threadIdx.x;
  int t0 = blockIdx.x * 64;
  if (tid < NEXP) hcnt[tid] = 0;
  if (tid < 64) flags[t0 + tid] = 0;
  for (int i = tid; i < DDIM * NEXP / 4; i += 256) {
    int idx = i * 4;
    int d = idx >> 4, n = idx & 15;
    float4 w = *(const float4*)(Wg + idx);
    wgt[n + 0][d] = w.x; wgt[n + 1][d] = w.y;
    wgt[n + 2][d] = w.z; wgt[n + 3][d] = w.w;
  }
  int t = tid & 63, g = tid >> 6;
  double acc[4] = {0.0, 0.0, 0.0, 0.0};
  int sr = tid >> 4;
  int sc = (tid & 15) * 4;
  for (int ch = 0; ch < 16; ++ch) {
    __syncthreads();
#pragma unroll
    for (int i = 0; i < 4; ++i) {
      int r = sr + i * 16;
      float4 xv = *(const float4*)(x + (size_t)(t0 + r) * DDIM + ch * 64 + sc);
      xt[r][sc + 0] = xv.x; xt[r][sc + 1] = xv.y;
      xt[r][sc + 2] = xv.z; xt[r][sc + 3] = xv.w;
      if (xb) {
        unsigned p0 = cvt_pk_bf16(xv.x, xv.y);
        unsigned p1 = cvt_pk_bf16(xv.z, xv.w);
        *(uint2*)(xb + (size_t)(t0 + r) * DDIM + ch * 64 + sc) = make_uint2(p0, p1);
      }
    }
    __syncthreads();
#pragma unroll
    for (int d4 = 0; d4 < 16; ++d4) {
      float4 xv = *(const float4*)(&xt[t][d4 * 4]);
#pragma unroll
      for (int j = 0; j < 4; ++j) {
        float4 wv = *(const float4*)(&wgt[4 * g + j][ch * 64 + d4 * 4]);
        acc[j] += (double)xv.x * (double)wv.x + (double)xv.y * (double)wv.y +
                  (double)xv.z * (double)wv.z + (double)xv.w * (double)wv.w;
      }
    }
  }
#pragma unroll
  for (int j = 0; j < 4; ++j) lg[t][4 * g + j] = acc[j];
  __syncthreads();
  if (tid < 64) {
    double mx = lg[tid][0]; int bi = 0;
#pragma unroll
    for (int n = 1; n < NEXP; ++n)
      if (lg[tid][n] > mx) { mx = lg[tid][n]; bi = n; }
    double s = 0.0;
#pragma unroll
    for (int n = 0; n < NEXP; ++n) s += exp(lg[tid][n] - mx);
    e[t0 + tid] = bi;
    v[t0 + tid] = (float)(1.0 / s);
    atomicAdd(&hcnt[bi], 1);
  }
  __syncthreads();
  if (tid < NEXP && hcnt[tid] > 0) atomicAdd(&counts[tid], hcnt[tid]);
}

// ======================= FAST PATH (bf16 pre-converted) =====================
// R12 FFN structure (best): 128x128 tile, BK=64, double-buffered, counted
// vmcnt, reg-prefetch within iter. B-panels read from TILED weights:
// granule byte = tile_id*8192 + (row&63)*128 + g*16, kt stride = 8192.
// Regressions to avoid: 256^2 tile (R8), 2-set frags (R10), BK=32 ring (R13).

__global__ __launch_bounds__(256) void ffn1_fast(
    const unsigned short* __restrict__ xb, const unsigned short* __restrict__ w1t,
    const float* __restrict__ b1, const int* __restrict__ m_sel,
    const int* __restrict__ lists, unsigned short* __restrict__ H) {
  __shared__ __align__(16) unsigned short As[2][128 * 64];
  __shared__ __align__(16) unsigned short Bs[2][128 * 64];
  const int NWG = NEXP * 10 * 16;  // 2560
  const int NT = DDIM / 64;        // 16
  int bid = blockIdx.x;
  int lid = (bid & 7) * (NWG / 8) + (bid >> 3);
  int n = lid / 160;
  int rem = lid - n * 160;
  int mt = rem >> 4, ht = rem & 15;
  int M = m_sel[n];
  if (mt * 128 >= M) return;
  int tid = threadIdx.x;
  int lane = tid & 63, wid = tid >> 6;
  int wr = (wid >> 1) * 64, wc = (wid & 1) * 64;
  int rbase = tid >> 3;
  int c16 = tid & 7;
  const char* xbase = (const char*)xb;
  const char* bbase = (const char*)w1t + (size_t)n * (DDIM * HDIM * 2);
  unsigned asrc[4], bsrc[4], ldsoff[4];
#pragma unroll
  for (int j = 0; j < 4; ++j) {
    int row = j * 32 + rbase;
    int g = c16 ^ (row & 7);
    int s = mt * 128 + row;
    int tok = lists[n * CAP + (s < M ? s : 0)];
    asrc[j] = (unsigned)tok * 2048u + g * 16;
    bsrc[j] = (unsigned)((ht * 2 + (row >> 6)) * 16) * 8192u +
              (unsigned)(row & 63) * 128u + g * 16;
    ldsoff[j] = j * 4096 + wid * 1024;
  }
  unsigned aoff[2][4], boff[2][4];
#pragma unroll
  for (int kk = 0; kk < 2; ++kk) {
#pragma unroll
    for (int mi = 0; mi < 4; ++mi) {
      int row = wr + mi * 16 + (lane & 15);
      aoff[kk][mi] = row * 128 + (((kk * 4 + (lane >> 4)) ^ (row & 7)) * 16);
    }
#pragma unroll
    for (int ni = 0; ni < 4; ++ni) {
      int row = wc + ni * 16 + (lane & 15);
      boff[kk][ni] = row * 128 + (((kk * 4 + (lane >> 4)) ^ (row & 7)) * 16);
    }
  }
  f32x4 acc[4][4] = {};
#define STAGE1(buf, kt)                                                     \
  {                                                                         \
    unsigned koa = (unsigned)(kt) * 128u;                                   \
    unsigned kob = (unsigned)(kt) * 8192u;                                  \
    _Pragma("unroll") for (int j = 0; j < 4; ++j) {                         \
      GLD16(xbase + (size_t)(asrc[j] + koa), (char*)As[buf] + ldsoff[j]);   \
      GLD16(bbase + (size_t)(bsrc[j] + kob), (char*)Bs[buf] + ldsoff[j]);   \
    }                                                                       \
  }
  STAGE1(0, 0);
  STAGE1(1, 1);
  int cur = 0;
  for (int kt = 0; kt < NT; ++kt) {
    if (kt < NT - 1) asm volatile("s_waitcnt vmcnt(8)" ::: "memory");
    else             asm volatile("s_waitcnt vmcnt(0)" ::: "memory");
    RAW_BARRIER();
    bf16x8 af[2][4], bfv[2][4];
#pragma unroll
    for (int kk = 0; kk < 2; ++kk) {
#pragma unroll
      for (int mi = 0; mi < 4; ++mi)
        af[kk][mi] = *(const bf16x8*)((const char*)As[cur] + aoff[kk][mi]);
#pragma unroll
      for (int ni = 0; ni < 4; ++ni)
        bfv[kk][ni] = *(const bf16x8*)((const char*)Bs[cur] + boff[kk][ni]);
    }
    asm volatile("s_waitcnt lgkmcnt(0)" ::: "memory");
    RAW_BARRIER();
    if (kt + 2 < NT) STAGE1(cur, kt + 2);
    __builtin_amdgcn_s_setprio(1);
#pragma unroll
    for (int kk = 0; kk < 2; ++kk)
#pragma unroll
      for (int mi = 0; mi < 4; ++mi)
#pragma unroll
        for (int ni = 0; ni < 4; ++ni)
          acc[mi][ni] = __builtin_amdgcn_mfma_f32_16x16x32_bf16(af[kk][mi], bfv[kk][ni], acc[mi][ni], 0, 0, 0);
    __builtin_amdgcn_s_setprio(0);
    cur ^= 1;
  }
  int rq = (lane >> 4) * 4;
#pragma unroll
  for (int ni = 0; ni < 4; ++ni) {
    int h = ht * 128 + wc + ni * 16 + (lane & 15);
    float bias = b1[n * HDIM + h];
#pragma unroll
    for (int mi = 0; mi < 4; ++mi) {
#pragma unroll
      for (int q = 0; q < 4; ++q) {
        int lr = wr + mi * 16 + rq + q;
        float val = acc[mi][ni][q] + bias;
        H[((size_t)n * CAP + mt * 128 + lr) * HDIM + h] = f2bf(fast_gelu(val));
      }
    }
  }
}

__global__ __launch_bounds__(256) void ffn2_fast(
    const unsigned short* __restrict__ H, const unsigned short* __restrict__ w2t,
    const float* __restrict__ b2, const int* __restrict__ m_sel,
    const int* __restrict__ lists, float* __restrict__ out) {
  __shared__ __align__(16) unsigned short As[2][128 * 64];
  __shared__ __align__(16) unsigned short Bs[2][128 * 64];
  const int NWG = NEXP * 10 * 8;  // 1280
  const int NT = HDIM / 64;       // 32
  int bid = blockIdx.x;
  int tid = threadIdx.x;
  int lid = (bid & 7) * (NWG / 8) + (bid >> 3);
  int n = lid / 80;
  int rem = lid - n * 80;
  int mt = rem >> 3, dt = rem & 7;
  int M = m_sel[n];
  if (mt * 128 >= M) return;
  int lane = tid & 63, wid = tid >> 6;
  int wr = (wid >> 1) * 64, wc = (wid & 1) * 64;
  int rbase = tid >> 3;
  int c16 = tid & 7;
  const char* abase = (const char*)H + (((size_t)n * CAP + (size_t)mt * 128) * HDIM) * 2;
  const char* bbase = (const char*)w2t + (size_t)n * (DDIM * HDIM * 2);
  unsigned asrc[4], bsrc[4], ldsoff[4];
#pragma unroll
  for (int j = 0; j < 4; ++j) {
    int row = j * 32 + rbase;
    int g = c16 ^ (row & 7);
    asrc[j] = (unsigned)row * 4096u + g * 16;
    bsrc[j] = (unsigned)((dt * 2 + (row >> 6)) * 32) * 8192u +
              (unsigned)(row & 63) * 128u + g * 16;
    ldsoff[j] = j * 4096 + wid * 1024;
  }
  unsigned aoff[2][4], boff[2][4];
#pragma unroll
  for (int kk = 0; kk < 2; ++kk) {
#pragma unroll
    for (int mi = 0; mi < 4; ++mi) {
      int row = wr + mi * 16 + (lane & 15);
      aoff[kk][mi] = row * 128 + (((kk * 4 + (lane >> 4)) ^ (row & 7)) * 16);
    }
#pragma unroll
    for (int ni = 0; ni < 4; ++ni) {
      int row = wc + ni * 16 + (lane & 15);
      boff[kk][ni] = row * 128 + (((kk * 4 + (lane >> 4)) ^ (row & 7)) * 16);
    }
  }
  f32x4 acc[4][4] = {};
#define STAGE2(buf, kt)                                                     \
  {                                                                         \
    unsigned koa = (unsigned)(kt) * 128u;                                   \
    unsigned kob = (unsigned)(kt) * 8192u;                                  \
    _Pragma("unroll") for (int j = 0; j < 4; ++j) {                         \
      GLD16(abase + (size_t)(asrc[j] + koa), (char*)As[buf] + ldsoff[j]);   \
      GLD16(bbase + (size_t)(bsrc[j] + kob), (char*)Bs[buf] + ldsoff[j]);   \
    }                                                                       \
  }
  STAGE2(0, 0);
  STAGE2(1, 1);
  int cur = 0;
  for (int kt = 0; kt < NT; ++kt) {
    if (kt < NT - 1) asm volatile("s_waitcnt vmcnt(8)" ::: "memory");
    else             asm volatile("s_waitcnt vmcnt(0)" ::: "memory");
    RAW_BARRIER();
    bf16x8 af[2][4], bfv[2][4];
#pragma unroll
    for (int kk = 0; kk < 2; ++kk) {
#pragma unroll
      for (int mi = 0; mi < 4; ++mi)
        af[kk][mi] = *(const bf16x8*)((const char*)As[cur] + aoff[kk][mi]);
#pragma unroll
      for (int ni = 0; ni < 4; ++ni)
        bfv[kk][ni] = *(const bf16x8*)((const char*)Bs[cur] + boff[kk][ni]);
    }
    asm volatile("s_waitcnt lgkmcnt(0)" ::: "memory");
    RAW_BARRIER();
    if (kt + 2 < NT) STAGE2(cur, kt + 2);
    __builtin_amdgcn_s_setprio(1);
#pragma unroll
    for (int kk = 0; kk < 2; ++kk)
#pragma unroll
      for (int mi = 0; mi < 4; ++mi)
#pragma unroll
        for (int ni = 0; ni < 4; ++ni)
          acc[mi][ni] = __builtin_amdgcn_mfma_f32_16x16x32_bf16(af[kk][mi], bfv[kk][ni], acc[mi][ni], 0, 0, 0);
    __builtin_amdgcn_s_setprio(0);
    cur ^= 1;
  }
  int rq = (lane >> 4) * 4;
  float bias[4];
#pragma unroll
  for (int ni = 0; ni < 4; ++ni)
    bias[ni] = b2[n * DDIM + dt * 128 + wc + ni * 16 + (lane & 15)];
#pragma unroll
  for (int mi = 0; mi < 4; ++mi) {
#pragma unroll
    for (int q = 0; q < 4; ++q) {
      int lr = wr + mi * 16 + rq + q;
      int s = mt * 128 + lr;
      if (s < M) {
        int tok = lists[n * CAP + s];
#pragma unroll
        for (int ni = 0; ni < 4; ++ni) {
          int dcol = dt * 128 + wc + ni * 16 + (lane & 15);
          out[(size_t)tok * DDIM + dcol] = acc[mi][ni][q] + bias[ni];
        }
      }
    }
  }
}

// ======================= SLOW PATH (ws fallback) ============================
__global__ __launch_bounds__(256) void ffn1_slow(
    const float* __restrict__ x, const float* __restrict__ W1, const float* __restrict__ b1,
    const int* __restrict__ m_sel, const int* __restrict__ lists,
    unsigned short* __restrict__ H) {
  __shared__ unsigned short Al[128 * APITCH];
  __shared__ unsigned short Bl[128 * APITCH];
  __shared__ int rows[128];
  int n = blockIdx.z, mt = blockIdx.y, ht = blockIdx.x;
  int M = m_sel[n];
  if (mt * 128 >= M) return;
  int tid = threadIdx.x;
  if (tid < 128) {
    int s = mt * 128 + tid;
    rows[tid] = lists[n * CAP + (s < M ? s : 0)];
  }
  __syncthreads();
  f32x4 acc[4][4] = {};
  int lane = tid & 63;
  int wid = tid >> 6;
  int wr = (wid >> 1) * 64, wc = (wid & 1) * 64;
  int ar = tid >> 4, ac = (tid & 15) * 4;
  int bh = tid & 127, bk8 = (tid >> 7) * 8;
  const size_t w1base = (size_t)n * DDIM * HDIM + (size_t)ht * 128;
  for (int kt = 0; kt < DDIM / 64; ++kt) {
#pragma unroll
    for (int i = 0; i < 8; ++i) {
      int r = ar + i * 16;
      float4 xv = *(const float4*)(x + (size_t)rows[r] * DDIM + kt * 64 + ac);
      unsigned plo = (unsigned)f2bf(xv.x) | ((unsigned)f2bf(xv.y) << 16);
      unsigned phi = (unsigned)f2bf(xv.z) | ((unsigned)f2bf(xv.w) << 16);
      *(uint2*)(&Al[r * APITCH + ac]) = make_uint2(plo, phi);
    }
#pragma unroll
    for (int i = 0; i < 4; ++i) {
      int k0 = bk8 + i * 16;
      const float* wp = W1 + w1base + (size_t)(kt * 64 + k0) * HDIM + bh;
      uint4 pk;
      pk.x = (unsigned)f2bf(wp[0]) | ((unsigned)f2bf(wp[HDIM]) << 16);
      pk.y = (unsigned)f2bf(wp[2 * HDIM]) | ((unsigned)f2bf(wp[3 * HDIM]) << 16);
      pk.z = (unsigned)f2bf(wp[4 * HDIM]) | ((unsigned)f2bf(wp[5 * HDIM]) << 16);
      pk.w = (unsigned)f2bf(wp[6 * HDIM]) | ((unsigned)f2bf(wp[7 * HDIM]) << 16);
      *(uint4*)(&Bl[bh * APITCH + k0]) = pk;
    }
    __syncthreads();
#pragma unroll
    for (int kk = 0; kk < 2; ++kk) {
      bf16x8 af[4], bfr[4];
#pragma unroll
      for (int mi = 0; mi < 4; ++mi)
        af[mi] = *(const bf16x8*)(&Al[(wr + mi * 16 + (lane & 15)) * APITCH + kk * 32 + (lane >> 4) * 8]);
#pragma unroll
      for (int ni = 0; ni < 4; ++ni)
        bfr[ni] = *(const bf16x8*)(&Bl[(wc + ni * 16 + (lane & 15)) * APITCH + kk * 32 + (lane >> 4) * 8]);
#pragma unroll
      for (int mi = 0; mi < 4; ++mi)
#pragma unroll
        for (int ni = 0; ni < 4; ++ni)
          acc[mi][ni] = __builtin_amdgcn_mfma_f32_16x16x32_bf16(af[mi], bfr[ni], acc[mi][ni], 0, 0, 0);
    }
    __syncthreads();
  }
  int rq = (lane >> 4) * 4;
#pragma unroll
  for (int ni = 0; ni < 4; ++ni) {
    int h = ht * 128 + wc + ni * 16 + (lane & 15);
    float bias = b1[n * HDIM + h];
#pragma unroll
    for (int mi = 0; mi < 4; ++mi) {
#pragma unroll
      for (int q = 0; q < 4; ++q) {
        int lr = wr + mi * 16 + rq + q;
        float val = acc[mi][ni][q] + bias;
        H[((size_t)n * CAP + mt * 128 + lr) * HDIM + h] = f2bf(fast_gelu(val));
      }
    }
  }
}

__global__ __launch_bounds__(256) void ffn2_slow(
    const unsigned short* __restrict__ H, const float* __restrict__ W2, const float* __restrict__ b2,
    const int* __restrict__ m_sel, const int* __restrict__ lists,
    float* __restrict__ out) {
  __shared__ unsigned short Al[128 * APITCH];
  __shared__ unsigned short Bl[128 * APITCH];
  __shared__ int rows[128];
  int n = blockIdx.z, mt = blockIdx.y, dt = blockIdx.x;
  int M = m_sel[n];
  if (mt * 128 >= M) return;
  int tid = threadIdx.x;
  if (tid < 128) {
    int s = mt * 128 + tid;
    rows[tid] = lists[n * CAP + (s < M ? s : 0)];
  }
  __syncthreads();
  f32x4 acc[4][4] = {};
  int lane = tid & 63;
  int wid = tid >> 6;
  int wr = (wid >> 1) * 64, wc = (wid & 1) * 64;
  int ar2 = tid >> 1, ak8 = (tid & 1) * 8;
  int bh = tid & 127, bk8 = (tid >> 7) * 8;
  const size_t hbase = ((size_t)n * CAP + (size_t)mt * 128) * HDIM;
  const size_t w2base = (size_t)n * HDIM * DDIM + (size_t)dt * 128;
  for (int kt = 0; kt < HDIM / 64; ++kt) {
#pragma unroll
    for (int i = 0; i < 4; ++i) {
      int k0 = ak8 + i * 16;
      uint4 hv = *(const uint4*)(H + hbase + (size_t)ar2 * HDIM + kt * 64 + k0);
      *(uint4*)(&Al[ar2 * APITCH + k0]) = hv;
    }
#pragma unroll
    for (int i = 0; i < 4; ++i) {
      int k0 = bk8 + i * 16;
      const float* wp = W2 + w2base + (size_t)(kt * 64 + k0) * DDIM + bh;
      uint4 pk;
      pk.x = (unsigned)f2bf(wp[0]) | ((unsigned)f2bf(wp[DDIM]) << 16);
      pk.y = (unsigned)f2bf(wp[2 * DDIM]) | ((unsigned)f2bf(wp[3 * DDIM]) << 16);
      pk.z = (unsigned)f2bf(wp[4 * DDIM]) | ((unsigned)f2bf(wp[5 * DDIM]) << 16);
      pk.w = (unsigned)f2bf(wp[6 * DDIM]) | ((unsigned)f2bf(wp[7 * DDIM]) << 16);
      *(uint4*)(&Bl[bh * APITCH + k0]) = pk;
    }
    __syncthreads();
#pragma unroll
    for (int kk = 0; kk < 2; ++kk) {
      bf16x8 af[4], bfr[4];
#pragma unroll
      for (int mi = 0; mi < 4; ++mi)
        af[mi] = *(const bf16x8*)(&Al[(wr + mi * 16 + (lane & 15)) * APITCH + kk * 32 + (lane >> 4) * 8]);
#pragma unroll
      for (int ni = 0; ni < 4; ++ni)
        bfr[ni] = *(const bf16x8*)(&Bl[(wc + ni * 16 + (lane & 15)) * APITCH + kk * 32 + (lane >> 4) * 8]);
#pragma unroll
      for (int mi = 0; mi < 4; ++mi)
#pragma unroll
        for (int ni = 0; ni < 4; ++ni)
          acc[mi][ni] = __builtin_amdgcn_mfma_f32_16x16x32_bf16(af[mi], bfr[ni], acc[mi][ni], 0, 0, 0);
    }
    __syncthreads();
  }
  int rq = (lane >> 4) * 4;
#pragma unroll
  for (int mi = 0; mi < 4; ++mi) {
#pragma unroll
    for (int q = 0; q < 4; ++q) {
      int lr = wr + mi * 16 + rq + q;
      int s = mt * 128 + lr;
      if (s < M) {
        int tok = rows[lr];
#pragma unroll
        for (int ni = 0; ni < 4; ++ni) {
          int dcol = dt * 128 + wc + ni * 16 + (lane & 15);
          out[(size_t)tok * DDIM + dcol] = acc[mi][ni][q] + b2[n * DDIM + dcol];
        }
      }
    }
  }
}

// ---------------- passthrough: one wave per row, 1024 blocks ----------------
__global__ __launch_bounds__(256) void passthrough_kernel(
    const float* __restrict__ x, const int* __restrict__ flags,
    float* __restrict__ out) {
  int lane = threadIdx.x & 63;
  int w = threadIdx.x >> 6;
  int base = blockIdx.x * 16;
  for (int r = base + w; r < base + 16; r += 4) {
    if (flags[r]) continue;
    const float4* s = (const float4*)(x + (size_t)r * DDIM);
    float4* d = (float4*)(out + (size_t)r * DDIM);
#pragma unroll
    for (int i = 0; i < 4; ++i) d[lane + i * 64] = s[lane + i * 64];
  }
}

extern "C" void kernel_launch(void* const* d_in, const int* in_sizes, int n_in,
                              void* d_out, int out_size, void* d_ws, size_t ws_size,
                              hipStream_t stream) {
  const float* x  = (const float*)d_in[0];
  const float* Wg = (const float*)d_in[1];
  const float* W1 = (const float*)d_in[2];
  const float* b1 = (const float*)d_in[3];
  const float* W2 = (const float*)d_in[4];
  const float* b2 = (const float*)d_in[5];
  float* out = (float*)d_out;
  char* ws = (char*)d_ws;
  int* counts = (int*)ws;
  int* m_sel  = (int*)(ws + 64);
  int* flags  = (int*)(ws + 128);
  int* e      = (int*)(ws + 128 + 4 * BT);
  float* v    = (float*)(ws + 128 + 8 * BT);
  int* lists  = (int*)(ws + 128 + 12 * BT);

  const size_t MB = 1024 * 1024;
  unsigned short* xb  = (unsigned short*)(ws + 1 * MB);
  unsigned short* w1t = (unsigned short*)(ws + 33 * MB);
  unsigned short* w2t = (unsigned short*)(ws + 97 * MB);
  unsigned short* Hf  = (unsigned short*)(ws + 161 * MB);
  bool fast = ws_size >= 242 * MB;

  zero_meta_kernel<<<1, 64, 0, stream>>>(counts);
  if (fast) {
    prep_kernel<<<256 + 4096, 256, 0, stream>>>(x, Wg, e, v, counts, xb, flags,
                                                W1, W2, w1t, w2t);
    select_kernel<<<NEXP, 256, 0, stream>>>(e, v, counts, m_sel, lists, flags);
    ffn1_fast<<<NEXP * 10 * 16, 256, 0, stream>>>(xb, w1t, b1, m_sel, lists, Hf);
    ffn2_fast<<<NEXP * 10 * 8, 256, 0, stream>>>(Hf, w2t, b2, m_sel, lists, out);
  } else {
    unsigned short* Hs = (unsigned short*)(ws + 1 * MB);
    gate_kernel<<<BT / 64, 256, 0, stream>>>(x, Wg, e, v, counts, (unsigned short*)nullptr, flags);
    select_kernel<<<NEXP, 256, 0, stream>>>(e, v, counts, m_sel, lists, flags);
    ffn1_slow<<<dim3(HDIM / 128, CAP / 128, NEXP), 256, 0, stream>>>(x, W1, b1, m_sel, lists, Hs);
    ffn2_slow<<<dim3(DDIM / 128, CAP / 128, NEXP), 256, 0, stream>>>(Hs, W2, b2, m_sel, lists, out);
  }
  passthrough_kernel<<<BT / 16, 256, 0, stream>>>(x, flags, out);
}

// Round 17
// 399.662 us; speedup vs baseline: 1.0003x; 1.0003x over previous
//
#include <hip/hip_runtime.h>
#include <hip/hip_bf16.h>
#include <math.h>

#define BT 16384
#define DDIM 1024
#define NEXP 16
#define HDIM 2048
#define CAP 1280
#define APITCH 72
#define LBP 262  // bf16 LDS slab pitch

typedef __bf16 bf16x8 __attribute__((ext_vector_type(8)));
typedef float f32x4 __attribute__((ext_vector_type(4)));

__device__ __forceinline__ unsigned short f2bf(float f) {
  unsigned u = __float_as_uint(f);
  u += 0x7FFFu + ((u >> 16) & 1u);
  return (unsigned short)(u >> 16);
}

// HW packed fp32->bf16 (RNE, identical to f2bf): dst.lo=cvt(a), dst.hi=cvt(b)
__device__ __forceinline__ unsigned cvt_pk_bf16(float a, float b) {
  unsigned r;
  asm("v_cvt_pk_bf16_f32 %0, %1, %2" : "=v"(r) : "v"(a), "v"(b));
  return r;
}

// gelu(tanh approx) == v * sigmoid(2z); hardware v_exp_f32 path.
__device__ __forceinline__ float fast_gelu(float v) {
  float z = 0.7978845608028654f * (v + 0.044715f * v * v * v);
  return v / (1.0f + __expf(-2.0f * z));
}

#define GLD16(g, l)                                                        \
  __builtin_amdgcn_global_load_lds(                                        \
      (const __attribute__((address_space(1))) unsigned int*)(g),          \
      (__attribute__((address_space(3))) unsigned int*)(l), 16, 0, 0)

// Raw barrier without the vmcnt(0) drain __syncthreads would emit.
#define RAW_BARRIER()                          \
  {                                            \
    __builtin_amdgcn_sched_barrier(0);         \
    __builtin_amdgcn_s_barrier();              \
    __builtin_amdgcn_sched_barrier(0);         \
  }

__global__ void zero_meta_kernel(int* p) {
  int i = threadIdx.x;
  if (i < 32) p[i] = 0;  // counts[16] + m_sel[16]
}

// ---- shared slab-transpose body: 64 rows x 256 cols fp32 -> 4 tiled 64x64
// bf16 tiles ([col][row] inside tile, 8KB each, 2x4KB contiguous bursts) ----
__device__ __forceinline__ void slab_transpose(
    unsigned short* Lb, const float* src, int C,
    unsigned short* outp, size_t tile_base, int tmul, int by, int bxq, int tid) {
  int w = tid >> 6, lane = tid & 63;
#pragma unroll
  for (int k = 0; k < 16; ++k) {
    int row = w + k * 4;
    float4 vv = *(const float4*)(src + (size_t)row * C + lane * 4);
    unsigned p0 = cvt_pk_bf16(vv.x, vv.y);
    unsigned p1 = cvt_pk_bf16(vv.z, vv.w);
    *(uint2*)(&Lb[row * LBP + lane * 4]) = make_uint2(p0, p1);
  }
  __syncthreads();
  int oc_lo = tid >> 3;
  int rb = (tid & 7) * 8;
#pragma unroll
  for (int p2 = 0; p2 < 4; ++p2) {
    int bx = bxq * 4 + p2;
    char* dstT = (char*)outp + (tile_base + (size_t)bx * tmul + by) * 8192;
#pragma unroll
    for (int p = 0; p < 2; ++p) {
      int oc = p * 32 + oc_lo;
      const unsigned short* col = &Lb[rb * LBP + p2 * 64 + oc];
      unsigned short u[8];
#pragma unroll
      for (int j = 0; j < 8; ++j) u[j] = col[j * LBP];
      uint4 pk;
      pk.x = (unsigned)u[0] | ((unsigned)u[1] << 16);
      pk.y = (unsigned)u[2] | ((unsigned)u[3] << 16);
      pk.z = (unsigned)u[4] | ((unsigned)u[5] << 16);
      pk.w = (unsigned)u[6] | ((unsigned)u[7] << 16);
      *(uint4*)(dstT + p * 4096 + tid * 16) = pk;
    }
  }
}

// ======== fused prep ========================================================
// blocks [0,256): gate. blocks [256,256+2048): W1 slab transpose only.
// (W2 transpose moved into ffn1's grid tail to hide under GEMM idle BW.)
__global__ __launch_bounds__(256) void prep_kernel(
    const float* __restrict__ x, const float* __restrict__ Wg,
    int* __restrict__ e, float* __restrict__ v, int* __restrict__ counts,
    unsigned short* __restrict__ xb, int* __restrict__ flags,
    const float* __restrict__ W1, unsigned short* __restrict__ w1t) {
  __shared__ __align__(16) char smem[64 * LBP * 2];  // 33536B
  int bid = blockIdx.x;
  int tid = threadIdx.x;
  if (bid < 256) {
    // ---------------- gate: 64 tokens/block ----------------
    float* xt = (float*)smem;                       // [64][68]  17408B
    double* lg = (double*)(smem + 17408);           // [64][16]   8192B
    float* wgt_c = (float*)(smem + 25600);          // [16][68]   4352B
    int* hcnt = (int*)(smem + 29952);               // [16]
    int t0 = bid * 64;
    if (tid < NEXP) hcnt[tid] = 0;
    if (tid < 64) flags[t0 + tid] = 0;
    int t = tid & 63, g = tid >> 6;
    double acc[4] = {0.0, 0.0, 0.0, 0.0};
    int sr = tid >> 4;
    int sc = (tid & 15) * 4;
    int wd = tid >> 2, wn = (tid & 3) * 4;
    for (int ch = 0; ch < 16; ++ch) {
      __syncthreads();
#pragma unroll
      for (int i = 0; i < 4; ++i) {
        int r = sr + i * 16;
        float4 xv = *(const float4*)(x + (size_t)(t0 + r) * DDIM + ch * 64 + sc);
        xt[r * 68 + sc + 0] = xv.x; xt[r * 68 + sc + 1] = xv.y;
        xt[r * 68 + sc + 2] = xv.z; xt[r * 68 + sc + 3] = xv.w;
        unsigned p0 = cvt_pk_bf16(xv.x, xv.y);
        unsigned p1 = cvt_pk_bf16(xv.z, xv.w);
        *(uint2*)(xb + (size_t)(t0 + r) * DDIM + ch * 64 + sc) = make_uint2(p0, p1);
      }
      {
        float4 w = *(const float4*)(Wg + ch * 1024 + tid * 4);
        wgt_c[(wn + 0) * 68 + wd] = w.x;
        wgt_c[(wn + 1) * 68 + wd] = w.y;
        wgt_c[(wn + 2) * 68 + wd] = w.z;
        wgt_c[(wn + 3) * 68 + wd] = w.w;
      }
      __syncthreads();
#pragma unroll
      for (int d4 = 0; d4 < 16; ++d4) {
        float4 xv = *(const float4*)(&xt[t * 68 + d4 * 4]);
#pragma unroll
        for (int j = 0; j < 4; ++j) {
          float4 wv = *(const float4*)(&wgt_c[(4 * g + j) * 68 + d4 * 4]);
          acc[j] += (double)xv.x * (double)wv.x + (double)xv.y * (double)wv.y +
                    (double)xv.z * (double)wv.z + (double)xv.w * (double)wv.w;
        }
      }
    }
#pragma unroll
    for (int j = 0; j < 4; ++j) lg[t * 16 + 4 * g + j] = acc[j];
    __syncthreads();
    if (tid < 64) {
      double mx = lg[tid * 16]; int bi = 0;
#pragma unroll
      for (int n = 1; n < NEXP; ++n)
        if (lg[tid * 16 + n] > mx) { mx = lg[tid * 16 + n]; bi = n; }
      double s = 0.0;
#pragma unroll
      for (int n = 0; n < NEXP; ++n) s += exp(lg[tid * 16 + n] - mx);
      e[t0 + tid] = bi;
      v[t0 + tid] = (float)(1.0 / s);
      atomicAdd(&hcnt[bi], 1);
    }
    __syncthreads();
    if (tid < NEXP && hcnt[tid] > 0) atomicAdd(&counts[tid], hcnt[tid]);
    return;
  }
  // ---------------- W1 slab transpose: 16 d-tiles x 8 col-quads/expert ------
  int b = bid - 256;  // 0..2047
  int n = b >> 7; int rem = b & 127; int by = rem >> 3, bxq = rem & 7;
  const float* src = W1 + (size_t)n * DDIM * HDIM + (size_t)by * 64 * HDIM + bxq * 256;
  slab_transpose((unsigned short*)smem, src, HDIM, w1t,
                 (size_t)n * 512, 16, by, bxq, tid);
}

// ---------------- select: per-expert token set under capacity ---------------
__global__ void select_kernel(const int* __restrict__ e, const float* __restrict__ v,
                              const int* __restrict__ counts, int* __restrict__ m_sel,
                              int* __restrict__ lists, int* __restrict__ flags) {
  int n = blockIdx.x;
  int tid = threadIdx.x;
  int cnt = counts[n];
  __shared__ int pos;
  if (tid == 0) pos = 0;
  __syncthreads();
  if (cnt <= CAP) {
    for (int t = tid; t < BT; t += 256) {
      if (e[t] == n) {
        int p = atomicAdd(&pos, 1);
        lists[n * CAP + p] = t;
        flags[t] = 1;
      }
    }
    __syncthreads();
    if (tid == 0) m_sel[n] = pos;
  } else {
    __shared__ int scnt;
    unsigned lo = 0u, hi = 0x7F800000u;
    while (hi - lo > 1u) {
      unsigned mid = lo + ((hi - lo) >> 1);
      if (tid == 0) scnt = 0;
      __syncthreads();
      int c = 0;
      for (int t = tid; t < BT; t += 256)
        if (e[t] == n && __float_as_uint(v[t]) >= mid) c++;
      atomicAdd(&scnt, c);
      __syncthreads();
      int tot = scnt;
      __syncthreads();
      if (tot >= CAP) lo = mid; else hi = mid;
    }
    for (int t = tid; t < BT; t += 256) {
      if (e[t] == n && __float_as_uint(v[t]) > lo) {
        int p = atomicAdd(&pos, 1);
        lists[n * CAP + p] = t;
        flags[t] = 1;
      }
    }
    __syncthreads();
    if (tid == 0) {
      int p = pos;
      for (int t = 0; t < BT && p < CAP; ++t) {
        if (e[t] == n && __float_as_uint(v[t]) == lo) {
          lists[n * CAP + p] = t; flags[t] = 1; ++p;
        }
      }
      m_sel[n] = p;
    }
  }
}

// ---------------- gate (slow path only, resident Wg table) ------------------
__global__ __launch_bounds__(256) void gate_kernel(
    const float* __restrict__ x, const float* __restrict__ Wg,
    int* __restrict__ e, float* __restrict__ v, int* __restrict__ counts,
    unsigned short* __restrict__ xb, int* __restrict__ flags) {
  __shared__ float wgt[NEXP][DDIM];
  __shared__ float xt[64][68];
  __shared__ double lg[64][NEXP];
  __shared__ int hcnt[NEXP];
  int tid = threadIdx.x;
  int t0 = blockIdx.x * 64;
  if (tid < NEXP) hcnt[tid] = 0;
  if (tid < 64) flags[t0 + tid] = 0;
  for (int i = tid; i < DDIM * NEXP / 4; i += 256) {
    int idx = i * 4;
    int d = idx >> 4, n = idx & 15;
    float4 w = *(const float4*)(Wg + idx);
    wgt[n + 0][d] = w.x; wgt[n + 1][d] = w.y;
    wgt[n + 2][d] = w.z; wgt[n + 3][d] = w.w;
  }
  int t = tid & 63, g = tid >> 6;
  double acc[4] = {0.0, 0.0, 0.0, 0.0};
  int sr = tid >> 4;
  int sc = (tid & 15) * 4;
  for (int ch = 0; ch < 16; ++ch) {
    __syncthreads();
#pragma unroll
    for (int i = 0; i < 4; ++i) {
      int r = sr + i * 16;
      float4 xv = *(const float4*)(x + (size_t)(t0 + r) * DDIM + ch * 64 + sc);
      xt[r][sc + 0] = xv.x; xt[r][sc + 1] = xv.y;
      xt[r][sc + 2] = xv.z; xt[r][sc + 3] = xv.w;
      if (xb) {
        unsigned p0 = cvt_pk_bf16(xv.x, xv.y);
        unsigned p1 = cvt_pk_bf16(xv.z, xv.w);
        *(uint2*)(xb + (size_t)(t0 + r) * DDIM + ch * 64 + sc) = make_uint2(p0, p1);
      }
    }
    __syncthreads();
#pragma unroll
    for (int d4 = 0; d4 < 16; ++d4) {
      float4 xv = *(const float4*)(&xt[t][d4 * 4]);
#pragma unroll
      for (int j = 0; j < 4; ++j) {
        float4 wv = *(const float4*)(&wgt[4 * g + j][ch * 64 + d4 * 4]);
        acc[j] += (double)xv.x * (double)wv.x + (double)xv.y * (double)wv.y +
                  (double)xv.z * (double)wv.z + (double)xv.w * (double)wv.w;
      }
    }
  }
#pragma unroll
  for (int j = 0; j < 4; ++j) lg[t][4 * g + j] = acc[j];
  __syncthreads();
  if (tid < 64) {
    double mx = lg[tid][0]; int bi = 0;
#pragma unroll
    for (int n = 1; n < NEXP; ++n)
      if (lg[tid][n] > mx) { mx = lg[tid][n]; bi = n; }
    double s = 0.0;
#pragma unroll
    for (int n = 0; n < NEXP; ++n) s += exp(lg[tid][n] - mx);
    e[t0 + tid] = bi;
    v[t0 + tid] = (float)(1.0 / s);
    atomicAdd(&hcnt[bi], 1);
  }
  __syncthreads();
  if (tid < NEXP && hcnt[tid] > 0) atomicAdd(&counts[tid], hcnt[tid]);
}

// ======================= FAST PATH (bf16 pre-converted) =====================
// R12 FFN structure. ffn1 additionally carries 2048 TAIL blocks (bid>=2560)
// doing the W2 slab transpose -- they fill ffn1's idle memory bandwidth
// (GEMM uses ~1.3 of 6.3 TB/s). w2t is complete when ffn1 retires, before
// ffn2 launches. Tiled weights: granule byte = tile*8192 + (row&63)*128+g*16.

__global__ __launch_bounds__(256) void ffn1_fast(
    const unsigned short* __restrict__ xb, const unsigned short* __restrict__ w1t,
    const float* __restrict__ b1, const int* __restrict__ m_sel,
    const int* __restrict__ lists, unsigned short* __restrict__ H,
    const float* __restrict__ W2f, unsigned short* __restrict__ w2t) {
  __shared__ __align__(16) char smem[65536];
  unsigned short (*As)[8192] = (unsigned short(*)[8192])smem;
  unsigned short (*Bs)[8192] = (unsigned short(*)[8192])(smem + 32768);
  const int NWG = NEXP * 10 * 16;  // 2560
  const int NT = DDIM / 64;        // 16
  int bid = blockIdx.x;
  int tid = threadIdx.x;
  if (bid >= NWG) {
    // ---- W2 slab transpose tail: 32 h-tiles x 4 col-quads/expert ----
    int b = bid - NWG;  // 0..2047
    int n2 = b >> 7; int rem = b & 127; int by = rem >> 2, bxq = rem & 3;
    const float* src = W2f + (size_t)n2 * DDIM * HDIM + (size_t)by * 64 * DDIM + bxq * 256;
    slab_transpose((unsigned short*)smem, src, DDIM, w2t,
                   (size_t)n2 * 512, 32, by, bxq, tid);
    return;
  }
  int lid = (bid & 7) * (NWG / 8) + (bid >> 3);
  int n = lid / 160;
  int rem = lid - n * 160;
  int mt = rem >> 4, ht = rem & 15;
  int M = m_sel[n];
  if (mt * 128 >= M) return;
  int lane = tid & 63, wid = tid >> 6;
  int wr = (wid >> 1) * 64, wc = (wid & 1) * 64;
  int rbase = tid >> 3;
  int c16 = tid & 7;
  const char* xbase = (const char*)xb;
  const char* bbase = (const char*)w1t + (size_t)n * (DDIM * HDIM * 2);
  unsigned asrc[4], bsrc[4], ldsoff[4];
#pragma unroll
  for (int j = 0; j < 4; ++j) {
    int row = j * 32 + rbase;
    int g = c16 ^ (row & 7);
    int s = mt * 128 + row;
    int tok = lists[n * CAP + (s < M ? s : 0)];
    asrc[j] = (unsigned)tok * 2048u + g * 16;
    bsrc[j] = (unsigned)((ht * 2 + (row >> 6)) * 16) * 8192u +
              (unsigned)(row & 63) * 128u + g * 16;
    ldsoff[j] = j * 4096 + wid * 1024;
  }
  unsigned aoff[2][4], boff[2][4];
#pragma unroll
  for (int kk = 0; kk < 2; ++kk) {
#pragma unroll
    for (int mi = 0; mi < 4; ++mi) {
      int row = wr + mi * 16 + (lane & 15);
      aoff[kk][mi] = row * 128 + (((kk * 4 + (lane >> 4)) ^ (row & 7)) * 16);
    }
#pragma unroll
    for (int ni = 0; ni < 4; ++ni) {
      int row = wc + ni * 16 + (lane & 15);
      boff[kk][ni] = row * 128 + (((kk * 4 + (lane >> 4)) ^ (row & 7)) * 16);
    }
  }
  f32x4 acc[4][4] = {};
#define STAGE1(buf, kt)                                                     \
  {                                                                         \
    unsigned koa = (unsigned)(kt) * 128u;                                   \
    unsigned kob = (unsigned)(kt) * 8192u;                                  \
    _Pragma("unroll") for (int j = 0; j < 4; ++j) {                         \
      GLD16(xbase + (size_t)(asrc[j] + koa), (char*)As[buf] + ldsoff[j]);   \
      GLD16(bbase + (size_t)(bsrc[j] + kob), (char*)Bs[buf] + ldsoff[j]);   \
    }                                                                       \
  }
  STAGE1(0, 0);
  STAGE1(1, 1);
  int cur = 0;
  for (int kt = 0; kt < NT; ++kt) {
    if (kt < NT - 1) asm volatile("s_waitcnt vmcnt(8)" ::: "memory");
    else             asm volatile("s_waitcnt vmcnt(0)" ::: "memory");
    RAW_BARRIER();
    bf16x8 af[2][4], bfv[2][4];
#pragma unroll
    for (int kk = 0; kk < 2; ++kk) {
#pragma unroll
      for (int mi = 0; mi < 4; ++mi)
        af[kk][mi] = *(const bf16x8*)((const char*)As[cur] + aoff[kk][mi]);
#pragma unroll
      for (int ni = 0; ni < 4; ++ni)
        bfv[kk][ni] = *(const bf16x8*)((const char*)Bs[cur] + boff[kk][ni]);
    }
    asm volatile("s_waitcnt lgkmcnt(0)" ::: "memory");
    RAW_BARRIER();
    if (kt + 2 < NT) STAGE1(cur, kt + 2);
    __builtin_amdgcn_s_setprio(1);
#pragma unroll
    for (int kk = 0; kk < 2; ++kk)
#pragma unroll
      for (int mi = 0; mi < 4; ++mi)
#pragma unroll
        for (int ni = 0; ni < 4; ++ni)
          acc[mi][ni] = __builtin_amdgcn_mfma_f32_16x16x32_bf16(af[kk][mi], bfv[kk][ni], acc[mi][ni], 0, 0, 0);
    __builtin_amdgcn_s_setprio(0);
    cur ^= 1;
  }
  int rq = (lane >> 4) * 4;
#pragma unroll
  for (int ni = 0; ni < 4; ++ni) {
    int h = ht * 128 + wc + ni * 16 + (lane & 15);
    float bias = b1[n * HDIM + h];
#pragma unroll
    for (int mi = 0; mi < 4; ++mi) {
#pragma unroll
      for (int q = 0; q < 4; ++q) {
        int lr = wr + mi * 16 + rq + q;
        float val = acc[mi][ni][q] + bias;
        H[((size_t)n * CAP + mt * 128 + lr) * HDIM + h] = f2bf(fast_gelu(val));
      }
    }
  }
}

__global__ __launch_bounds__(256) void ffn2_fast(
    const unsigned short* __restrict__ H, const unsigned short* __restrict__ w2t,
    const float* __restrict__ b2, const int* __restrict__ m_sel,
    const int* __restrict__ lists, float* __restrict__ out) {
  __shared__ __align__(16) unsigned short As[2][128 * 64];
  __shared__ __align__(16) unsigned short Bs[2][128 * 64];
  const int NWG = NEXP * 10 * 8;  // 1280
  const int NT = HDIM / 64;       // 32
  int bid = blockIdx.x;
  int tid = threadIdx.x;
  int lid = (bid & 7) * (NWG / 8) + (bid >> 3);
  int n = lid / 80;
  int rem = lid - n * 80;
  int mt = rem >> 3, dt = rem & 7;
  int M = m_sel[n];
  if (mt * 128 >= M) return;
  int lane = tid & 63, wid = tid >> 6;
  int wr = (wid >> 1) * 64, wc = (wid & 1) * 64;
  int rbase = tid >> 3;
  int c16 = tid & 7;
  const char* abase = (const char*)H + (((size_t)n * CAP + (size_t)mt * 128) * HDIM) * 2;
  const char* bbase = (const char*)w2t + (size_t)n * (DDIM * HDIM * 2);
  unsigned asrc[4], bsrc[4], ldsoff[4];
#pragma unroll
  for (int j = 0; j < 4; ++j) {
    int row = j * 32 + rbase;
    int g = c16 ^ (row & 7);
    asrc[j] = (unsigned)row * 4096u + g * 16;
    bsrc[j] = (unsigned)((dt * 2 + (row >> 6)) * 32) * 8192u +
              (unsigned)(row & 63) * 128u + g * 16;
    ldsoff[j] = j * 4096 + wid * 1024;
  }
  unsigned aoff[2][4], boff[2][4];
#pragma unroll
  for (int kk = 0; kk < 2; ++kk) {
#pragma unroll
    for (int mi = 0; mi < 4; ++mi) {
      int row = wr + mi * 16 + (lane & 15);
      aoff[kk][mi] = row * 128 + (((kk * 4 + (lane >> 4)) ^ (row & 7)) * 16);
    }
#pragma unroll
    for (int ni = 0; ni < 4; ++ni) {
      int row = wc + ni * 16 + (lane & 15);
      boff[kk][ni] = row * 128 + (((kk * 4 + (lane >> 4)) ^ (row & 7)) * 16);
    }
  }
  f32x4 acc[4][4] = {};
#define STAGE2(buf, kt)                                                     \
  {                                                                         \
    unsigned koa = (unsigned)(kt) * 128u;                                   \
    unsigned kob = (unsigned)(kt) * 8192u;                                  \
    _Pragma("unroll") for (int j = 0; j < 4; ++j) {                         \
      GLD16(abase + (size_t)(asrc[j] + koa), (char*)As[buf] + ldsoff[j]);   \
      GLD16(bbase + (size_t)(bsrc[j] + kob), (char*)Bs[buf] + ldsoff[j]);   \
    }                                                                       \
  }
  STAGE2(0, 0);
  STAGE2(1, 1);
  int cur = 0;
  for (int kt = 0; kt < NT; ++kt) {
    if (kt < NT - 1) asm volatile("s_waitcnt vmcnt(8)" ::: "memory");
    else             asm volatile("s_waitcnt vmcnt(0)" ::: "memory");
    RAW_BARRIER();
    bf16x8 af[2][4], bfv[2][4];
#pragma unroll
    for (int kk = 0; kk < 2; ++kk) {
#pragma unroll
      for (int mi = 0; mi < 4; ++mi)
        af[kk][mi] = *(const bf16x8*)((const char*)As[cur] + aoff[kk][mi]);
#pragma unroll
      for (int ni = 0; ni < 4; ++ni)
        bfv[kk][ni] = *(const bf16x8*)((const char*)Bs[cur] + boff[kk][ni]);
    }
    asm volatile("s_waitcnt lgkmcnt(0)" ::: "memory");
    RAW_BARRIER();
    if (kt + 2 < NT) STAGE2(cur, kt + 2);
    __builtin_amdgcn_s_setprio(1);
#pragma unroll
    for (int kk = 0; kk < 2; ++kk)
#pragma unroll
      for (int mi = 0; mi < 4; ++mi)
#pragma unroll
        for (int ni = 0; ni < 4; ++ni)
          acc[mi][ni] = __builtin_amdgcn_mfma_f32_16x16x32_bf16(af[kk][mi], bfv[kk][ni], acc[mi][ni], 0, 0, 0);
    __builtin_amdgcn_s_setprio(0);
    cur ^= 1;
  }
  int rq = (lane >> 4) * 4;
  float bias[4];
#pragma unroll
  for (int ni = 0; ni < 4; ++ni)
    bias[ni] = b2[n * DDIM + dt * 128 + wc + ni * 16 + (lane & 15)];
#pragma unroll
  for (int mi = 0; mi < 4; ++mi) {
#pragma unroll
    for (int q = 0; q < 4; ++q) {
      int lr = wr + mi * 16 + rq + q;
      int s = mt * 128 + lr;
      if (s < M) {
        int tok = lists[n * CAP + s];
#pragma unroll
        for (int ni = 0; ni < 4; ++ni) {
          int dcol = dt * 128 + wc + ni * 16 + (lane & 15);
          out[(size_t)tok * DDIM + dcol] = acc[mi][ni][q] + bias[ni];
        }
      }
    }
  }
}

// ======================= SLOW PATH (ws fallback) ============================
__global__ __launch_bounds__(256) void ffn1_slow(
    const float* __restrict__ x, const float* __restrict__ W1, const float* __restrict__ b1,
    const int* __restrict__ m_sel, const int* __restrict__ lists,
    unsigned short* __restrict__ H) {
  __shared__ unsigned short Al[128 * APITCH];
  __shared__ unsigned short Bl[128 * APITCH];
  __shared__ int rows[128];
  int n = blockIdx.z, mt = blockIdx.y, ht = blockIdx.x;
  int M = m_sel[n];
  if (mt * 128 >= M) return;
  int tid = threadIdx.x;
  if (tid < 128) {
    int s = mt * 128 + tid;
    rows[tid] = lists[n * CAP + (s < M ? s : 0)];
  }
  __syncthreads();
  f32x4 acc[4][4] = {};
  int lane = tid & 63;
  int wid = tid >> 6;
  int wr = (wid >> 1) * 64, wc = (wid & 1) * 64;
  int ar = tid >> 4, ac = (tid & 15) * 4;
  int bh = tid & 127, bk8 = (tid >> 7) * 8;
  const size_t w1base = (size_t)n * DDIM * HDIM + (size_t)ht * 128;
  for (int kt = 0; kt < DDIM / 64; ++kt) {
#pragma unroll
    for (int i = 0; i < 8; ++i) {
      int r = ar + i * 16;
      float4 xv = *(const float4*)(x + (size_t)rows[r] * DDIM + kt * 64 + ac);
      unsigned plo = (unsigned)f2bf(xv.x) | ((unsigned)f2bf(xv.y) << 16);
      unsigned phi = (unsigned)f2bf(xv.z) | ((unsigned)f2bf(xv.w) << 16);
      *(uint2*)(&Al[r * APITCH + ac]) = make_uint2(plo, phi);
    }
#pragma unroll
    for (int i = 0; i < 4; ++i) {
      int k0 = bk8 + i * 16;
      const float* wp = W1 + w1base + (size_t)(kt * 64 + k0) * HDIM + bh;
      uint4 pk;
      pk.x = (unsigned)f2bf(wp[0]) | ((unsigned)f2bf(wp[HDIM]) << 16);
      pk.y = (unsigned)f2bf(wp[2 * HDIM]) | ((unsigned)f2bf(wp[3 * HDIM]) << 16);
      pk.z = (unsigned)f2bf(wp[4 * HDIM]) | ((unsigned)f2bf(wp[5 * HDIM]) << 16);
      pk.w = (unsigned)f2bf(wp[6 * HDIM]) | ((unsigned)f2bf(wp[7 * HDIM]) << 16);
      *(uint4*)(&Bl[bh * APITCH + k0]) = pk;
    }
    __syncthreads();
#pragma unroll
    for (int kk = 0; kk < 2; ++kk) {
      bf16x8 af[4], bfr[4];
#pragma unroll
      for (int mi = 0; mi < 4; ++mi)
        af[mi] = *(const bf16x8*)(&Al[(wr + mi * 16 + (lane & 15)) * APITCH + kk * 32 + (lane >> 4) * 8]);
#pragma unroll
      for (int ni = 0; ni < 4; ++ni)
        bfr[ni] = *(const bf16x8*)(&Bl[(wc + ni * 16 + (lane & 15)) * APITCH + kk * 32 + (lane >> 4) * 8]);
#pragma unroll
      for (int mi = 0; mi < 4; ++mi)
#pragma unroll
        for (int ni = 0; ni < 4; ++ni)
          acc[mi][ni] = __builtin_amdgcn_mfma_f32_16x16x32_bf16(af[mi], bfr[ni], acc[mi][ni], 0, 0, 0);
    }
    __syncthreads();
  }
  int rq = (lane >> 4) * 4;
#pragma unroll
  for (int ni = 0; ni < 4; ++ni) {
    int h = ht * 128 + wc + ni * 16 + (lane & 15);
    float bias = b1[n * HDIM + h];
#pragma unroll
    for (int mi = 0; mi < 4; ++mi) {
#pragma unroll
      for (int q = 0; q < 4; ++q) {
        int lr = wr + mi * 16 + rq + q;
        float val = acc[mi][ni][q] + bias;
        H[((size_t)n * CAP + mt * 128 + lr) * HDIM + h] = f2bf(fast_gelu(val));
      }
    }
  }
}

__global__ __launch_bounds__(256) void ffn2_slow(
    const unsigned short* __restrict__ H, const float* __restrict__ W2, const float* __restrict__ b2,
    const int* __restrict__ m_sel, const int* __restrict__ lists,
    float* __restrict__ out) {
  __shared__ unsigned short Al[128 * APITCH];
  __shared__ unsigned short Bl[128 * APITCH];
  __shared__ int rows[128];
  int n = blockIdx.z, mt = blockIdx.y, dt = blockIdx.x;
  int M = m_sel[n];
  if (mt * 128 >= M) return;
  int tid = threadIdx.x;
  if (tid < 128) {
    int s = mt * 128 + tid;
    rows[tid] = lists[n * CAP + (s < M ? s : 0)];
  }
  __syncthreads();
  f32x4 acc[4][4] = {};
  int lane = tid & 63;
  int wid = tid >> 6;
  int wr = (wid >> 1) * 64, wc = (wid & 1) * 64;
  int ar2 = tid >> 1, ak8 = (tid & 1) * 8;
  int bh = tid & 127, bk8 = (tid >> 7) * 8;
  const size_t hbase = ((size_t)n * CAP + (size_t)mt * 128) * HDIM;
  const size_t w2base = (size_t)n * HDIM * DDIM + (size_t)dt * 128;
  for (int kt = 0; kt < HDIM / 64; ++kt) {
#pragma unroll
    for (int i = 0; i < 4; ++i) {
      int k0 = ak8 + i * 16;
      uint4 hv = *(const uint4*)(H + hbase + (size_t)ar2 * HDIM + kt * 64 + k0);
      *(uint4*)(&Al[ar2 * APITCH + k0]) = hv;
    }
#pragma unroll
    for (int i = 0; i < 4; ++i) {
      int k0 = bk8 + i * 16;
      const float* wp = W2 + w2base + (size_t)(kt * 64 + k0) * DDIM + bh;
      uint4 pk;
      pk.x = (unsigned)f2bf(wp[0]) | ((unsigned)f2bf(wp[DDIM]) << 16);
      pk.y = (unsigned)f2bf(wp[2 * DDIM]) | ((unsigned)f2bf(wp[3 * DDIM]) << 16);
      pk.z = (unsigned)f2bf(wp[4 * DDIM]) | ((unsigned)f2bf(wp[5 * DDIM]) << 16);
      pk.w = (unsigned)f2bf(wp[6 * DDIM]) | ((unsigned)f2bf(wp[7 * DDIM]) << 16);
      *(uint4*)(&Bl[bh * APITCH + k0]) = pk;
    }
    __syncthreads();
#pragma unroll
    for (int kk = 0; kk < 2; ++kk) {
      bf16x8 af[4], bfr[4];
#pragma unroll
      for (int mi = 0; mi < 4; ++mi)
        af[mi] = *(const bf16x8*)(&Al[(wr + mi * 16 + (lane & 15)) * APITCH + kk * 32 + (lane >> 4) * 8]);
#pragma unroll
      for (int ni = 0; ni < 4; ++ni)
        bfr[ni] = *(const bf16x8*)(&Bl[(wc + ni * 16 + (lane & 15)) * APITCH + kk * 32 + (lane >> 4) * 8]);
#pragma unroll
      for (int mi = 0; mi < 4; ++mi)
#pragma unroll
        for (int ni = 0; ni < 4; ++ni)
          acc[mi][ni] = __builtin_amdgcn_mfma_f32_16x16x32_bf16(af[mi], bfr[ni], acc[mi][ni], 0, 0, 0);
    }
    __syncthreads();
  }
  int rq = (lane >> 4) * 4;
#pragma unroll
  for (int mi = 0; mi < 4; ++mi) {
#pragma unroll
    for (int q = 0; q < 4; ++q) {
      int lr = wr + mi * 16 + rq + q;
      int s = mt * 128 + lr;
      if (s < M) {
        int tok = rows[lr];
#pragma unroll
        for (int ni = 0; ni < 4; ++ni) {
          int dcol = dt * 128 + wc + ni * 16 + (lane & 15);
          out[(size_t)tok * DDIM + dcol] = acc[mi][ni][q] + b2[n * DDIM + dcol];
        }
      }
    }
  }
}

// ---------------- passthrough: one wave per row, 1024 blocks ----------------
__global__ __launch_bounds__(256) void passthrough_kernel(
    const float* __restrict__ x, const int* __restrict__ flags,
    float* __restrict__ out) {
  int lane = threadIdx.x & 63;
  int w = threadIdx.x >> 6;
  int base = blockIdx.x * 16;
  for (int r = base + w; r < base + 16; r += 4) {
    if (flags[r]) continue;
    const float4* s = (const float4*)(x + (size_t)r * DDIM);
    float4* d = (float4*)(out + (size_t)r * DDIM);
#pragma unroll
    for (int i = 0; i < 4; ++i) d[lane + i * 64] = s[lane + i * 64];
  }
}

extern "C" void kernel_launch(void* const* d_in, const int* in_sizes, int n_in,
                              void* d_out, int out_size, void* d_ws, size_t ws_size,
                              hipStream_t stream) {
  const float* x  = (const float*)d_in[0];
  const float* Wg = (const float*)d_in[1];
  const float* W1 = (const float*)d_in[2];
  const float* b1 = (const float*)d_in[3];
  const float* W2 = (const float*)d_in[4];
  const float* b2 = (const float*)d_in[5];
  float* out = (float*)d_out;
  char* ws = (char*)d_ws;
  int* counts = (int*)ws;
  int* m_sel  = (int*)(ws + 64);
  int* flags  = (int*)(ws + 128);
  int* e      = (int*)(ws + 128 + 4 * BT);
  float* v    = (float*)(ws + 128 + 8 * BT);
  int* lists  = (int*)(ws + 128 + 12 * BT);

  const size_t MB = 1024 * 1024;
  unsigned short* xb  = (unsigned short*)(ws + 1 * MB);
  unsigned short* w1t = (unsigned short*)(ws + 33 * MB);
  unsigned short* w2t = (unsigned short*)(ws + 97 * MB);
  unsigned short* Hf  = (unsigned short*)(ws + 161 * MB);
  bool fast = ws_size >= 242 * MB;

  zero_meta_kernel<<<1, 64, 0, stream>>>(counts);
  if (fast) {
    prep_kernel<<<256 + 2048, 256, 0, stream>>>(x, Wg, e, v, counts, xb, flags, W1, w1t);
    select_kernel<<<NEXP, 256, 0, stream>>>(e, v, counts, m_sel, lists, flags);
    ffn1_fast<<<NEXP * 10 * 16 + 2048, 256, 0, stream>>>(xb, w1t, b1, m_sel, lists, Hf, W2, w2t);
    ffn2_fast<<<NEXP * 10 * 8, 256, 0, stream>>>(Hf, w2t, b2, m_sel, lists, out);
  } else {
    unsigned short* Hs = (unsigned short*)(ws + 1 * MB);
    gate_kernel<<<BT / 64, 256, 0, stream>>>(x, Wg, e, v, counts, (unsigned short*)nullptr, flags);
    select_kernel<<<NEXP, 256, 0, stream>>>(e, v, counts, m_sel, lists, flags);
    ffn1_slow<<<dim3(HDIM / 128, CAP / 128, NEXP), 256, 0, stream>>>(x, W1, b1, m_sel, lists, Hs);
    ffn2_slow<<<dim3(DDIM / 128, CAP / 128, NEXP), 256, 0, stream>>>(Hs, W2, b2, m_sel, lists, out);
  }
  passthrough_kernel<<<BT / 16, 256, 0, stream>>>(x, flags, out);
}

// Round 18
// 389.498 us; speedup vs baseline: 1.0264x; 1.0261x over previous
//
#include <hip/hip_runtime.h>
#include <hip/hip_bf16.h>
#include <math.h>

#define BT 16384
#define DDIM 1024
#define NEXP 16
#define HDIM 2048
#define CAP 1280
#define APITCH 72

typedef __bf16 bf16x8 __attribute__((ext_vector_type(8)));
typedef float f32x4 __attribute__((ext_vector_type(4)));

__device__ __forceinline__ unsigned short f2bf(float f) {
  unsigned u = __float_as_uint(f);
  u += 0x7FFFu + ((u >> 16) & 1u);
  return (unsigned short)(u >> 16);
}

// HW packed fp32->bf16 (RNE, identical to f2bf): dst.lo=cvt(a), dst.hi=cvt(b)
__device__ __forceinline__ unsigned cvt_pk_bf16(float a, float b) {
  unsigned r;
  asm("v_cvt_pk_bf16_f32 %0, %1, %2" : "=v"(r) : "v"(a), "v"(b));
  return r;
}

// gelu(tanh approx) == v * sigmoid(2z); hardware v_exp_f32 path.
__device__ __forceinline__ float fast_gelu(float v) {
  float z = 0.7978845608028654f * (v + 0.044715f * v * v * v);
  return v / (1.0f + __expf(-2.0f * z));
}

#define GLD16(g, l)                                                        \
  __builtin_amdgcn_global_load_lds(                                        \
      (const __attribute__((address_space(1))) unsigned int*)(g),          \
      (__attribute__((address_space(3))) unsigned int*)(l), 16, 0, 0)

// Raw barrier without the vmcnt(0) drain __syncthreads would emit.
#define RAW_BARRIER()                          \
  {                                            \
    __builtin_amdgcn_sched_barrier(0);         \
    __builtin_amdgcn_s_barrier();              \
    __builtin_amdgcn_sched_barrier(0);         \
  }

__global__ void zero_meta_kernel(int* p) {
  int i = threadIdx.x;
  if (i < 32) p[i] = 0;  // counts[16] + m_sel[16]
}

// ======== fused prep (R15 configuration — session best 389.6us) ============
// blocks [0,256) = gate (streamed Wg chunks, 30KB LDS);
// blocks [256,..) = W1/W2 transpose+cvt into TILED layout.
// Weights stored as 64x64 bf16 tiles (8KB, [col][row] within tile):
//   w1t: expert n, tile (i_h, i_d) at (n*512 + i_h*16 + i_d)*8192 bytes
//   w2t: expert n, tile (i_d, i_h) at (n*512 + i_d*32 + i_h)*8192 bytes
__global__ __launch_bounds__(256) void prep_kernel(
    const float* __restrict__ x, const float* __restrict__ Wg,
    int* __restrict__ e, float* __restrict__ v, int* __restrict__ counts,
    unsigned short* __restrict__ xb, int* __restrict__ flags,
    const float* __restrict__ W1, const float* __restrict__ W2,
    unsigned short* __restrict__ w1t, unsigned short* __restrict__ w2t) {
  __shared__ __align__(16) char smem[30016];
  int bid = blockIdx.x;
  int tid = threadIdx.x;
  if (bid < 256) {
    // ---------------- gate: 64 tokens/block ----------------
    float* xt = (float*)smem;                       // [64][68]  17408B
    double* lg = (double*)(smem + 17408);           // [64][16]   8192B
    float* wgt_c = (float*)(smem + 25600);          // [16][68]   4352B
    int* hcnt = (int*)(smem + 29952);               // [16]
    int t0 = bid * 64;
    if (tid < NEXP) hcnt[tid] = 0;
    if (tid < 64) flags[t0 + tid] = 0;
    int t = tid & 63, g = tid >> 6;
    double acc[4] = {0.0, 0.0, 0.0, 0.0};
    int sr = tid >> 4;
    int sc = (tid & 15) * 4;
    int wd = tid >> 2, wn = (tid & 3) * 4;
    for (int ch = 0; ch < 16; ++ch) {
      __syncthreads();
#pragma unroll
      for (int i = 0; i < 4; ++i) {
        int r = sr + i * 16;
        float4 xv = *(const float4*)(x + (size_t)(t0 + r) * DDIM + ch * 64 + sc);
        xt[r * 68 + sc + 0] = xv.x; xt[r * 68 + sc + 1] = xv.y;
        xt[r * 68 + sc + 2] = xv.z; xt[r * 68 + sc + 3] = xv.w;
        unsigned p0 = cvt_pk_bf16(xv.x, xv.y);
        unsigned p1 = cvt_pk_bf16(xv.z, xv.w);
        *(uint2*)(xb + (size_t)(t0 + r) * DDIM + ch * 64 + sc) = make_uint2(p0, p1);
      }
      {
        float4 w = *(const float4*)(Wg + ch * 1024 + tid * 4);
        wgt_c[(wn + 0) * 68 + wd] = w.x;
        wgt_c[(wn + 1) * 68 + wd] = w.y;
        wgt_c[(wn + 2) * 68 + wd] = w.z;
        wgt_c[(wn + 3) * 68 + wd] = w.w;
      }
      __syncthreads();
#pragma unroll
      for (int d4 = 0; d4 < 16; ++d4) {
        float4 xv = *(const float4*)(&xt[t * 68 + d4 * 4]);
#pragma unroll
        for (int j = 0; j < 4; ++j) {
          float4 wv = *(const float4*)(&wgt_c[(4 * g + j) * 68 + d4 * 4]);
          acc[j] += (double)xv.x * (double)wv.x + (double)xv.y * (double)wv.y +
                    (double)xv.z * (double)wv.z + (double)xv.w * (double)wv.w;
        }
      }
    }
#pragma unroll
    for (int j = 0; j < 4; ++j) lg[t * 16 + 4 * g + j] = acc[j];
    __syncthreads();
    if (tid < 64) {
      double mx = lg[tid * 16]; int bi = 0;
#pragma unroll
      for (int n = 1; n < NEXP; ++n)
        if (lg[tid * 16 + n] > mx) { mx = lg[tid * 16 + n]; bi = n; }
      double s = 0.0;
#pragma unroll
      for (int n = 0; n < NEXP; ++n) s += exp(lg[tid * 16 + n] - mx);
      e[t0 + tid] = bi;
      v[t0 + tid] = (float)(1.0 / s);
      atomicAdd(&hcnt[bi], 1);
    }
    __syncthreads();
    if (tid < NEXP && hcnt[tid] > 0) atomicAdd(&counts[tid], hcnt[tid]);
    return;
  }
  // ---------------- transpose + fp32->bf16 into tiled layout ----------------
  float* tile = (float*)smem;  // [64][65]
  int b = bid - 256;
  const float* in;
  unsigned short* outp;
  int C, n, bx, by;
  size_t tile_off;
  if (b < 8192) {  // W1 [n][1024][2048]: bx = i_h (0..31), by = i_d (0..15)
    in = W1; outp = w1t; C = HDIM;
    n = b >> 9; int rem = b & 511; by = rem >> 5; bx = rem & 31;
    tile_off = ((size_t)n * 512 + (size_t)bx * 16 + by) * 8192;
  } else {         // W2 [n][2048][1024]: bx = i_d (0..15), by = i_h (0..31)
    b -= 8192;
    in = W2; outp = w2t; C = DDIM;
    n = b >> 9; int rem = b & 511; by = rem >> 4; bx = rem & 15;
    tile_off = ((size_t)n * 512 + (size_t)bx * 32 + by) * 8192;
  }
  const float* src = in + (size_t)n * DDIM * HDIM;
  int r0 = by * 64, c0 = bx * 64;
  int lr = tid >> 2, lq = tid & 3;
#pragma unroll
  for (int i = 0; i < 4; ++i) {
    float4 vv = *(const float4*)(src + (size_t)(r0 + lr) * C + c0 + i * 16 + lq * 4);
    *(float4*)(&tile[lr * 65 + i * 16 + lq * 4]) = vv;
  }
  __syncthreads();
  char* dstT = (char*)outp + tile_off;
  int oc2 = tid >> 3, lq2 = tid & 7;
#pragma unroll
  for (int p = 0; p < 2; ++p) {
    int oc = p * 32 + oc2;
    int rb = lq2 * 8;
    uint4 pk;
    pk.x = cvt_pk_bf16(tile[(rb + 0) * 65 + oc], tile[(rb + 1) * 65 + oc]);
    pk.y = cvt_pk_bf16(tile[(rb + 2) * 65 + oc], tile[(rb + 3) * 65 + oc]);
    pk.z = cvt_pk_bf16(tile[(rb + 4) * 65 + oc], tile[(rb + 5) * 65 + oc]);
    pk.w = cvt_pk_bf16(tile[(rb + 6) * 65 + oc], tile[(rb + 7) * 65 + oc]);
    *(uint4*)(dstT + p * 4096 + tid * 16) = pk;
  }
}

// ---------------- select: per-expert token set under capacity ---------------
__global__ void select_kernel(const int* __restrict__ e, const float* __restrict__ v,
                              const int* __restrict__ counts, int* __restrict__ m_sel,
                              int* __restrict__ lists, int* __restrict__ flags) {
  int n = blockIdx.x;
  int tid = threadIdx.x;
  int cnt = counts[n];
  __shared__ int pos;
  if (tid == 0) pos = 0;
  __syncthreads();
  if (cnt <= CAP) {
    for (int t = tid; t < BT; t += 256) {
      if (e[t] == n) {
        int p = atomicAdd(&pos, 1);
        lists[n * CAP + p] = t;
        flags[t] = 1;
      }
    }
    __syncthreads();
    if (tid == 0) m_sel[n] = pos;
  } else {
    __shared__ int scnt;
    unsigned lo = 0u, hi = 0x7F800000u;
    while (hi - lo > 1u) {
      unsigned mid = lo + ((hi - lo) >> 1);
      if (tid == 0) scnt = 0;
      __syncthreads();
      int c = 0;
      for (int t = tid; t < BT; t += 256)
        if (e[t] == n && __float_as_uint(v[t]) >= mid) c++;
      atomicAdd(&scnt, c);
      __syncthreads();
      int tot = scnt;
      __syncthreads();
      if (tot >= CAP) lo = mid; else hi = mid;
    }
    for (int t = tid; t < BT; t += 256) {
      if (e[t] == n && __float_as_uint(v[t]) > lo) {
        int p = atomicAdd(&pos, 1);
        lists[n * CAP + p] = t;
        flags[t] = 1;
      }
    }
    __syncthreads();
    if (tid == 0) {
      int p = pos;
      for (int t = 0; t < BT && p < CAP; ++t) {
        if (e[t] == n && __float_as_uint(v[t]) == lo) {
          lists[n * CAP + p] = t; flags[t] = 1; ++p;
        }
      }
      m_sel[n] = p;
    }
  }
}

// ---------------- gate (slow path only, resident Wg table) ------------------
__global__ __launch_bounds__(256) void gate_kernel(
    const float* __restrict__ x, const float* __restrict__ Wg,
    int* __restrict__ e, float* __restrict__ v, int* __restrict__ counts,
    unsigned short* __restrict__ xb, int* __restrict__ flags) {
  __shared__ float wgt[NEXP][DDIM];
  __shared__ float xt[64][68];
  __shared__ double lg[64][NEXP];
  __shared__ int hcnt[NEXP];
  int tid = threadIdx.x;
  int t0 = blockIdx.x * 64;
  if (tid < NEXP) hcnt[tid] = 0;
  if (tid < 64) flags[t0 + tid] = 0;
  for (int i = tid; i < DDIM * NEXP / 4; i += 256) {
    int idx = i * 4;
    int d = idx >> 4, n = idx & 15;
    float4 w = *(const float4*)(Wg + idx);
    wgt[n + 0][d] = w.x; wgt[n + 1][d] = w.y;
    wgt[n + 2][d] = w.z; wgt[n + 3][d] = w.w;
  }
  int t = tid & 63, g = tid >> 6;
  double acc[4] = {0.0, 0.0, 0.0, 0.0};
  int sr = tid >> 4;
  int sc = (tid & 15) * 4;
  for (int ch = 0; ch < 16; ++ch) {
    __syncthreads();
#pragma unroll
    for (int i = 0; i < 4; ++i) {
      int r = sr + i * 16;
      float4 xv = *(const float4*)(x + (size_t)(t0 + r) * DDIM + ch * 64 + sc);
      xt[r][sc + 0] = xv.x; xt[r][sc + 1] = xv.y;
      xt[r][sc + 2] = xv.z; xt[r][sc + 3] = xv.w;
      if (xb) {
        unsigned p0 = cvt_pk_bf16(xv.x, xv.y);
        unsigned p1 = cvt_pk_bf16(xv.z, xv.w);
        *(uint2*)(xb + (size_t)(t0 + r) * DDIM + ch * 64 + sc) = make_uint2(p0, p1);
      }
    }
    __syncthreads();
#pragma unroll
    for (int d4 = 0; d4 < 16; ++d4) {
      float4 xv = *(const float4*)(&xt[t][d4 * 4]);
#pragma unroll
      for (int j = 0; j < 4; ++j) {
        float4 wv = *(const float4*)(&wgt[4 * g + j][ch * 64 + d4 * 4]);
        acc[j] += (double)xv.x * (double)wv.x + (double)xv.y * (double)wv.y +
                  (double)xv.z * (double)wv.z + (double)xv.w * (double)wv.w;
      }
    }
  }
#pragma unroll
  for (int j = 0; j < 4; ++j) lg[t][4 * g + j] = acc[j];
  __syncthreads();
  if (tid < 64) {
    double mx = lg[tid][0]; int bi = 0;
#pragma unroll
    for (int n = 1; n < NEXP; ++n)
      if (lg[tid][n] > mx) { mx = lg[tid][n]; bi = n; }
    double s = 0.0;
#pragma unroll
    for (int n = 0; n < NEXP; ++n) s += exp(lg[tid][n] - mx);
    e[t0 + tid] = bi;
    v[t0 + tid] = (float)(1.0 / s);
    atomicAdd(&hcnt[bi], 1);
  }
  __syncthreads();
  if (tid < NEXP && hcnt[tid] > 0) atomicAdd(&counts[tid], hcnt[tid]);
}

// ======================= FAST PATH (bf16 pre-converted) =====================
// R12 FFN structure (local optimum across R8/R10/R13 ablations): 128x128
// tile, BK=64, double-buffered, counted vmcnt, reg-prefetch within iter:
// { vmcnt(8); BAR; ds_read all frags; lgkmcnt(0); BAR; stage(t+2);
//   setprio(1); 32 MFMA; setprio(0) }. VGPR 92 -> 5 waves/SIMD.
// B-panels from TILED weights: byte = tile*8192 + (row&63)*128 + g*16.

__global__ __launch_bounds__(256) void ffn1_fast(
    const unsigned short* __restrict__ xb, const unsigned short* __restrict__ w1t,
    const float* __restrict__ b1, const int* __restrict__ m_sel,
    const int* __restrict__ lists, unsigned short* __restrict__ H) {
  __shared__ __align__(16) unsigned short As[2][128 * 64];
  __shared__ __align__(16) unsigned short Bs[2][128 * 64];
  const int NWG = NEXP * 10 * 16;  // 2560
  const int NT = DDIM / 64;        // 16
  int bid = blockIdx.x;
  int lid = (bid & 7) * (NWG / 8) + (bid >> 3);
  int n = lid / 160;
  int rem = lid - n * 160;
  int mt = rem >> 4, ht = rem & 15;
  int M = m_sel[n];
  if (mt * 128 >= M) return;
  int tid = threadIdx.x;
  int lane = tid & 63, wid = tid >> 6;
  int wr = (wid >> 1) * 64, wc = (wid & 1) * 64;
  int rbase = tid >> 3;
  int c16 = tid & 7;
  const char* xbase = (const char*)xb;
  const char* bbase = (const char*)w1t + (size_t)n * (DDIM * HDIM * 2);
  unsigned asrc[4], bsrc[4], ldsoff[4];
#pragma unroll
  for (int j = 0; j < 4; ++j) {
    int row = j * 32 + rbase;
    int g = c16 ^ (row & 7);
    int s = mt * 128 + row;
    int tok = lists[n * CAP + (s < M ? s : 0)];
    asrc[j] = (unsigned)tok * 2048u + g * 16;
    bsrc[j] = (unsigned)((ht * 2 + (row >> 6)) * 16) * 8192u +
              (unsigned)(row & 63) * 128u + g * 16;
    ldsoff[j] = j * 4096 + wid * 1024;
  }
  unsigned aoff[2][4], boff[2][4];
#pragma unroll
  for (int kk = 0; kk < 2; ++kk) {
#pragma unroll
    for (int mi = 0; mi < 4; ++mi) {
      int row = wr + mi * 16 + (lane & 15);
      aoff[kk][mi] = row * 128 + (((kk * 4 + (lane >> 4)) ^ (row & 7)) * 16);
    }
#pragma unroll
    for (int ni = 0; ni < 4; ++ni) {
      int row = wc + ni * 16 + (lane & 15);
      boff[kk][ni] = row * 128 + (((kk * 4 + (lane >> 4)) ^ (row & 7)) * 16);
    }
  }
  f32x4 acc[4][4] = {};
#define STAGE1(buf, kt)                                                     \
  {                                                                         \
    unsigned koa = (unsigned)(kt) * 128u;                                   \
    unsigned kob = (unsigned)(kt) * 8192u;                                  \
    _Pragma("unroll") for (int j = 0; j < 4; ++j) {                         \
      GLD16(xbase + (size_t)(asrc[j] + koa), (char*)As[buf] + ldsoff[j]);   \
      GLD16(bbase + (size_t)(bsrc[j] + kob), (char*)Bs[buf] + ldsoff[j]);   \
    }                                                                       \
  }
  STAGE1(0, 0);
  STAGE1(1, 1);
  int cur = 0;
  for (int kt = 0; kt < NT; ++kt) {
    if (kt < NT - 1) asm volatile("s_waitcnt vmcnt(8)" ::: "memory");
    else             asm volatile("s_waitcnt vmcnt(0)" ::: "memory");
    RAW_BARRIER();
    bf16x8 af[2][4], bfv[2][4];
#pragma unroll
    for (int kk = 0; kk < 2; ++kk) {
#pragma unroll
      for (int mi = 0; mi < 4; ++mi)
        af[kk][mi] = *(const bf16x8*)((const char*)As[cur] + aoff[kk][mi]);
#pragma unroll
      for (int ni = 0; ni < 4; ++ni)
        bfv[kk][ni] = *(const bf16x8*)((const char*)Bs[cur] + boff[kk][ni]);
    }
    asm volatile("s_waitcnt lgkmcnt(0)" ::: "memory");
    RAW_BARRIER();
    if (kt + 2 < NT) STAGE1(cur, kt + 2);
    __builtin_amdgcn_s_setprio(1);
#pragma unroll
    for (int kk = 0; kk < 2; ++kk)
#pragma unroll
      for (int mi = 0; mi < 4; ++mi)
#pragma unroll
        for (int ni = 0; ni < 4; ++ni)
          acc[mi][ni] = __builtin_amdgcn_mfma_f32_16x16x32_bf16(af[kk][mi], bfv[kk][ni], acc[mi][ni], 0, 0, 0);
    __builtin_amdgcn_s_setprio(0);
    cur ^= 1;
  }
  int rq = (lane >> 4) * 4;
#pragma unroll
  for (int ni = 0; ni < 4; ++ni) {
    int h = ht * 128 + wc + ni * 16 + (lane & 15);
    float bias = b1[n * HDIM + h];
#pragma unroll
    for (int mi = 0; mi < 4; ++mi) {
#pragma unroll
      for (int q = 0; q < 4; ++q) {
        int lr = wr + mi * 16 + rq + q;
        float val = acc[mi][ni][q] + bias;
        H[((size_t)n * CAP + mt * 128 + lr) * HDIM + h] = f2bf(fast_gelu(val));
      }
    }
  }
}

__global__ __launch_bounds__(256) void ffn2_fast(
    const unsigned short* __restrict__ H, const unsigned short* __restrict__ w2t,
    const float* __restrict__ b2, const int* __restrict__ m_sel,
    const int* __restrict__ lists, float* __restrict__ out) {
  __shared__ __align__(16) unsigned short As[2][128 * 64];
  __shared__ __align__(16) unsigned short Bs[2][128 * 64];
  const int NWG = NEXP * 10 * 8;  // 1280
  const int NT = HDIM / 64;       // 32
  int bid = blockIdx.x;
  int tid = threadIdx.x;
  int lid = (bid & 7) * (NWG / 8) + (bid >> 3);
  int n = lid / 80;
  int rem = lid - n * 80;
  int mt = rem >> 3, dt = rem & 7;
  int M = m_sel[n];
  if (mt * 128 >= M) return;
  int lane = tid & 63, wid = tid >> 6;
  int wr = (wid >> 1) * 64, wc = (wid & 1) * 64;
  int rbase = tid >> 3;
  int c16 = tid & 7;
  const char* abase = (const char*)H + (((size_t)n * CAP + (size_t)mt * 128) * HDIM) * 2;
  const char* bbase = (const char*)w2t + (size_t)n * (DDIM * HDIM * 2);
  unsigned asrc[4], bsrc[4], ldsoff[4];
#pragma unroll
  for (int j = 0; j < 4; ++j) {
    int row = j * 32 + rbase;
    int g = c16 ^ (row & 7);
    asrc[j] = (unsigned)row * 4096u + g * 16;
    bsrc[j] = (unsigned)((dt * 2 + (row >> 6)) * 32) * 8192u +
              (unsigned)(row & 63) * 128u + g * 16;
    ldsoff[j] = j * 4096 + wid * 1024;
  }
  unsigned aoff[2][4], boff[2][4];
#pragma unroll
  for (int kk = 0; kk < 2; ++kk) {
#pragma unroll
    for (int mi = 0; mi < 4; ++mi) {
      int row = wr + mi * 16 + (lane & 15);
      aoff[kk][mi] = row * 128 + (((kk * 4 + (lane >> 4)) ^ (row & 7)) * 16);
    }
#pragma unroll
    for (int ni = 0; ni < 4; ++ni) {
      int row = wc + ni * 16 + (lane & 15);
      boff[kk][ni] = row * 128 + (((kk * 4 + (lane >> 4)) ^ (row & 7)) * 16);
    }
  }
  f32x4 acc[4][4] = {};
#define STAGE2(buf, kt)                                                     \
  {                                                                         \
    unsigned koa = (unsigned)(kt) * 128u;                                   \
    unsigned kob = (unsigned)(kt) * 8192u;                                  \
    _Pragma("unroll") for (int j = 0; j < 4; ++j) {                         \
      GLD16(abase + (size_t)(asrc[j] + koa), (char*)As[buf] + ldsoff[j]);   \
      GLD16(bbase + (size_t)(bsrc[j] + kob), (char*)Bs[buf] + ldsoff[j]);   \
    }                                                                       \
  }
  STAGE2(0, 0);
  STAGE2(1, 1);
  int cur = 0;
  for (int kt = 0; kt < NT; ++kt) {
    if (kt < NT - 1) asm volatile("s_waitcnt vmcnt(8)" ::: "memory");
    else             asm volatile("s_waitcnt vmcnt(0)" ::: "memory");
    RAW_BARRIER();
    bf16x8 af[2][4], bfv[2][4];
#pragma unroll
    for (int kk = 0; kk < 2; ++kk) {
#pragma unroll
      for (int mi = 0; mi < 4; ++mi)
        af[kk][mi] = *(const bf16x8*)((const char*)As[cur] + aoff[kk][mi]);
#pragma unroll
      for (int ni = 0; ni < 4; ++ni)
        bfv[kk][ni] = *(const bf16x8*)((const char*)Bs[cur] + boff[kk][ni]);
    }
    asm volatile("s_waitcnt lgkmcnt(0)" ::: "memory");
    RAW_BARRIER();
    if (kt + 2 < NT) STAGE2(cur, kt + 2);
    __builtin_amdgcn_s_setprio(1);
#pragma unroll
    for (int kk = 0; kk < 2; ++kk)
#pragma unroll
      for (int mi = 0; mi < 4; ++mi)
#pragma unroll
        for (int ni = 0; ni < 4; ++ni)
          acc[mi][ni] = __builtin_amdgcn_mfma_f32_16x16x32_bf16(af[kk][mi], bfv[kk][ni], acc[mi][ni], 0, 0, 0);
    __builtin_amdgcn_s_setprio(0);
    cur ^= 1;
  }
  int rq = (lane >> 4) * 4;
  float bias[4];
#pragma unroll
  for (int ni = 0; ni < 4; ++ni)
    bias[ni] = b2[n * DDIM + dt * 128 + wc + ni * 16 + (lane & 15)];
#pragma unroll
  for (int mi = 0; mi < 4; ++mi) {
#pragma unroll
    for (int q = 0; q < 4; ++q) {
      int lr = wr + mi * 16 + rq + q;
      int s = mt * 128 + lr;
      if (s < M) {
        int tok = lists[n * CAP + s];
#pragma unroll
        for (int ni = 0; ni < 4; ++ni) {
          int dcol = dt * 128 + wc + ni * 16 + (lane & 15);
          out[(size_t)tok * DDIM + dcol] = acc[mi][ni][q] + bias[ni];
        }
      }
    }
  }
}

// ======================= SLOW PATH (ws fallback) ============================
__global__ __launch_bounds__(256) void ffn1_slow(
    const float* __restrict__ x, const float* __restrict__ W1, const float* __restrict__ b1,
    const int* __restrict__ m_sel, const int* __restrict__ lists,
    unsigned short* __restrict__ H) {
  __shared__ unsigned short Al[128 * APITCH];
  __shared__ unsigned short Bl[128 * APITCH];
  __shared__ int rows[128];
  int n = blockIdx.z, mt = blockIdx.y, ht = blockIdx.x;
  int M = m_sel[n];
  if (mt * 128 >= M) return;
  int tid = threadIdx.x;
  if (tid < 128) {
    int s = mt * 128 + tid;
    rows[tid] = lists[n * CAP + (s < M ? s : 0)];
  }
  __syncthreads();
  f32x4 acc[4][4] = {};
  int lane = tid & 63;
  int wid = tid >> 6;
  int wr = (wid >> 1) * 64, wc = (wid & 1) * 64;
  int ar = tid >> 4, ac = (tid & 15) * 4;
  int bh = tid & 127, bk8 = (tid >> 7) * 8;
  const size_t w1base = (size_t)n * DDIM * HDIM + (size_t)ht * 128;
  for (int kt = 0; kt < DDIM / 64; ++kt) {
#pragma unroll
    for (int i = 0; i < 8; ++i) {
      int r = ar + i * 16;
      float4 xv = *(const float4*)(x + (size_t)rows[r] * DDIM + kt * 64 + ac);
      unsigned plo = (unsigned)f2bf(xv.x) | ((unsigned)f2bf(xv.y) << 16);
      unsigned phi = (unsigned)f2bf(xv.z) | ((unsigned)f2bf(xv.w) << 16);
      *(uint2*)(&Al[r * APITCH + ac]) = make_uint2(plo, phi);
    }
#pragma unroll
    for (int i = 0; i < 4; ++i) {
      int k0 = bk8 + i * 16;
      const float* wp = W1 + w1base + (size_t)(kt * 64 + k0) * HDIM + bh;
      uint4 pk;
      pk.x = (unsigned)f2bf(wp[0]) | ((unsigned)f2bf(wp[HDIM]) << 16);
      pk.y = (unsigned)f2bf(wp[2 * HDIM]) | ((unsigned)f2bf(wp[3 * HDIM]) << 16);
      pk.z = (unsigned)f2bf(wp[4 * HDIM]) | ((unsigned)f2bf(wp[5 * HDIM]) << 16);
      pk.w = (unsigned)f2bf(wp[6 * HDIM]) | ((unsigned)f2bf(wp[7 * HDIM]) << 16);
      *(uint4*)(&Bl[bh * APITCH + k0]) = pk;
    }
    __syncthreads();
#pragma unroll
    for (int kk = 0; kk < 2; ++kk) {
      bf16x8 af[4], bfr[4];
#pragma unroll
      for (int mi = 0; mi < 4; ++mi)
        af[mi] = *(const bf16x8*)(&Al[(wr + mi * 16 + (lane & 15)) * APITCH + kk * 32 + (lane >> 4) * 8]);
#pragma unroll
      for (int ni = 0; ni < 4; ++ni)
        bfr[ni] = *(const bf16x8*)(&Bl[(wc + ni * 16 + (lane & 15)) * APITCH + kk * 32 + (lane >> 4) * 8]);
#pragma unroll
      for (int mi = 0; mi < 4; ++mi)
#pragma unroll
        for (int ni = 0; ni < 4; ++ni)
          acc[mi][ni] = __builtin_amdgcn_mfma_f32_16x16x32_bf16(af[mi], bfr[ni], acc[mi][ni], 0, 0, 0);
    }
    __syncthreads();
  }
  int rq = (lane >> 4) * 4;
#pragma unroll
  for (int ni = 0; ni < 4; ++ni) {
    int h = ht * 128 + wc + ni * 16 + (lane & 15);
    float bias = b1[n * HDIM + h];
#pragma unroll
    for (int mi = 0; mi < 4; ++mi) {
#pragma unroll
      for (int q = 0; q < 4; ++q) {
        int lr = wr + mi * 16 + rq + q;
        float val = acc[mi][ni][q] + bias;
        H[((size_t)n * CAP + mt * 128 + lr) * HDIM + h] = f2bf(fast_gelu(val));
      }
    }
  }
}

__global__ __launch_bounds__(256) void ffn2_slow(
    const unsigned short* __restrict__ H, const float* __restrict__ W2, const float* __restrict__ b2,
    const int* __restrict__ m_sel, const int* __restrict__ lists,
    float* __restrict__ out) {
  __shared__ unsigned short Al[128 * APITCH];
  __shared__ unsigned short Bl[128 * APITCH];
  __shared__ int rows[128];
  int n = blockIdx.z, mt = blockIdx.y, dt = blockIdx.x;
  int M = m_sel[n];
  if (mt * 128 >= M) return;
  int tid = threadIdx.x;
  if (tid < 128) {
    int s = mt * 128 + tid;
    rows[tid] = lists[n * CAP + (s < M ? s : 0)];
  }
  __syncthreads();
  f32x4 acc[4][4] = {};
  int lane = tid & 63;
  int wid = tid >> 6;
  int wr = (wid >> 1) * 64, wc = (wid & 1) * 64;
  int ar2 = tid >> 1, ak8 = (tid & 1) * 8;
  int bh = tid & 127, bk8 = (tid >> 7) * 8;
  const size_t hbase = ((size_t)n * CAP + (size_t)mt * 128) * HDIM;
  const size_t w2base = (size_t)n * HDIM * DDIM + (size_t)dt * 128;
  for (int kt = 0; kt < HDIM / 64; ++kt) {
#pragma unroll
    for (int i = 0; i < 4; ++i) {
      int k0 = ak8 + i * 16;
      uint4 hv = *(const uint4*)(H + hbase + (size_t)ar2 * HDIM + kt * 64 + k0);
      *(uint4*)(&Al[ar2 * APITCH + k0]) = hv;
    }
#pragma unroll
    for (int i = 0; i < 4; ++i) {
      int k0 = bk8 + i * 16;
      const float* wp = W2 + w2base + (size_t)(kt * 64 + k0) * DDIM + bh;
      uint4 pk;
      pk.x = (unsigned)f2bf(wp[0]) | ((unsigned)f2bf(wp[DDIM]) << 16);
      pk.y = (unsigned)f2bf(wp[2 * DDIM]) | ((unsigned)f2bf(wp[3 * DDIM]) << 16);
      pk.z = (unsigned)f2bf(wp[4 * DDIM]) | ((unsigned)f2bf(wp[5 * DDIM]) << 16);
      pk.w = (unsigned)f2bf(wp[6 * DDIM]) | ((unsigned)f2bf(wp[7 * DDIM]) << 16);
      *(uint4*)(&Bl[bh * APITCH + k0]) = pk;
    }
    __syncthreads();
#pragma unroll
    for (int kk = 0; kk < 2; ++kk) {
      bf16x8 af[4], bfr[4];
#pragma unroll
      for (int mi = 0; mi < 4; ++mi)
        af[mi] = *(const bf16x8*)(&Al[(wr + mi * 16 + (lane & 15)) * APITCH + kk * 32 + (lane >> 4) * 8]);
#pragma unroll
      for (int ni = 0; ni < 4; ++ni)
        bfr[ni] = *(const bf16x8*)(&Bl[(wc + ni * 16 + (lane & 15)) * APITCH + kk * 32 + (lane >> 4) * 8]);
#pragma unroll
      for (int mi = 0; mi < 4; ++mi)
#pragma unroll
        for (int ni = 0; ni < 4; ++ni)
          acc[mi][ni] = __builtin_amdgcn_mfma_f32_16x16x32_bf16(af[mi], bfr[ni], acc[mi][ni], 0, 0, 0);
    }
    __syncthreads();
  }
  int rq = (lane >> 4) * 4;
#pragma unroll
  for (int mi = 0; mi < 4; ++mi) {
#pragma unroll
    for (int q = 0; q < 4; ++q) {
      int lr = wr + mi * 16 + rq + q;
      int s = mt * 128 + lr;
      if (s < M) {
        int tok = rows[lr];
#pragma unroll
        for (int ni = 0; ni < 4; ++ni) {
          int dcol = dt * 128 + wc + ni * 16 + (lane & 15);
          out[(size_t)tok * DDIM + dcol] = acc[mi][ni][q] + b2[n * DDIM + dcol];
        }
      }
    }
  }
}

// ---------------- passthrough: one wave per row, 1024 blocks ----------------
__global__ __launch_bounds__(256) void passthrough_kernel(
    const float* __restrict__ x, const int* __restrict__ flags,
    float* __restrict__ out) {
  int lane = threadIdx.x & 63;
  int w = threadIdx.x >> 6;
  int base = blockIdx.x * 16;
  for (int r = base + w; r < base + 16; r += 4) {
    if (flags[r]) continue;
    const float4* s = (const float4*)(x + (size_t)r * DDIM);
    float4* d = (float4*)(out + (size_t)r * DDIM);
#pragma unroll
    for (int i = 0; i < 4; ++i) d[lane + i * 64] = s[lane + i * 64];
  }
}

extern "C" void kernel_launch(void* const* d_in, const int* in_sizes, int n_in,
                              void* d_out, int out_size, void* d_ws, size_t ws_size,
                              hipStream_t stream) {
  const float* x  = (const float*)d_in[0];
  const float* Wg = (const float*)d_in[1];
  const float* W1 = (const float*)d_in[2];
  const float* b1 = (const float*)d_in[3];
  const float* W2 = (const float*)d_in[4];
  const float* b2 = (const float*)d_in[5];
  float* out = (float*)d_out;
  char* ws = (char*)d_ws;
  int* counts = (int*)ws;
  int* m_sel  = (int*)(ws + 64);
  int* flags  = (int*)(ws + 128);
  int* e      = (int*)(ws + 128 + 4 * BT);
  float* v    = (float*)(ws + 128 + 8 * BT);
  int* lists  = (int*)(ws + 128 + 12 * BT);

  const size_t MB = 1024 * 1024;
  unsigned short* xb  = (unsigned short*)(ws + 1 * MB);
  unsigned short* w1t = (unsigned short*)(ws + 33 * MB);
  unsigned short* w2t = (unsigned short*)(ws + 97 * MB);
  unsigned short* Hf  = (unsigned short*)(ws + 161 * MB);
  bool fast = ws_size >= 242 * MB;

  zero_meta_kernel<<<1, 64, 0, stream>>>(counts);
  if (fast) {
    prep_kernel<<<256 + 16384, 256, 0, stream>>>(x, Wg, e, v, counts, xb, flags,
                                                 W1, W2, w1t, w2t);
    select_kernel<<<NEXP, 256, 0, stream>>>(e, v, counts, m_sel, lists, flags);
    ffn1_fast<<<NEXP * 10 * 16, 256, 0, stream>>>(xb, w1t, b1, m_sel, lists, Hf);
    ffn2_fast<<<NEXP * 10 * 8, 256, 0, stream>>>(Hf, w2t, b2, m_sel, lists, out);
  } else {
    unsigned short* Hs = (unsigned short*)(ws + 1 * MB);
    gate_kernel<<<BT / 64, 256, 0, stream>>>(x, Wg, e, v, counts, (unsigned short*)nullptr, flags);
    select_kernel<<<NEXP, 256, 0, stream>>>(e, v, counts, m_sel, lists, flags);
    ffn1_slow<<<dim3(HDIM / 128, CAP / 128, NEXP), 256, 0, stream>>>(x, W1, b1, m_sel, lists, Hs);
    ffn2_slow<<<dim3(DDIM / 128, CAP / 128, NEXP), 256, 0, stream>>>(Hs, W2, b2, m_sel, lists, out);
  }
  passthrough_kernel<<<BT / 16, 256, 0, stream>>>(x, flags, out);
}

// Round 19
// 385.343 us; speedup vs baseline: 1.0374x; 1.0108x over previous
//
#include <hip/hip_runtime.h>
#include <hip/hip_bf16.h>
#include <math.h>

#define BT 16384
#define DDIM 1024
#define NEXP 16
#define HDIM 2048
#define CAP 1280
#define APITCH 72
#define LBP 262  // bf16 LDS slab pitch for in-GEMM transpose tail

typedef __bf16 bf16x8 __attribute__((ext_vector_type(8)));
typedef float f32x4 __attribute__((ext_vector_type(4)));

__device__ __forceinline__ unsigned short f2bf(float f) {
  unsigned u = __float_as_uint(f);
  u += 0x7FFFu + ((u >> 16) & 1u);
  return (unsigned short)(u >> 16);
}

// HW packed fp32->bf16 (RNE, identical to f2bf): dst.lo=cvt(a), dst.hi=cvt(b)
__device__ __forceinline__ unsigned cvt_pk_bf16(float a, float b) {
  unsigned r;
  asm("v_cvt_pk_bf16_f32 %0, %1, %2" : "=v"(r) : "v"(a), "v"(b));
  return r;
}

// gelu(tanh approx) == v * sigmoid(2z); hardware v_exp_f32 path.
__device__ __forceinline__ float fast_gelu(float v) {
  float z = 0.7978845608028654f * (v + 0.044715f * v * v * v);
  return v / (1.0f + __expf(-2.0f * z));
}

#define GLD16(g, l)                                                        \
  __builtin_amdgcn_global_load_lds(                                        \
      (const __attribute__((address_space(1))) unsigned int*)(g),          \
      (__attribute__((address_space(3))) unsigned int*)(l), 16, 0, 0)

// Raw barrier without the vmcnt(0) drain __syncthreads would emit.
#define RAW_BARRIER()                          \
  {                                            \
    __builtin_amdgcn_sched_barrier(0);         \
    __builtin_amdgcn_s_barrier();              \
    __builtin_amdgcn_sched_barrier(0);         \
  }

__global__ void zero_meta_kernel(int* p) {
  int i = threadIdx.x;
  if (i < 32) p[i] = 0;  // counts[16] + m_sel[16]
}

// ---- slab transpose body: 64 rows x 256 cols fp32 -> 4 tiled 64x64 bf16
// tiles ([col][row] inside tile, 8KB each, 2x4KB contiguous bursts) ---------
__device__ __forceinline__ void slab_transpose(
    unsigned short* Lb, const float* src, int C,
    unsigned short* outp, size_t tile_base, int tmul, int by, int bxq, int tid) {
  int w = tid >> 6, lane = tid & 63;
#pragma unroll
  for (int k = 0; k < 16; ++k) {
    int row = w + k * 4;
    float4 vv = *(const float4*)(src + (size_t)row * C + lane * 4);
    unsigned p0 = cvt_pk_bf16(vv.x, vv.y);
    unsigned p1 = cvt_pk_bf16(vv.z, vv.w);
    *(uint2*)(&Lb[row * LBP + lane * 4]) = make_uint2(p0, p1);
  }
  __syncthreads();
  int oc_lo = tid >> 3;
  int rb = (tid & 7) * 8;
#pragma unroll
  for (int p2 = 0; p2 < 4; ++p2) {
    int bx = bxq * 4 + p2;
    char* dstT = (char*)outp + (tile_base + (size_t)bx * tmul + by) * 8192;
#pragma unroll
    for (int p = 0; p < 2; ++p) {
      int oc = p * 32 + oc_lo;
      const unsigned short* col = &Lb[rb * LBP + p2 * 64 + oc];
      unsigned short u[8];
#pragma unroll
      for (int j = 0; j < 8; ++j) u[j] = col[j * LBP];
      uint4 pk;
      pk.x = (unsigned)u[0] | ((unsigned)u[1] << 16);
      pk.y = (unsigned)u[2] | ((unsigned)u[3] << 16);
      pk.z = (unsigned)u[4] | ((unsigned)u[5] << 16);
      pk.w = (unsigned)u[6] | ((unsigned)u[7] << 16);
      *(uint4*)(dstT + p * 4096 + tid * 16) = pk;
    }
  }
}

// ======== fused prep: blocks [0,256) = gate; [256,8448) = W1 tiled transpose
// (R15 per-tile variant: 64x64 per block). W2 moved into ffn1 (scattered).
__global__ __launch_bounds__(256) void prep_kernel(
    const float* __restrict__ x, const float* __restrict__ Wg,
    int* __restrict__ e, float* __restrict__ v, int* __restrict__ counts,
    unsigned short* __restrict__ xb, int* __restrict__ flags,
    const float* __restrict__ W1, unsigned short* __restrict__ w1t) {
  __shared__ __align__(16) char smem[30016];
  int bid = blockIdx.x;
  int tid = threadIdx.x;
  if (bid < 256) {
    // ---------------- gate: 64 tokens/block ----------------
    float* xt = (float*)smem;                       // [64][68]  17408B
    double* lg = (double*)(smem + 17408);           // [64][16]   8192B
    float* wgt_c = (float*)(smem + 25600);          // [16][68]   4352B
    int* hcnt = (int*)(smem + 29952);               // [16]
    int t0 = bid * 64;
    if (tid < NEXP) hcnt[tid] = 0;
    if (tid < 64) flags[t0 + tid] = 0;
    int t = tid & 63, g = tid >> 6;
    double acc[4] = {0.0, 0.0, 0.0, 0.0};
    int sr = tid >> 4;
    int sc = (tid & 15) * 4;
    int wd = tid >> 2, wn = (tid & 3) * 4;
    for (int ch = 0; ch < 16; ++ch) {
      __syncthreads();
#pragma unroll
      for (int i = 0; i < 4; ++i) {
        int r = sr + i * 16;
        float4 xv = *(const float4*)(x + (size_t)(t0 + r) * DDIM + ch * 64 + sc);
        xt[r * 68 + sc + 0] = xv.x; xt[r * 68 + sc + 1] = xv.y;
        xt[r * 68 + sc + 2] = xv.z; xt[r * 68 + sc + 3] = xv.w;
        unsigned p0 = cvt_pk_bf16(xv.x, xv.y);
        unsigned p1 = cvt_pk_bf16(xv.z, xv.w);
        *(uint2*)(xb + (size_t)(t0 + r) * DDIM + ch * 64 + sc) = make_uint2(p0, p1);
      }
      {
        float4 w = *(const float4*)(Wg + ch * 1024 + tid * 4);
        wgt_c[(wn + 0) * 68 + wd] = w.x;
        wgt_c[(wn + 1) * 68 + wd] = w.y;
        wgt_c[(wn + 2) * 68 + wd] = w.z;
        wgt_c[(wn + 3) * 68 + wd] = w.w;
      }
      __syncthreads();
#pragma unroll
      for (int d4 = 0; d4 < 16; ++d4) {
        float4 xv = *(const float4*)(&xt[t * 68 + d4 * 4]);
#pragma unroll
        for (int j = 0; j < 4; ++j) {
          float4 wv = *(const float4*)(&wgt_c[(4 * g + j) * 68 + d4 * 4]);
          acc[j] += (double)xv.x * (double)wv.x + (double)xv.y * (double)wv.y +
                    (double)xv.z * (double)wv.z + (double)xv.w * (double)wv.w;
        }
      }
    }
#pragma unroll
    for (int j = 0; j < 4; ++j) lg[t * 16 + 4 * g + j] = acc[j];
    __syncthreads();
    if (tid < 64) {
      double mx = lg[tid * 16]; int bi = 0;
#pragma unroll
      for (int n = 1; n < NEXP; ++n)
        if (lg[tid * 16 + n] > mx) { mx = lg[tid * 16 + n]; bi = n; }
      double s = 0.0;
#pragma unroll
      for (int n = 0; n < NEXP; ++n) s += exp(lg[tid * 16 + n] - mx);
      e[t0 + tid] = bi;
      v[t0 + tid] = (float)(1.0 / s);
      atomicAdd(&hcnt[bi], 1);
    }
    __syncthreads();
    if (tid < NEXP && hcnt[tid] > 0) atomicAdd(&counts[tid], hcnt[tid]);
    return;
  }
  // ---------------- W1 transpose + fp32->bf16, tiled (R15 body) -------------
  float* tile = (float*)smem;  // [64][65]
  int b = bid - 256;  // 0..8191
  int n = b >> 9; int rem = b & 511; int by = rem >> 5, bx = rem & 31;
  size_t tile_off = ((size_t)n * 512 + (size_t)bx * 16 + by) * 8192;
  const float* src = W1 + (size_t)n * DDIM * HDIM;
  int r0 = by * 64, c0 = bx * 64;
  int lr = tid >> 2, lq = tid & 3;
#pragma unroll
  for (int i = 0; i < 4; ++i) {
    float4 vv = *(const float4*)(src + (size_t)(r0 + lr) * HDIM + c0 + i * 16 + lq * 4);
    *(float4*)(&tile[lr * 65 + i * 16 + lq * 4]) = vv;
  }
  __syncthreads();
  char* dstT = (char*)w1t + tile_off;
  int oc2 = tid >> 3, lq2 = tid & 7;
#pragma unroll
  for (int p = 0; p < 2; ++p) {
    int oc = p * 32 + oc2;
    int rb = lq2 * 8;
    uint4 pk;
    pk.x = cvt_pk_bf16(tile[(rb + 0) * 65 + oc], tile[(rb + 1) * 65 + oc]);
    pk.y = cvt_pk_bf16(tile[(rb + 2) * 65 + oc], tile[(rb + 3) * 65 + oc]);
    pk.z = cvt_pk_bf16(tile[(rb + 4) * 65 + oc], tile[(rb + 5) * 65 + oc]);
    pk.w = cvt_pk_bf16(tile[(rb + 6) * 65 + oc], tile[(rb + 7) * 65 + oc]);
    *(uint4*)(dstT + p * 4096 + tid * 16) = pk;
  }
}

// ---------------- select: per-expert token set under capacity ---------------
__global__ void select_kernel(const int* __restrict__ e, const float* __restrict__ v,
                              const int* __restrict__ counts, int* __restrict__ m_sel,
                              int* __restrict__ lists, int* __restrict__ flags) {
  int n = blockIdx.x;
  int tid = threadIdx.x;
  int cnt = counts[n];
  __shared__ int pos;
  if (tid == 0) pos = 0;
  __syncthreads();
  if (cnt <= CAP) {
    for (int t = tid; t < BT; t += 256) {
      if (e[t] == n) {
        int p = atomicAdd(&pos, 1);
        lists[n * CAP + p] = t;
        flags[t] = 1;
      }
    }
    __syncthreads();
    if (tid == 0) m_sel[n] = pos;
  } else {
    __shared__ int scnt;
    unsigned lo = 0u, hi = 0x7F800000u;
    while (hi - lo > 1u) {
      unsigned mid = lo + ((hi - lo) >> 1);
      if (tid == 0) scnt = 0;
      __syncthreads();
      int c = 0;
      for (int t = tid; t < BT; t += 256)
        if (e[t] == n && __float_as_uint(v[t]) >= mid) c++;
      atomicAdd(&scnt, c);
      __syncthreads();
      int tot = scnt;
      __syncthreads();
      if (tot >= CAP) lo = mid; else hi = mid;
    }
    for (int t = tid; t < BT; t += 256) {
      if (e[t] == n && __float_as_uint(v[t]) > lo) {
        int p = atomicAdd(&pos, 1);
        lists[n * CAP + p] = t;
        flags[t] = 1;
      }
    }
    __syncthreads();
    if (tid == 0) {
      int p = pos;
      for (int t = 0; t < BT && p < CAP; ++t) {
        if (e[t] == n && __float_as_uint(v[t]) == lo) {
          lists[n * CAP + p] = t; flags[t] = 1; ++p;
        }
      }
      m_sel[n] = p;
    }
  }
}

// ---------------- gate (slow path only, resident Wg table) ------------------
__global__ __launch_bounds__(256) void gate_kernel(
    const float* __restrict__ x, const float* __restrict__ Wg,
    int* __restrict__ e, float* __restrict__ v, int* __restrict__ counts,
    unsigned short* __restrict__ xb, int* __restrict__ flags) {
  __shared__ float wgt[NEXP][DDIM];
  __shared__ float xt[64][68];
  __shared__ double lg[64][NEXP];
  __shared__ int hcnt[NEXP];
  int tid = threadIdx.x;
  int t0 = blockIdx.x * 64;
  if (tid < NEXP) hcnt[tid] = 0;
  if (tid < 64) flags[t0 + tid] = 0;
  for (int i = tid; i < DDIM * NEXP / 4; i += 256) {
    int idx = i * 4;
    int d = idx >> 4, n = idx & 15;
    float4 w = *(const float4*)(Wg + idx);
    wgt[n + 0][d] = w.x; wgt[n + 1][d] = w.y;
    wgt[n + 2][d] = w.z; wgt[n + 3][d] = w.w;
  }
  int t = tid & 63, g = tid >> 6;
  double acc[4] = {0.0, 0.0, 0.0, 0.0};
  int sr = tid >> 4;
  int sc = (tid & 15) * 4;
  for (int ch = 0; ch < 16; ++ch) {
    __syncthreads();
#pragma unroll
    for (int i = 0; i < 4; ++i) {
      int r = sr + i * 16;
      float4 xv = *(const float4*)(x + (size_t)(t0 + r) * DDIM + ch * 64 + sc);
      xt[r][sc + 0] = xv.x; xt[r][sc + 1] = xv.y;
      xt[r][sc + 2] = xv.z; xt[r][sc + 3] = xv.w;
      if (xb) {
        unsigned p0 = cvt_pk_bf16(xv.x, xv.y);
        unsigned p1 = cvt_pk_bf16(xv.z, xv.w);
        *(uint2*)(xb + (size_t)(t0 + r) * DDIM + ch * 64 + sc) = make_uint2(p0, p1);
      }
    }
    __syncthreads();
#pragma unroll
    for (int d4 = 0; d4 < 16; ++d4) {
      float4 xv = *(const float4*)(&xt[t][d4 * 4]);
#pragma unroll
      for (int j = 0; j < 4; ++j) {
        float4 wv = *(const float4*)(&wgt[4 * g + j][ch * 64 + d4 * 4]);
        acc[j] += (double)xv.x * (double)wv.x + (double)xv.y * (double)wv.y +
                  (double)xv.z * (double)wv.z + (double)xv.w * (double)wv.w;
      }
    }
  }
#pragma unroll
  for (int j = 0; j < 4; ++j) lg[t][4 * g + j] = acc[j];
  __syncthreads();
  if (tid < 64) {
    double mx = lg[tid][0]; int bi = 0;
#pragma unroll
    for (int n = 1; n < NEXP; ++n)
      if (lg[tid][n] > mx) { mx = lg[tid][n]; bi = n; }
    double s = 0.0;
#pragma unroll
    for (int n = 0; n < NEXP; ++n) s += exp(lg[tid][n] - mx);
    e[t0 + tid] = bi;
    v[t0 + tid] = (float)(1.0 / s);
    atomicAdd(&hcnt[bi], 1);
  }
  __syncthreads();
  if (tid < NEXP && hcnt[tid] > 0) atomicAdd(&counts[tid], hcnt[tid]);
}

// ======================= FAST PATH (bf16 pre-converted) =====================
// R12 FFN structure. ffn1 grid = 4608 blocks with SCATTERED roles (period 72
// = 9 groups of 8): groups r<5 -> GEMM (2560), r>=5 -> W2 slab transpose
// (2048), so transpose blocks interleave through the dispatch order and fill
// ffn1's idle HBM bandwidth (R17's tail-append serialized instead). g&7 ==
// bid&7 preserves the XCD swizzle. w2t complete when ffn1 retires.

__global__ __launch_bounds__(256) void ffn1_fast(
    const unsigned short* __restrict__ xb, const unsigned short* __restrict__ w1t,
    const float* __restrict__ b1, const int* __restrict__ m_sel,
    const int* __restrict__ lists, unsigned short* __restrict__ H,
    const float* __restrict__ W2f, unsigned short* __restrict__ w2t) {
  __shared__ __align__(16) char smem[65536];
  unsigned short (*As)[8192] = (unsigned short(*)[8192])smem;
  unsigned short (*Bs)[8192] = (unsigned short(*)[8192])(smem + 32768);
  const int NWG = NEXP * 10 * 16;  // 2560
  const int NT = DDIM / 64;        // 16
  int bid = blockIdx.x;
  int tid = threadIdx.x;
  int grp = bid >> 3;
  int r9 = grp % 9;
  if (r9 >= 5) {
    // ---- W2 slab transpose: 32 h-tiles x 4 col-quads/expert (2048 blocks) --
    int b = ((grp / 9) * 4 + (r9 - 5)) * 8 + (bid & 7);  // 0..2047
    int n2 = b >> 7; int rem = b & 127; int by = rem >> 2, bxq = rem & 3;
    const float* src = W2f + (size_t)n2 * DDIM * HDIM + (size_t)by * 64 * DDIM + bxq * 256;
    slab_transpose((unsigned short*)smem, src, DDIM, w2t,
                   (size_t)n2 * 512, 32, by, bxq, tid);
    return;
  }
  int g = ((grp / 9) * 5 + r9) * 8 + (bid & 7);  // 0..2559, g&7 == bid&7
  int lid = (g & 7) * (NWG / 8) + (g >> 3);
  int n = lid / 160;
  int rem = lid - n * 160;
  int mt = rem >> 4, ht = rem & 15;
  int M = m_sel[n];
  if (mt * 128 >= M) return;
  int lane = tid & 63, wid = tid >> 6;
  int wr = (wid >> 1) * 64, wc = (wid & 1) * 64;
  int rbase = tid >> 3;
  int c16 = tid & 7;
  const char* xbase = (const char*)xb;
  const char* bbase = (const char*)w1t + (size_t)n * (DDIM * HDIM * 2);
  unsigned asrc[4], bsrc[4], ldsoff[4];
#pragma unroll
  for (int j = 0; j < 4; ++j) {
    int row = j * 32 + rbase;
    int gx = c16 ^ (row & 7);
    int s = mt * 128 + row;
    int tok = lists[n * CAP + (s < M ? s : 0)];
    asrc[j] = (unsigned)tok * 2048u + gx * 16;
    bsrc[j] = (unsigned)((ht * 2 + (row >> 6)) * 16) * 8192u +
              (unsigned)(row & 63) * 128u + gx * 16;
    ldsoff[j] = j * 4096 + wid * 1024;
  }
  unsigned aoff[2][4], boff[2][4];
#pragma unroll
  for (int kk = 0; kk < 2; ++kk) {
#pragma unroll
    for (int mi = 0; mi < 4; ++mi) {
      int row = wr + mi * 16 + (lane & 15);
      aoff[kk][mi] = row * 128 + (((kk * 4 + (lane >> 4)) ^ (row & 7)) * 16);
    }
#pragma unroll
    for (int ni = 0; ni < 4; ++ni) {
      int row = wc + ni * 16 + (lane & 15);
      boff[kk][ni] = row * 128 + (((kk * 4 + (lane >> 4)) ^ (row & 7)) * 16);
    }
  }
  f32x4 acc[4][4] = {};
#define STAGE1(buf, kt)                                                     \
  {                                                                         \
    unsigned koa = (unsigned)(kt) * 128u;                                   \
    unsigned kob = (unsigned)(kt) * 8192u;                                  \
    _Pragma("unroll") for (int j = 0; j < 4; ++j) {                         \
      GLD16(xbase + (size_t)(asrc[j] + koa), (char*)As[buf] + ldsoff[j]);   \
      GLD16(bbase + (size_t)(bsrc[j] + kob), (char*)Bs[buf] + ldsoff[j]);   \
    }                                                                       \
  }
  STAGE1(0, 0);
  STAGE1(1, 1);
  int cur = 0;
  for (int kt = 0; kt < NT; ++kt) {
    if (kt < NT - 1) asm volatile("s_waitcnt vmcnt(8)" ::: "memory");
    else             asm volatile("s_waitcnt vmcnt(0)" ::: "memory");
    RAW_BARRIER();
    bf16x8 af[2][4], bfv[2][4];
#pragma unroll
    for (int kk = 0; kk < 2; ++kk) {
#pragma unroll
      for (int mi = 0; mi < 4; ++mi)
        af[kk][mi] = *(const bf16x8*)((const char*)As[cur] + aoff[kk][mi]);
#pragma unroll
      for (int ni = 0; ni < 4; ++ni)
        bfv[kk][ni] = *(const bf16x8*)((const char*)Bs[cur] + boff[kk][ni]);
    }
    asm volatile("s_waitcnt lgkmcnt(0)" ::: "memory");
    RAW_BARRIER();
    if (kt + 2 < NT) STAGE1(cur, kt + 2);
    __builtin_amdgcn_s_setprio(1);
#pragma unroll
    for (int kk = 0; kk < 2; ++kk)
#pragma unroll
      for (int mi = 0; mi < 4; ++mi)
#pragma unroll
        for (int ni = 0; ni < 4; ++ni)
          acc[mi][ni] = __builtin_amdgcn_mfma_f32_16x16x32_bf16(af[kk][mi], bfv[kk][ni], acc[mi][ni], 0, 0, 0);
    __builtin_amdgcn_s_setprio(0);
    cur ^= 1;
  }
  int rq = (lane >> 4) * 4;
#pragma unroll
  for (int ni = 0; ni < 4; ++ni) {
    int h = ht * 128 + wc + ni * 16 + (lane & 15);
    float bias = b1[n * HDIM + h];
#pragma unroll
    for (int mi = 0; mi < 4; ++mi) {
#pragma unroll
      for (int q = 0; q < 4; ++q) {
        int lr = wr + mi * 16 + rq + q;
        float val = acc[mi][ni][q] + bias;
        H[((size_t)n * CAP + mt * 128 + lr) * HDIM + h] = f2bf(fast_gelu(val));
      }
    }
  }
}

__global__ __launch_bounds__(256) void ffn2_fast(
    const unsigned short* __restrict__ H, const unsigned short* __restrict__ w2t,
    const float* __restrict__ b2, const int* __restrict__ m_sel,
    const int* __restrict__ lists, float* __restrict__ out) {
  __shared__ __align__(16) unsigned short As[2][128 * 64];
  __shared__ __align__(16) unsigned short Bs[2][128 * 64];
  const int NWG = NEXP * 10 * 8;  // 1280
  const int NT = HDIM / 64;       // 32
  int bid = blockIdx.x;
  int tid = threadIdx.x;
  int lid = (bid & 7) * (NWG / 8) + (bid >> 3);
  int n = lid / 80;
  int rem = lid - n * 80;
  int mt = rem >> 3, dt = rem & 7;
  int M = m_sel[n];
  if (mt * 128 >= M) return;
  int lane = tid & 63, wid = tid >> 6;
  int wr = (wid >> 1) * 64, wc = (wid & 1) * 64;
  int rbase = tid >> 3;
  int c16 = tid & 7;
  const char* abase = (const char*)H + (((size_t)n * CAP + (size_t)mt * 128) * HDIM) * 2;
  const char* bbase = (const char*)w2t + (size_t)n * (DDIM * HDIM * 2);
  unsigned asrc[4], bsrc[4], ldsoff[4];
#pragma unroll
  for (int j = 0; j < 4; ++j) {
    int row = j * 32 + rbase;
    int g = c16 ^ (row & 7);
    asrc[j] = (unsigned)row * 4096u + g * 16;
    bsrc[j] = (unsigned)((dt * 2 + (row >> 6)) * 32) * 8192u +
              (unsigned)(row & 63) * 128u + g * 16;
    ldsoff[j] = j * 4096 + wid * 1024;
  }
  unsigned aoff[2][4], boff[2][4];
#pragma unroll
  for (int kk = 0; kk < 2; ++kk) {
#pragma unroll
    for (int mi = 0; mi < 4; ++mi) {
      int row = wr + mi * 16 + (lane & 15);
      aoff[kk][mi] = row * 128 + (((kk * 4 + (lane >> 4)) ^ (row & 7)) * 16);
    }
#pragma unroll
    for (int ni = 0; ni < 4; ++ni) {
      int row = wc + ni * 16 + (lane & 15);
      boff[kk][ni] = row * 128 + (((kk * 4 + (lane >> 4)) ^ (row & 7)) * 16);
    }
  }
  f32x4 acc[4][4] = {};
#define STAGE2(buf, kt)                                                     \
  {                                                                         \
    unsigned koa = (unsigned)(kt) * 128u;                                   \
    unsigned kob = (unsigned)(kt) * 8192u;                                  \
    _Pragma("unroll") for (int j = 0; j < 4; ++j) {                         \
      GLD16(abase + (size_t)(asrc[j] + koa), (char*)As[buf] + ldsoff[j]);   \
      GLD16(bbase + (size_t)(bsrc[j] + kob), (char*)Bs[buf] + ldsoff[j]);   \
    }                                                                       \
  }
  STAGE2(0, 0);
  STAGE2(1, 1);
  int cur = 0;
  for (int kt = 0; kt < NT; ++kt) {
    if (kt < NT - 1) asm volatile("s_waitcnt vmcnt(8)" ::: "memory");
    else             asm volatile("s_waitcnt vmcnt(0)" ::: "memory");
    RAW_BARRIER();
    bf16x8 af[2][4], bfv[2][4];
#pragma unroll
    for (int kk = 0; kk < 2; ++kk) {
#pragma unroll
      for (int mi = 0; mi < 4; ++mi)
        af[kk][mi] = *(const bf16x8*)((const char*)As[cur] + aoff[kk][mi]);
#pragma unroll
      for (int ni = 0; ni < 4; ++ni)
        bfv[kk][ni] = *(const bf16x8*)((const char*)Bs[cur] + boff[kk][ni]);
    }
    asm volatile("s_waitcnt lgkmcnt(0)" ::: "memory");
    RAW_BARRIER();
    if (kt + 2 < NT) STAGE2(cur, kt + 2);
    __builtin_amdgcn_s_setprio(1);
#pragma unroll
    for (int kk = 0; kk < 2; ++kk)
#pragma unroll
      for (int mi = 0; mi < 4; ++mi)
#pragma unroll
        for (int ni = 0; ni < 4; ++ni)
          acc[mi][ni] = __builtin_amdgcn_mfma_f32_16x16x32_bf16(af[kk][mi], bfv[kk][ni], acc[mi][ni], 0, 0, 0);
    __builtin_amdgcn_s_setprio(0);
    cur ^= 1;
  }
  int rq = (lane >> 4) * 4;
  float bias[4];
#pragma unroll
  for (int ni = 0; ni < 4; ++ni)
    bias[ni] = b2[n * DDIM + dt * 128 + wc + ni * 16 + (lane & 15)];
#pragma unroll
  for (int mi = 0; mi < 4; ++mi) {
#pragma unroll
    for (int q = 0; q < 4; ++q) {
      int lr = wr + mi * 16 + rq + q;
      int s = mt * 128 + lr;
      if (s < M) {
        int tok = lists[n * CAP + s];
#pragma unroll
        for (int ni = 0; ni < 4; ++ni) {
          int dcol = dt * 128 + wc + ni * 16 + (lane & 15);
          out[(size_t)tok * DDIM + dcol] = acc[mi][ni][q] + bias[ni];
        }
      }
    }
  }
}

// ======================= SLOW PATH (ws fallback) ============================
__global__ __launch_bounds__(256) void ffn1_slow(
    const float* __restrict__ x, const float* __restrict__ W1, const float* __restrict__ b1,
    const int* __restrict__ m_sel, const int* __restrict__ lists,
    unsigned short* __restrict__ H) {
  __shared__ unsigned short Al[128 * APITCH];
  __shared__ unsigned short Bl[128 * APITCH];
  __shared__ int rows[128];
  int n = blockIdx.z, mt = blockIdx.y, ht = blockIdx.x;
  int M = m_sel[n];
  if (mt * 128 >= M) return;
  int tid = threadIdx.x;
  if (tid < 128) {
    int s = mt * 128 + tid;
    rows[tid] = lists[n * CAP + (s < M ? s : 0)];
  }
  __syncthreads();
  f32x4 acc[4][4] = {};
  int lane = tid & 63;
  int wid = tid >> 6;
  int wr = (wid >> 1) * 64, wc = (wid & 1) * 64;
  int ar = tid >> 4, ac = (tid & 15) * 4;
  int bh = tid & 127, bk8 = (tid >> 7) * 8;
  const size_t w1base = (size_t)n * DDIM * HDIM + (size_t)ht * 128;
  for (int kt = 0; kt < DDIM / 64; ++kt) {
#pragma unroll
    for (int i = 0; i < 8; ++i) {
      int r = ar + i * 16;
      float4 xv = *(const float4*)(x + (size_t)rows[r] * DDIM + kt * 64 + ac);
      unsigned plo = (unsigned)f2bf(xv.x) | ((unsigned)f2bf(xv.y) << 16);
      unsigned phi = (unsigned)f2bf(xv.z) | ((unsigned)f2bf(xv.w) << 16);
      *(uint2*)(&Al[r * APITCH + ac]) = make_uint2(plo, phi);
    }
#pragma unroll
    for (int i = 0; i < 4; ++i) {
      int k0 = bk8 + i * 16;
      const float* wp = W1 + w1base + (size_t)(kt * 64 + k0) * HDIM + bh;
      uint4 pk;
      pk.x = (unsigned)f2bf(wp[0]) | ((unsigned)f2bf(wp[HDIM]) << 16);
      pk.y = (unsigned)f2bf(wp[2 * HDIM]) | ((unsigned)f2bf(wp[3 * HDIM]) << 16);
      pk.z = (unsigned)f2bf(wp[4 * HDIM]) | ((unsigned)f2bf(wp[5 * HDIM]) << 16);
      pk.w = (unsigned)f2bf(wp[6 * HDIM]) | ((unsigned)f2bf(wp[7 * HDIM]) << 16);
      *(uint4*)(&Bl[bh * APITCH + k0]) = pk;
    }
    __syncthreads();
#pragma unroll
    for (int kk = 0; kk < 2; ++kk) {
      bf16x8 af[4], bfr[4];
#pragma unroll
      for (int mi = 0; mi < 4; ++mi)
        af[mi] = *(const bf16x8*)(&Al[(wr + mi * 16 + (lane & 15)) * APITCH + kk * 32 + (lane >> 4) * 8]);
#pragma unroll
      for (int ni = 0; ni < 4; ++ni)
        bfr[ni] = *(const bf16x8*)(&Bl[(wc + ni * 16 + (lane & 15)) * APITCH + kk * 32 + (lane >> 4) * 8]);
#pragma unroll
      for (int mi = 0; mi < 4; ++mi)
#pragma unroll
        for (int ni = 0; ni < 4; ++ni)
          acc[mi][ni] = __builtin_amdgcn_mfma_f32_16x16x32_bf16(af[mi], bfr[ni], acc[mi][ni], 0, 0, 0);
    }
    __syncthreads();
  }
  int rq = (lane >> 4) * 4;
#pragma unroll
  for (int ni = 0; ni < 4; ++ni) {
    int h = ht * 128 + wc + ni * 16 + (lane & 15);
    float bias = b1[n * HDIM + h];
#pragma unroll
    for (int mi = 0; mi < 4; ++mi) {
#pragma unroll
      for (int q = 0; q < 4; ++q) {
        int lr = wr + mi * 16 + rq + q;
        float val = acc[mi][ni][q] + bias;
        H[((size_t)n * CAP + mt * 128 + lr) * HDIM + h] = f2bf(fast_gelu(val));
      }
    }
  }
}

__global__ __launch_bounds__(256) void ffn2_slow(
    const unsigned short* __restrict__ H, const float* __restrict__ W2, const float* __restrict__ b2,
    const int* __restrict__ m_sel, const int* __restrict__ lists,
    float* __restrict__ out) {
  __shared__ unsigned short Al[128 * APITCH];
  __shared__ unsigned short Bl[128 * APITCH];
  __shared__ int rows[128];
  int n = blockIdx.z, mt = blockIdx.y, dt = blockIdx.x;
  int M = m_sel[n];
  if (mt * 128 >= M) return;
  int tid = threadIdx.x;
  if (tid < 128) {
    int s = mt * 128 + tid;
    rows[tid] = lists[n * CAP + (s < M ? s : 0)];
  }
  __syncthreads();
  f32x4 acc[4][4] = {};
  int lane = tid & 63;
  int wid = tid >> 6;
  int wr = (wid >> 1) * 64, wc = (wid & 1) * 64;
  int ar2 = tid >> 1, ak8 = (tid & 1) * 8;
  int bh = tid & 127, bk8 = (tid >> 7) * 8;
  const size_t hbase = ((size_t)n * CAP + (size_t)mt * 128) * HDIM;
  const size_t w2base = (size_t)n * HDIM * DDIM + (size_t)dt * 128;
  for (int kt = 0; kt < HDIM / 64; ++kt) {
#pragma unroll
    for (int i = 0; i < 4; ++i) {
      int k0 = ak8 + i * 16;
      uint4 hv = *(const uint4*)(H + hbase + (size_t)ar2 * HDIM + kt * 64 + k0);
      *(uint4*)(&Al[ar2 * APITCH + k0]) = hv;
    }
#pragma unroll
    for (int i = 0; i < 4; ++i) {
      int k0 = bk8 + i * 16;
      const float* wp = W2 + w2base + (size_t)(kt * 64 + k0) * DDIM + bh;
      uint4 pk;
      pk.x = (unsigned)f2bf(wp[0]) | ((unsigned)f2bf(wp[DDIM]) << 16);
      pk.y = (unsigned)f2bf(wp[2 * DDIM]) | ((unsigned)f2bf(wp[3 * DDIM]) << 16);
      pk.z = (unsigned)f2bf(wp[4 * DDIM]) | ((unsigned)f2bf(wp[5 * DDIM]) << 16);
      pk.w = (unsigned)f2bf(wp[6 * DDIM]) | ((unsigned)f2bf(wp[7 * DDIM]) << 16);
      *(uint4*)(&Bl[bh * APITCH + k0]) = pk;
    }
    __syncthreads();
#pragma unroll
    for (int kk = 0; kk < 2; ++kk) {
      bf16x8 af[4], bfr[4];
#pragma unroll
      for (int mi = 0; mi < 4; ++mi)
        af[mi] = *(const bf16x8*)(&Al[(wr + mi * 16 + (lane & 15)) * APITCH + kk * 32 + (lane >> 4) * 8]);
#pragma unroll
      for (int ni = 0; ni < 4; ++ni)
        bfr[ni] = *(const bf16x8*)(&Bl[(wc + ni * 16 + (lane & 15)) * APITCH + kk * 32 + (lane >> 4) * 8]);
#pragma unroll
      for (int mi = 0; mi < 4; ++mi)
#pragma unroll
        for (int ni = 0; ni < 4; ++ni)
          acc[mi][ni] = __builtin_amdgcn_mfma_f32_16x16x32_bf16(af[mi], bfr[ni], acc[mi][ni], 0, 0, 0);
    }
    __syncthreads();
  }
  int rq = (lane >> 4) * 4;
#pragma unroll
  for (int mi = 0; mi < 4; ++mi) {
#pragma unroll
    for (int q = 0; q < 4; ++q) {
      int lr = wr + mi * 16 + rq + q;
      int s = mt * 128 + lr;
      if (s < M) {
        int tok = rows[lr];
#pragma unroll
        for (int ni = 0; ni < 4; ++ni) {
          int dcol = dt * 128 + wc + ni * 16 + (lane & 15);
          out[(size_t)tok * DDIM + dcol] = acc[mi][ni][q] + b2[n * DDIM + dcol];
        }
      }
    }
  }
}

// ---------------- passthrough: one wave per row, 1024 blocks ----------------
__global__ __launch_bounds__(256) void passthrough_kernel(
    const float* __restrict__ x, const int* __restrict__ flags,
    float* __restrict__ out) {
  int lane = threadIdx.x & 63;
  int w = threadIdx.x >> 6;
  int base = blockIdx.x * 16;
  for (int r = base + w; r < base + 16; r += 4) {
    if (flags[r]) continue;
    const float4* s = (const float4*)(x + (size_t)r * DDIM);
    float4* d = (float4*)(out + (size_t)r * DDIM);
#pragma unroll
    for (int i = 0; i < 4; ++i) d[lane + i * 64] = s[lane + i * 64];
  }
}

extern "C" void kernel_launch(void* const* d_in, const int* in_sizes, int n_in,
                              void* d_out, int out_size, void* d_ws, size_t ws_size,
                              hipStream_t stream) {
  const float* x  = (const float*)d_in[0];
  const float* Wg = (const float*)d_in[1];
  const float* W1 = (const float*)d_in[2];
  const float* b1 = (const float*)d_in[3];
  const float* W2 = (const float*)d_in[4];
  const float* b2 = (const float*)d_in[5];
  float* out = (float*)d_out;
  char* ws = (char*)d_ws;
  int* counts = (int*)ws;
  int* m_sel  = (int*)(ws + 64);
  int* flags  = (int*)(ws + 128);
  int* e      = (int*)(ws + 128 + 4 * BT);
  float* v    = (float*)(ws + 128 + 8 * BT);
  int* lists  = (int*)(ws + 128 + 12 * BT);

  const size_t MB = 1024 * 1024;
  unsigned short* xb  = (unsigned short*)(ws + 1 * MB);
  unsigned short* w1t = (unsigned short*)(ws + 33 * MB);
  unsigned short* w2t = (unsigned short*)(ws + 97 * MB);
  unsigned short* Hf  = (unsigned short*)(ws + 161 * MB);
  bool fast = ws_size >= 242 * MB;

  zero_meta_kernel<<<1, 64, 0, stream>>>(counts);
  if (fast) {
    prep_kernel<<<256 + 8192, 256, 0, stream>>>(x, Wg, e, v, counts, xb, flags, W1, w1t);
    select_kernel<<<NEXP, 256, 0, stream>>>(e, v, counts, m_sel, lists, flags);
    ffn1_fast<<<4608, 256, 0, stream>>>(xb, w1t, b1, m_sel, lists, Hf, W2, w2t);
    ffn2_fast<<<NEXP * 10 * 8, 256, 0, stream>>>(Hf, w2t, b2, m_sel, lists, out);
  } else {
    unsigned short* Hs = (unsigned short*)(ws + 1 * MB);
    gate_kernel<<<BT / 64, 256, 0, stream>>>(x, Wg, e, v, counts, (unsigned short*)nullptr, flags);
    select_kernel<<<NEXP, 256, 0, stream>>>(e, v, counts, m_sel, lists, flags);
    ffn1_slow<<<dim3(HDIM / 128, CAP / 128, NEXP), 256, 0, stream>>>(x, W1, b1, m_sel, lists, Hs);
    ffn2_slow<<<dim3(DDIM / 128, CAP / 128, NEXP), 256, 0, stream>>>(Hs, W2, b2, m_sel, lists, out);
  }
  passthrough_kernel<<<BT / 16, 256, 0, stream>>>(x, flags, out);
}

// Round 20
// 383.414 us; speedup vs baseline: 1.0426x; 1.0050x over previous
//
#include <hip/hip_runtime.h>
#include <hip/hip_bf16.h>
#include <math.h>

#define BT 16384
#define DDIM 1024
#define NEXP 16
#define HDIM 2048
#define CAP 1280
#define APITCH 72
#define LBP 262  // bf16 LDS slab pitch for in-GEMM transpose tail

typedef __bf16 bf16x8 __attribute__((ext_vector_type(8)));
typedef float f32x4 __attribute__((ext_vector_type(4)));

__device__ __forceinline__ unsigned short f2bf(float f) {
  unsigned u = __float_as_uint(f);
  u += 0x7FFFu + ((u >> 16) & 1u);
  return (unsigned short)(u >> 16);
}

// HW packed fp32->bf16 (RNE, identical to f2bf): dst.lo=cvt(a), dst.hi=cvt(b)
__device__ __forceinline__ unsigned cvt_pk_bf16(float a, float b) {
  unsigned r;
  asm("v_cvt_pk_bf16_f32 %0, %1, %2" : "=v"(r) : "v"(a), "v"(b));
  return r;
}

// gelu(tanh approx) == v * sigmoid(2z); hardware v_exp_f32 path.
__device__ __forceinline__ float fast_gelu(float v) {
  float z = 0.7978845608028654f * (v + 0.044715f * v * v * v);
  return v / (1.0f + __expf(-2.0f * z));
}

#define GLD16(g, l)                                                        \
  __builtin_amdgcn_global_load_lds(                                        \
      (const __attribute__((address_space(1))) unsigned int*)(g),          \
      (__attribute__((address_space(3))) unsigned int*)(l), 16, 0, 0)

// Raw barrier without the vmcnt(0) drain __syncthreads would emit.
#define RAW_BARRIER()                          \
  {                                            \
    __builtin_amdgcn_sched_barrier(0);         \
    __builtin_amdgcn_s_barrier();              \
    __builtin_amdgcn_sched_barrier(0);         \
  }

__global__ void zero_meta_kernel(int* p) {
  int i = threadIdx.x;
  if (i < 32) p[i] = 0;  // counts[16] + m_sel[16]
}

// ---- slab transpose body: 64 rows x 256 cols fp32 -> 4 tiled 64x64 bf16
// tiles ([col][row] inside tile, 8KB each, 2x4KB contiguous bursts) ---------
__device__ __forceinline__ void slab_transpose(
    unsigned short* Lb, const float* src, int C,
    unsigned short* outp, size_t tile_base, int tmul, int by, int bxq, int tid) {
  int w = tid >> 6, lane = tid & 63;
#pragma unroll
  for (int k = 0; k < 16; ++k) {
    int row = w + k * 4;
    float4 vv = *(const float4*)(src + (size_t)row * C + lane * 4);
    unsigned p0 = cvt_pk_bf16(vv.x, vv.y);
    unsigned p1 = cvt_pk_bf16(vv.z, vv.w);
    *(uint2*)(&Lb[row * LBP + lane * 4]) = make_uint2(p0, p1);
  }
  __syncthreads();
  int oc_lo = tid >> 3;
  int rb = (tid & 7) * 8;
#pragma unroll
  for (int p2 = 0; p2 < 4; ++p2) {
    int bx = bxq * 4 + p2;
    char* dstT = (char*)outp + (tile_base + (size_t)bx * tmul + by) * 8192;
#pragma unroll
    for (int p = 0; p < 2; ++p) {
      int oc = p * 32 + oc_lo;
      const unsigned short* col = &Lb[rb * LBP + p2 * 64 + oc];
      unsigned short u[8];
#pragma unroll
      for (int j = 0; j < 8; ++j) u[j] = col[j * LBP];
      uint4 pk;
      pk.x = (unsigned)u[0] | ((unsigned)u[1] << 16);
      pk.y = (unsigned)u[2] | ((unsigned)u[3] << 16);
      pk.z = (unsigned)u[4] | ((unsigned)u[5] << 16);
      pk.w = (unsigned)u[6] | ((unsigned)u[7] << 16);
      *(uint4*)(dstT + p * 4096 + tid * 16) = pk;
    }
  }
}

// ======== fused prep: blocks [0,256) = gate; [256,8448) = W1 tiled transpose
__global__ __launch_bounds__(256) void prep_kernel(
    const float* __restrict__ x, const float* __restrict__ Wg,
    int* __restrict__ e, float* __restrict__ v, int* __restrict__ counts,
    unsigned short* __restrict__ xb, int* __restrict__ flags,
    const float* __restrict__ W1, unsigned short* __restrict__ w1t) {
  __shared__ __align__(16) char smem[30016];
  int bid = blockIdx.x;
  int tid = threadIdx.x;
  if (bid < 256) {
    // ---------------- gate: 64 tokens/block ----------------
    float* xt = (float*)smem;                       // [64][68]  17408B
    double* lg = (double*)(smem + 17408);           // [64][16]   8192B
    float* wgt_c = (float*)(smem + 25600);          // [16][68]   4352B
    int* hcnt = (int*)(smem + 29952);               // [16]
    int t0 = bid * 64;
    if (tid < NEXP) hcnt[tid] = 0;
    if (tid < 64) flags[t0 + tid] = 0;
    int t = tid & 63, g = tid >> 6;
    double acc[4] = {0.0, 0.0, 0.0, 0.0};
    int sr = tid >> 4;
    int sc = (tid & 15) * 4;
    int wd = tid >> 2, wn = (tid & 3) * 4;
    for (int ch = 0; ch < 16; ++ch) {
      __syncthreads();
#pragma unroll
      for (int i = 0; i < 4; ++i) {
        int r = sr + i * 16;
        float4 xv = *(const float4*)(x + (size_t)(t0 + r) * DDIM + ch * 64 + sc);
        xt[r * 68 + sc + 0] = xv.x; xt[r * 68 + sc + 1] = xv.y;
        xt[r * 68 + sc + 2] = xv.z; xt[r * 68 + sc + 3] = xv.w;
        unsigned p0 = cvt_pk_bf16(xv.x, xv.y);
        unsigned p1 = cvt_pk_bf16(xv.z, xv.w);
        *(uint2*)(xb + (size_t)(t0 + r) * DDIM + ch * 64 + sc) = make_uint2(p0, p1);
      }
      {
        float4 w = *(const float4*)(Wg + ch * 1024 + tid * 4);
        wgt_c[(wn + 0) * 68 + wd] = w.x;
        wgt_c[(wn + 1) * 68 + wd] = w.y;
        wgt_c[(wn + 2) * 68 + wd] = w.z;
        wgt_c[(wn + 3) * 68 + wd] = w.w;
      }
      __syncthreads();
#pragma unroll
      for (int d4 = 0; d4 < 16; ++d4) {
        float4 xv = *(const float4*)(&xt[t * 68 + d4 * 4]);
#pragma unroll
        for (int j = 0; j < 4; ++j) {
          float4 wv = *(const float4*)(&wgt_c[(4 * g + j) * 68 + d4 * 4]);
          acc[j] += (double)xv.x * (double)wv.x + (double)xv.y * (double)wv.y +
                    (double)xv.z * (double)wv.z + (double)xv.w * (double)wv.w;
        }
      }
    }
#pragma unroll
    for (int j = 0; j < 4; ++j) lg[t * 16 + 4 * g + j] = acc[j];
    __syncthreads();
    if (tid < 64) {
      double mx = lg[tid * 16]; int bi = 0;
#pragma unroll
      for (int n = 1; n < NEXP; ++n)
        if (lg[tid * 16 + n] > mx) { mx = lg[tid * 16 + n]; bi = n; }
      double s = 0.0;
#pragma unroll
      for (int n = 0; n < NEXP; ++n) s += exp(lg[tid * 16 + n] - mx);
      e[t0 + tid] = bi;
      v[t0 + tid] = (float)(1.0 / s);
      atomicAdd(&hcnt[bi], 1);
    }
    __syncthreads();
    if (tid < NEXP && hcnt[tid] > 0) atomicAdd(&counts[tid], hcnt[tid]);
    return;
  }
  // ---------------- W1 transpose + fp32->bf16, tiled (R15 body) -------------
  float* tile = (float*)smem;  // [64][65]
  int b = bid - 256;  // 0..8191
  int n = b >> 9; int rem = b & 511; int by = rem >> 5, bx = rem & 31;
  size_t tile_off = ((size_t)n * 512 + (size_t)bx * 16 + by) * 8192;
  const float* src = W1 + (size_t)n * DDIM * HDIM;
  int r0 = by * 64, c0 = bx * 64;
  int lr = tid >> 2, lq = tid & 3;
#pragma unroll
  for (int i = 0; i < 4; ++i) {
    float4 vv = *(const float4*)(src + (size_t)(r0 + lr) * HDIM + c0 + i * 16 + lq * 4);
    *(float4*)(&tile[lr * 65 + i * 16 + lq * 4]) = vv;
  }
  __syncthreads();
  char* dstT = (char*)w1t + tile_off;
  int oc2 = tid >> 3, lq2 = tid & 7;
#pragma unroll
  for (int p = 0; p < 2; ++p) {
    int oc = p * 32 + oc2;
    int rb = lq2 * 8;
    uint4 pk;
    pk.x = cvt_pk_bf16(tile[(rb + 0) * 65 + oc], tile[(rb + 1) * 65 + oc]);
    pk.y = cvt_pk_bf16(tile[(rb + 2) * 65 + oc], tile[(rb + 3) * 65 + oc]);
    pk.z = cvt_pk_bf16(tile[(rb + 4) * 65 + oc], tile[(rb + 5) * 65 + oc]);
    pk.w = cvt_pk_bf16(tile[(rb + 6) * 65 + oc], tile[(rb + 7) * 65 + oc]);
    *(uint4*)(dstT + p * 4096 + tid * 16) = pk;
  }
}

// ---------------- select: per-expert token set under capacity ---------------
__global__ void select_kernel(const int* __restrict__ e, const float* __restrict__ v,
                              const int* __restrict__ counts, int* __restrict__ m_sel,
                              int* __restrict__ lists, int* __restrict__ flags) {
  int n = blockIdx.x;
  int tid = threadIdx.x;
  int cnt = counts[n];
  __shared__ int pos;
  if (tid == 0) pos = 0;
  __syncthreads();
  if (cnt <= CAP) {
    for (int t = tid; t < BT; t += 256) {
      if (e[t] == n) {
        int p = atomicAdd(&pos, 1);
        lists[n * CAP + p] = t;
        flags[t] = 1;
      }
    }
    __syncthreads();
    if (tid == 0) m_sel[n] = pos;
  } else {
    __shared__ int scnt;
    unsigned lo = 0u, hi = 0x7F800000u;
    while (hi - lo > 1u) {
      unsigned mid = lo + ((hi - lo) >> 1);
      if (tid == 0) scnt = 0;
      __syncthreads();
      int c = 0;
      for (int t = tid; t < BT; t += 256)
        if (e[t] == n && __float_as_uint(v[t]) >= mid) c++;
      atomicAdd(&scnt, c);
      __syncthreads();
      int tot = scnt;
      __syncthreads();
      if (tot >= CAP) lo = mid; else hi = mid;
    }
    for (int t = tid; t < BT; t += 256) {
      if (e[t] == n && __float_as_uint(v[t]) > lo) {
        int p = atomicAdd(&pos, 1);
        lists[n * CAP + p] = t;
        flags[t] = 1;
      }
    }
    __syncthreads();
    if (tid == 0) {
      int p = pos;
      for (int t = 0; t < BT && p < CAP; ++t) {
        if (e[t] == n && __float_as_uint(v[t]) == lo) {
          lists[n * CAP + p] = t; flags[t] = 1; ++p;
        }
      }
      m_sel[n] = p;
    }
  }
}

// ---------------- gate (slow path only, resident Wg table) ------------------
__global__ __launch_bounds__(256) void gate_kernel(
    const float* __restrict__ x, const float* __restrict__ Wg,
    int* __restrict__ e, float* __restrict__ v, int* __restrict__ counts,
    unsigned short* __restrict__ xb, int* __restrict__ flags) {
  __shared__ float wgt[NEXP][DDIM];
  __shared__ float xt[64][68];
  __shared__ double lg[64][NEXP];
  __shared__ int hcnt[NEXP];
  int tid = threadIdx.x;
  int t0 = blockIdx.x * 64;
  if (tid < NEXP) hcnt[tid] = 0;
  if (tid < 64) flags[t0 + tid] = 0;
  for (int i = tid; i < DDIM * NEXP / 4; i += 256) {
    int idx = i * 4;
    int d = idx >> 4, n = idx & 15;
    float4 w = *(const float4*)(Wg + idx);
    wgt[n + 0][d] = w.x; wgt[n + 1][d] = w.y;
    wgt[n + 2][d] = w.z; wgt[n + 3][d] = w.w;
  }
  int t = tid & 63, g = tid >> 6;
  double acc[4] = {0.0, 0.0, 0.0, 0.0};
  int sr = tid >> 4;
  int sc = (tid & 15) * 4;
  for (int ch = 0; ch < 16; ++ch) {
    __syncthreads();
#pragma unroll
    for (int i = 0; i < 4; ++i) {
      int r = sr + i * 16;
      float4 xv = *(const float4*)(x + (size_t)(t0 + r) * DDIM + ch * 64 + sc);
      xt[r][sc + 0] = xv.x; xt[r][sc + 1] = xv.y;
      xt[r][sc + 2] = xv.z; xt[r][sc + 3] = xv.w;
      if (xb) {
        unsigned p0 = cvt_pk_bf16(xv.x, xv.y);
        unsigned p1 = cvt_pk_bf16(xv.z, xv.w);
        *(uint2*)(xb + (size_t)(t0 + r) * DDIM + ch * 64 + sc) = make_uint2(p0, p1);
      }
    }
    __syncthreads();
#pragma unroll
    for (int d4 = 0; d4 < 16; ++d4) {
      float4 xv = *(const float4*)(&xt[t][d4 * 4]);
#pragma unroll
      for (int j = 0; j < 4; ++j) {
        float4 wv = *(const float4*)(&wgt[4 * g + j][ch * 64 + d4 * 4]);
        acc[j] += (double)xv.x * (double)wv.x + (double)xv.y * (double)wv.y +
                  (double)xv.z * (double)wv.z + (double)xv.w * (double)wv.w;
      }
    }
  }
#pragma unroll
  for (int j = 0; j < 4; ++j) lg[t][4 * g + j] = acc[j];
  __syncthreads();
  if (tid < 64) {
    double mx = lg[tid][0]; int bi = 0;
#pragma unroll
    for (int n = 1; n < NEXP; ++n)
      if (lg[tid][n] > mx) { mx = lg[tid][n]; bi = n; }
    double s = 0.0;
#pragma unroll
    for (int n = 0; n < NEXP; ++n) s += exp(lg[tid][n] - mx);
    e[t0 + tid] = bi;
    v[t0 + tid] = (float)(1.0 / s);
    atomicAdd(&hcnt[bi], 1);
  }
  __syncthreads();
  if (tid < NEXP && hcnt[tid] > 0) atomicAdd(&counts[tid], hcnt[tid]);
}

// ======================= FAST PATH (bf16 pre-converted) =====================
// R12 FFN structure. ffn1 grid = 4608 blocks with SCATTERED roles (period 9
// groups of 8: r<5 GEMM 2560, r>=5 W2 slab transpose 2048) -- transpose fills
// ffn1's idle HBM BW (R19: +10us marginal for 70us of work, 3.0 TB/s agg).
// ffn2 grid = 2304 blocks (period 9: r<5 GEMM 1280, r>=5 passthrough 1024).
// g&7 == bid&7 preserves XCD swizzle in both.

__global__ __launch_bounds__(256) void ffn1_fast(
    const unsigned short* __restrict__ xb, const unsigned short* __restrict__ w1t,
    const float* __restrict__ b1, const int* __restrict__ m_sel,
    const int* __restrict__ lists, unsigned short* __restrict__ H,
    const float* __restrict__ W2f, unsigned short* __restrict__ w2t) {
  __shared__ __align__(16) char smem[65536];
  unsigned short (*As)[8192] = (unsigned short(*)[8192])smem;
  unsigned short (*Bs)[8192] = (unsigned short(*)[8192])(smem + 32768);
  const int NWG = NEXP * 10 * 16;  // 2560
  const int NT = DDIM / 64;        // 16
  int bid = blockIdx.x;
  int tid = threadIdx.x;
  int grp = bid >> 3;
  int r9 = grp % 9;
  if (r9 >= 5) {
    // ---- W2 slab transpose: 32 h-tiles x 4 col-quads/expert (2048 blocks) --
    int b = ((grp / 9) * 4 + (r9 - 5)) * 8 + (bid & 7);  // 0..2047
    int n2 = b >> 7; int rem = b & 127; int by = rem >> 2, bxq = rem & 3;
    const float* src = W2f + (size_t)n2 * DDIM * HDIM + (size_t)by * 64 * DDIM + bxq * 256;
    slab_transpose((unsigned short*)smem, src, DDIM, w2t,
                   (size_t)n2 * 512, 32, by, bxq, tid);
    return;
  }
  int g = ((grp / 9) * 5 + r9) * 8 + (bid & 7);  // 0..2559, g&7 == bid&7
  int lid = (g & 7) * (NWG / 8) + (g >> 3);
  int n = lid / 160;
  int rem = lid - n * 160;
  int mt = rem >> 4, ht = rem & 15;
  int M = m_sel[n];
  if (mt * 128 >= M) return;
  int lane = tid & 63, wid = tid >> 6;
  int wr = (wid >> 1) * 64, wc = (wid & 1) * 64;
  int rbase = tid >> 3;
  int c16 = tid & 7;
  const char* xbase = (const char*)xb;
  const char* bbase = (const char*)w1t + (size_t)n * (DDIM * HDIM * 2);
  unsigned asrc[4], bsrc[4], ldsoff[4];
#pragma unroll
  for (int j = 0; j < 4; ++j) {
    int row = j * 32 + rbase;
    int gx = c16 ^ (row & 7);
    int s = mt * 128 + row;
    int tok = lists[n * CAP + (s < M ? s : 0)];
    asrc[j] = (unsigned)tok * 2048u + gx * 16;
    bsrc[j] = (unsigned)((ht * 2 + (row >> 6)) * 16) * 8192u +
              (unsigned)(row & 63) * 128u + gx * 16;
    ldsoff[j] = j * 4096 + wid * 1024;
  }
  unsigned aoff[2][4], boff[2][4];
#pragma unroll
  for (int kk = 0; kk < 2; ++kk) {
#pragma unroll
    for (int mi = 0; mi < 4; ++mi) {
      int row = wr + mi * 16 + (lane & 15);
      aoff[kk][mi] = row * 128 + (((kk * 4 + (lane >> 4)) ^ (row & 7)) * 16);
    }
#pragma unroll
    for (int ni = 0; ni < 4; ++ni) {
      int row = wc + ni * 16 + (lane & 15);
      boff[kk][ni] = row * 128 + (((kk * 4 + (lane >> 4)) ^ (row & 7)) * 16);
    }
  }
  f32x4 acc[4][4] = {};
#define STAGE1(buf, kt)                                                     \
  {                                                                         \
    unsigned koa = (unsigned)(kt) * 128u;                                   \
    unsigned kob = (unsigned)(kt) * 8192u;                                  \
    _Pragma("unroll") for (int j = 0; j < 4; ++j) {                         \
      GLD16(xbase + (size_t)(asrc[j] + koa), (char*)As[buf] + ldsoff[j]);   \
      GLD16(bbase + (size_t)(bsrc[j] + kob), (char*)Bs[buf] + ldsoff[j]);   \
    }                                                                       \
  }
  STAGE1(0, 0);
  STAGE1(1, 1);
  int cur = 0;
  for (int kt = 0; kt < NT; ++kt) {
    if (kt < NT - 1) asm volatile("s_waitcnt vmcnt(8)" ::: "memory");
    else             asm volatile("s_waitcnt vmcnt(0)" ::: "memory");
    RAW_BARRIER();
    bf16x8 af[2][4], bfv[2][4];
#pragma unroll
    for (int kk = 0; kk < 2; ++kk) {
#pragma unroll
      for (int mi = 0; mi < 4; ++mi)
        af[kk][mi] = *(const bf16x8*)((const char*)As[cur] + aoff[kk][mi]);
#pragma unroll
      for (int ni = 0; ni < 4; ++ni)
        bfv[kk][ni] = *(const bf16x8*)((const char*)Bs[cur] + boff[kk][ni]);
    }
    asm volatile("s_waitcnt lgkmcnt(0)" ::: "memory");
    RAW_BARRIER();
    if (kt + 2 < NT) STAGE1(cur, kt + 2);
    __builtin_amdgcn_s_setprio(1);
#pragma unroll
    for (int kk = 0; kk < 2; ++kk)
#pragma unroll
      for (int mi = 0; mi < 4; ++mi)
#pragma unroll
        for (int ni = 0; ni < 4; ++ni)
          acc[mi][ni] = __builtin_amdgcn_mfma_f32_16x16x32_bf16(af[kk][mi], bfv[kk][ni], acc[mi][ni], 0, 0, 0);
    __builtin_amdgcn_s_setprio(0);
    cur ^= 1;
  }
  int rq = (lane >> 4) * 4;
#pragma unroll
  for (int ni = 0; ni < 4; ++ni) {
    int h = ht * 128 + wc + ni * 16 + (lane & 15);
    float bias = b1[n * HDIM + h];
#pragma unroll
    for (int mi = 0; mi < 4; ++mi) {
#pragma unroll
      for (int q = 0; q < 4; ++q) {
        int lr = wr + mi * 16 + rq + q;
        float val = acc[mi][ni][q] + bias;
        H[((size_t)n * CAP + mt * 128 + lr) * HDIM + h] = f2bf(fast_gelu(val));
      }
    }
  }
}

__global__ __launch_bounds__(256) void ffn2_fast(
    const unsigned short* __restrict__ H, const unsigned short* __restrict__ w2t,
    const float* __restrict__ b2, const int* __restrict__ m_sel,
    const int* __restrict__ lists, float* __restrict__ out,
    const float* __restrict__ x, const int* __restrict__ flags) {
  __shared__ __align__(16) unsigned short As[2][128 * 64];
  __shared__ __align__(16) unsigned short Bs[2][128 * 64];
  const int NWG = NEXP * 10 * 8;  // 1280
  const int NT = HDIM / 64;       // 32
  int bid = blockIdx.x;
  int tid = threadIdx.x;
  int grp = bid >> 3;
  int r9 = grp % 9;
  if (r9 >= 5) {
    // ---- scattered passthrough: 1024 blocks, 16 rows each ----
    int pb = ((grp / 9) * 4 + (r9 - 5)) * 8 + (bid & 7);  // 0..1023
    int lane = tid & 63, w = tid >> 6;
    int base = pb * 16;
    for (int r = base + w; r < base + 16; r += 4) {
      if (flags[r]) continue;
      const float4* s = (const float4*)(x + (size_t)r * DDIM);
      float4* d = (float4*)(out + (size_t)r * DDIM);
#pragma unroll
      for (int i = 0; i < 4; ++i) d[lane + i * 64] = s[lane + i * 64];
    }
    return;
  }
  int g = ((grp / 9) * 5 + r9) * 8 + (bid & 7);  // 0..1279, g&7 == bid&7
  int lid = (g & 7) * (NWG / 8) + (g >> 3);
  int n = lid / 80;
  int rem = lid - n * 80;
  int mt = rem >> 3, dt = rem & 7;
  int M = m_sel[n];
  if (mt * 128 >= M) return;
  int lane = tid & 63, wid = tid >> 6;
  int wr = (wid >> 1) * 64, wc = (wid & 1) * 64;
  int rbase = tid >> 3;
  int c16 = tid & 7;
  const char* abase = (const char*)H + (((size_t)n * CAP + (size_t)mt * 128) * HDIM) * 2;
  const char* bbase = (const char*)w2t + (size_t)n * (DDIM * HDIM * 2);
  unsigned asrc[4], bsrc[4], ldsoff[4];
#pragma unroll
  for (int j = 0; j < 4; ++j) {
    int row = j * 32 + rbase;
    int gx = c16 ^ (row & 7);
    asrc[j] = (unsigned)row * 4096u + gx * 16;
    bsrc[j] = (unsigned)((dt * 2 + (row >> 6)) * 32) * 8192u +
              (unsigned)(row & 63) * 128u + gx * 16;
    ldsoff[j] = j * 4096 + wid * 1024;
  }
  unsigned aoff[2][4], boff[2][4];
#pragma unroll
  for (int kk = 0; kk < 2; ++kk) {
#pragma unroll
    for (int mi = 0; mi < 4; ++mi) {
      int row = wr + mi * 16 + (lane & 15);
      aoff[kk][mi] = row * 128 + (((kk * 4 + (lane >> 4)) ^ (row & 7)) * 16);
    }
#pragma unroll
    for (int ni = 0; ni < 4; ++ni) {
      int row = wc + ni * 16 + (lane & 15);
      boff[kk][ni] = row * 128 + (((kk * 4 + (lane >> 4)) ^ (row & 7)) * 16);
    }
  }
  f32x4 acc[4][4] = {};
#define STAGE2(buf, kt)                                                     \
  {                                                                         \
    unsigned koa = (unsigned)(kt) * 128u;                                   \
    unsigned kob = (unsigned)(kt) * 8192u;                                  \
    _Pragma("unroll") for (int j = 0; j < 4; ++j) {                         \
      GLD16(abase + (size_t)(asrc[j] + koa), (char*)As[buf] + ldsoff[j]);   \
      GLD16(bbase + (size_t)(bsrc[j] + kob), (char*)Bs[buf] + ldsoff[j]);   \
    }                                                                       \
  }
  STAGE2(0, 0);
  STAGE2(1, 1);
  int cur = 0;
  for (int kt = 0; kt < NT; ++kt) {
    if (kt < NT - 1) asm volatile("s_waitcnt vmcnt(8)" ::: "memory");
    else             asm volatile("s_waitcnt vmcnt(0)" ::: "memory");
    RAW_BARRIER();
    bf16x8 af[2][4], bfv[2][4];
#pragma unroll
    for (int kk = 0; kk < 2; ++kk) {
#pragma unroll
      for (int mi = 0; mi < 4; ++mi)
        af[kk][mi] = *(const bf16x8*)((const char*)As[cur] + aoff[kk][mi]);
#pragma unroll
      for (int ni = 0; ni < 4; ++ni)
        bfv[kk][ni] = *(const bf16x8*)((const char*)Bs[cur] + boff[kk][ni]);
    }
    asm volatile("s_waitcnt lgkmcnt(0)" ::: "memory");
    RAW_BARRIER();
    if (kt + 2 < NT) STAGE2(cur, kt + 2);
    __builtin_amdgcn_s_setprio(1);
#pragma unroll
    for (int kk = 0; kk < 2; ++kk)
#pragma unroll
      for (int mi = 0; mi < 4; ++mi)
#pragma unroll
        for (int ni = 0; ni < 4; ++ni)
          acc[mi][ni] = __builtin_amdgcn_mfma_f32_16x16x32_bf16(af[kk][mi], bfv[kk][ni], acc[mi][ni], 0, 0, 0);
    __builtin_amdgcn_s_setprio(0);
    cur ^= 1;
  }
  int rq = (lane >> 4) * 4;
  float bias[4];
#pragma unroll
  for (int ni = 0; ni < 4; ++ni)
    bias[ni] = b2[n * DDIM + dt * 128 + wc + ni * 16 + (lane & 15)];
#pragma unroll
  for (int mi = 0; mi < 4; ++mi) {
#pragma unroll
    for (int q = 0; q < 4; ++q) {
      int lr = wr + mi * 16 + rq + q;
      int s = mt * 128 + lr;
      if (s < M) {
        int tok = lists[n * CAP + s];
#pragma unroll
        for (int ni = 0; ni < 4; ++ni) {
          int dcol = dt * 128 + wc + ni * 16 + (lane & 15);
          out[(size_t)tok * DDIM + dcol] = acc[mi][ni][q] + bias[ni];
        }
      }
    }
  }
}

// ======================= SLOW PATH (ws fallback) ============================
__global__ __launch_bounds__(256) void ffn1_slow(
    const float* __restrict__ x, const float* __restrict__ W1, const float* __restrict__ b1,
    const int* __restrict__ m_sel, const int* __restrict__ lists,
    unsigned short* __restrict__ H) {
  __shared__ unsigned short Al[128 * APITCH];
  __shared__ unsigned short Bl[128 * APITCH];
  __shared__ int rows[128];
  int n = blockIdx.z, mt = blockIdx.y, ht = blockIdx.x;
  int M = m_sel[n];
  if (mt * 128 >= M) return;
  int tid = threadIdx.x;
  if (tid < 128) {
    int s = mt * 128 + tid;
    rows[tid] = lists[n * CAP + (s < M ? s : 0)];
  }
  __syncthreads();
  f32x4 acc[4][4] = {};
  int lane = tid & 63;
  int wid = tid >> 6;
  int wr = (wid >> 1) * 64, wc = (wid & 1) * 64;
  int ar = tid >> 4, ac = (tid & 15) * 4;
  int bh = tid & 127, bk8 = (tid >> 7) * 8;
  const size_t w1base = (size_t)n * DDIM * HDIM + (size_t)ht * 128;
  for (int kt = 0; kt < DDIM / 64; ++kt) {
#pragma unroll
    for (int i = 0; i < 8; ++i) {
      int r = ar + i * 16;
      float4 xv = *(const float4*)(x + (size_t)rows[r] * DDIM + kt * 64 + ac);
      unsigned plo = (unsigned)f2bf(xv.x) | ((unsigned)f2bf(xv.y) << 16);
      unsigned phi = (unsigned)f2bf(xv.z) | ((unsigned)f2bf(xv.w) << 16);
      *(uint2*)(&Al[r * APITCH + ac]) = make_uint2(plo, phi);
    }
#pragma unroll
    for (int i = 0; i < 4; ++i) {
      int k0 = bk8 + i * 16;
      const float* wp = W1 + w1base + (size_t)(kt * 64 + k0) * HDIM + bh;
      uint4 pk;
      pk.x = (unsigned)f2bf(wp[0]) | ((unsigned)f2bf(wp[HDIM]) << 16);
      pk.y = (unsigned)f2bf(wp[2 * HDIM]) | ((unsigned)f2bf(wp[3 * HDIM]) << 16);
      pk.z = (unsigned)f2bf(wp[4 * HDIM]) | ((unsigned)f2bf(wp[5 * HDIM]) << 16);
      pk.w = (unsigned)f2bf(wp[6 * HDIM]) | ((unsigned)f2bf(wp[7 * HDIM]) << 16);
      *(uint4*)(&Bl[bh * APITCH + k0]) = pk;
    }
    __syncthreads();
#pragma unroll
    for (int kk = 0; kk < 2; ++kk) {
      bf16x8 af[4], bfr[4];
#pragma unroll
      for (int mi = 0; mi < 4; ++mi)
        af[mi] = *(const bf16x8*)(&Al[(wr + mi * 16 + (lane & 15)) * APITCH + kk * 32 + (lane >> 4) * 8]);
#pragma unroll
      for (int ni = 0; ni < 4; ++ni)
        bfr[ni] = *(const bf16x8*)(&Bl[(wc + ni * 16 + (lane & 15)) * APITCH + kk * 32 + (lane >> 4) * 8]);
#pragma unroll
      for (int mi = 0; mi < 4; ++mi)
#pragma unroll
        for (int ni = 0; ni < 4; ++ni)
          acc[mi][ni] = __builtin_amdgcn_mfma_f32_16x16x32_bf16(af[mi], bfr[ni], acc[mi][ni], 0, 0, 0);
    }
    __syncthreads();
  }
  int rq = (lane >> 4) * 4;
#pragma unroll
  for (int ni = 0; ni < 4; ++ni) {
    int h = ht * 128 + wc + ni * 16 + (lane & 15);
    float bias = b1[n * HDIM + h];
#pragma unroll
    for (int mi = 0; mi < 4; ++mi) {
#pragma unroll
      for (int q = 0; q < 4; ++q) {
        int lr = wr + mi * 16 + rq + q;
        float val = acc[mi][ni][q] + bias;
        H[((size_t)n * CAP + mt * 128 + lr) * HDIM + h] = f2bf(fast_gelu(val));
      }
    }
  }
}

__global__ __launch_bounds__(256) void ffn2_slow(
    const unsigned short* __restrict__ H, const float* __restrict__ W2, const float* __restrict__ b2,
    const int* __restrict__ m_sel, const int* __restrict__ lists,
    float* __restrict__ out) {
  __shared__ unsigned short Al[128 * APITCH];
  __shared__ unsigned short Bl[128 * APITCH];
  __shared__ int rows[128];
  int n = blockIdx.z, mt = blockIdx.y, dt = blockIdx.x;
  int M = m_sel[n];
  if (mt * 128 >= M) return;
  int tid = threadIdx.x;
  if (tid < 128) {
    int s = mt * 128 + tid;
    rows[tid] = lists[n * CAP + (s < M ? s : 0)];
  }
  __syncthreads();
  f32x4 acc[4][4] = {};
  int lane = tid & 63;
  int wid = tid >> 6;
  int wr = (wid >> 1) * 64, wc = (wid & 1) * 64;
  int ar2 = tid >> 1, ak8 = (tid & 1) * 8;
  int bh = tid & 127, bk8 = (tid >> 7) * 8;
  const size_t hbase = ((size_t)n * CAP + (size_t)mt * 128) * HDIM;
  const size_t w2base = (size_t)n * HDIM * DDIM + (size_t)dt * 128;
  for (int kt = 0; kt < HDIM / 64; ++kt) {
#pragma unroll
    for (int i = 0; i < 4; ++i) {
      int k0 = ak8 + i * 16;
      uint4 hv = *(const uint4*)(H + hbase + (size_t)ar2 * HDIM + kt * 64 + k0);
      *(uint4*)(&Al[ar2 * APITCH + k0]) = hv;
    }
#pragma unroll
    for (int i = 0; i < 4; ++i) {
      int k0 = bk8 + i * 16;
      const float* wp = W2 + w2base + (size_t)(kt * 64 + k0) * DDIM + bh;
      uint4 pk;
      pk.x = (unsigned)f2bf(wp[0]) | ((unsigned)f2bf(wp[DDIM]) << 16);
      pk.y = (unsigned)f2bf(wp[2 * DDIM]) | ((unsigned)f2bf(wp[3 * DDIM]) << 16);
      pk.z = (unsigned)f2bf(wp[4 * DDIM]) | ((unsigned)f2bf(wp[5 * DDIM]) << 16);
      pk.w = (unsigned)f2bf(wp[6 * DDIM]) | ((unsigned)f2bf(wp[7 * DDIM]) << 16);
      *(uint4*)(&Bl[bh * APITCH + k0]) = pk;
    }
    __syncthreads();
#pragma unroll
    for (int kk = 0; kk < 2; ++kk) {
      bf16x8 af[4], bfr[4];
#pragma unroll
      for (int mi = 0; mi < 4; ++mi)
        af[mi] = *(const bf16x8*)(&Al[(wr + mi * 16 + (lane & 15)) * APITCH + kk * 32 + (lane >> 4) * 8]);
#pragma unroll
      for (int ni = 0; ni < 4; ++ni)
        bfr[ni] = *(const bf16x8*)(&Bl[(wc + ni * 16 + (lane & 15)) * APITCH + kk * 32 + (lane >> 4) * 8]);
#pragma unroll
      for (int mi = 0; mi < 4; ++mi)
#pragma unroll
        for (int ni = 0; ni < 4; ++ni)
          acc[mi][ni] = __builtin_amdgcn_mfma_f32_16x16x32_bf16(af[mi], bfr[ni], acc[mi][ni], 0, 0, 0);
    }
    __syncthreads();
  }
  int rq = (lane >> 4) * 4;
#pragma unroll
  for (int mi = 0; mi < 4; ++mi) {
#pragma unroll
    for (int q = 0; q < 4; ++q) {
      int lr = wr + mi * 16 + rq + q;
      int s = mt * 128 + lr;
      if (s < M) {
        int tok = rows[lr];
#pragma unroll
        for (int ni = 0; ni < 4; ++ni) {
          int dcol = dt * 128 + wc + ni * 16 + (lane & 15);
          out[(size_t)tok * DDIM + dcol] = acc[mi][ni][q] + b2[n * DDIM + dcol];
        }
      }
    }
  }
}

// ---------------- passthrough (slow path only) ------------------------------
__global__ __launch_bounds__(256) void passthrough_kernel(
    const float* __restrict__ x, const int* __restrict__ flags,
    float* __restrict__ out) {
  int lane = threadIdx.x & 63;
  int w = threadIdx.x >> 6;
  int base = blockIdx.x * 16;
  for (int r = base + w; r < base + 16; r += 4) {
    if (flags[r]) continue;
    const float4* s = (const float4*)(x + (size_t)r * DDIM);
    float4* d = (float4*)(out + (size_t)r * DDIM);
#pragma unroll
    for (int i = 0; i < 4; ++i) d[lane + i * 64] = s[lane + i * 64];
  }
}

extern "C" void kernel_launch(void* const* d_in, const int* in_sizes, int n_in,
                              void* d_out, int out_size, void* d_ws, size_t ws_size,
                              hipStream_t stream) {
  const float* x  = (const float*)d_in[0];
  const float* Wg = (const float*)d_in[1];
  const float* W1 = (const float*)d_in[2];
  const float* b1 = (const float*)d_in[3];
  const float* W2 = (const float*)d_in[4];
  const float* b2 = (const float*)d_in[5];
  float* out = (float*)d_out;
  char* ws = (char*)d_ws;
  int* counts = (int*)ws;
  int* m_sel  = (int*)(ws + 64);
  int* flags  = (int*)(ws + 128);
  int* e      = (int*)(ws + 128 + 4 * BT);
  float* v    = (float*)(ws + 128 + 8 * BT);
  int* lists  = (int*)(ws + 128 + 12 * BT);

  const size_t MB = 1024 * 1024;
  unsigned short* xb  = (unsigned short*)(ws + 1 * MB);
  unsigned short* w1t = (unsigned short*)(ws + 33 * MB);
  unsigned short* w2t = (unsigned short*)(ws + 97 * MB);
  unsigned short* Hf  = (unsigned short*)(ws + 161 * MB);
  bool fast = ws_size >= 242 * MB;

  zero_meta_kernel<<<1, 64, 0, stream>>>(counts);
  if (fast) {
    prep_kernel<<<256 + 8192, 256, 0, stream>>>(x, Wg, e, v, counts, xb, flags, W1, w1t);
    select_kernel<<<NEXP, 256, 0, stream>>>(e, v, counts, m_sel, lists, flags);
    ffn1_fast<<<4608, 256, 0, stream>>>(xb, w1t, b1, m_sel, lists, Hf, W2, w2t);
    ffn2_fast<<<2304, 256, 0, stream>>>(Hf, w2t, b2, m_sel, lists, out, x, flags);
  } else {
    unsigned short* Hs = (unsigned short*)(ws + 1 * MB);
    gate_kernel<<<BT / 64, 256, 0, stream>>>(x, Wg, e, v, counts, (unsigned short*)nullptr, flags);
    select_kernel<<<NEXP, 256, 0, stream>>>(e, v, counts, m_sel, lists, flags);
    ffn1_slow<<<dim3(HDIM / 128, CAP / 128, NEXP), 256, 0, stream>>>(x, W1, b1, m_sel, lists, Hs);
    ffn2_slow<<<dim3(DDIM / 128, CAP / 128, NEXP), 256, 0, stream>>>(Hs, W2, b2, m_sel, lists, out);
    passthrough_kernel<<<BT / 16, 256, 0, stream>>>(x, flags, out);
  }
}

// Round 21
// 338.436 us; speedup vs baseline: 1.1812x; 1.1329x over previous
//
#include <hip/hip_runtime.h>
#include <hip/hip_bf16.h>
#include <math.h>

#define BT 16384
#define DDIM 1024
#define NEXP 16
#define HDIM 2048
#define CAP 1280
#define APITCH 72
#define LBP 262  // bf16 LDS slab pitch for in-GEMM transpose tail

typedef __bf16 bf16x8 __attribute__((ext_vector_type(8)));
typedef float f32x4 __attribute__((ext_vector_type(4)));

__device__ __forceinline__ unsigned short f2bf(float f) {
  unsigned u = __float_as_uint(f);
  u += 0x7FFFu + ((u >> 16) & 1u);
  return (unsigned short)(u >> 16);
}

// HW packed fp32->bf16 (RNE, identical to f2bf): dst.lo=cvt(a), dst.hi=cvt(b)
__device__ __forceinline__ unsigned cvt_pk_bf16(float a, float b) {
  unsigned r;
  asm("v_cvt_pk_bf16_f32 %0, %1, %2" : "=v"(r) : "v"(a), "v"(b));
  return r;
}

// gelu(tanh approx) == v * sigmoid(2z); hardware v_exp_f32 path.
__device__ __forceinline__ float fast_gelu(float v) {
  float z = 0.7978845608028654f * (v + 0.044715f * v * v * v);
  return v / (1.0f + __expf(-2.0f * z));
}

#define GLD16(g, l)                                                        \
  __builtin_amdgcn_global_load_lds(                                        \
      (const __attribute__((address_space(1))) unsigned int*)(g),          \
      (__attribute__((address_space(3))) unsigned int*)(l), 16, 0, 0)

// Raw barrier without the vmcnt(0) drain __syncthreads would emit.
#define RAW_BARRIER()                          \
  {                                            \
    __builtin_amdgcn_sched_barrier(0);         \
    __builtin_amdgcn_s_barrier();              \
    __builtin_amdgcn_sched_barrier(0);         \
  }

__global__ void zero_meta_kernel(int* p) {
  int i = threadIdx.x;
  if (i < 32) p[i] = 0;  // counts[16] + m_sel[16]
}

// ---- slab transpose body: 64 rows x 256 cols fp32 -> 4 tiled 64x64 bf16
// tiles ([col][row] inside tile, 8KB each, 2x4KB contiguous bursts) ---------
__device__ __forceinline__ void slab_transpose(
    unsigned short* Lb, const float* src, int C,
    unsigned short* outp, size_t tile_base, int tmul, int by, int bxq, int tid) {
  int w = tid >> 6, lane = tid & 63;
#pragma unroll
  for (int k = 0; k < 16; ++k) {
    int row = w + k * 4;
    float4 vv = *(const float4*)(src + (size_t)row * C + lane * 4);
    unsigned p0 = cvt_pk_bf16(vv.x, vv.y);
    unsigned p1 = cvt_pk_bf16(vv.z, vv.w);
    *(uint2*)(&Lb[row * LBP + lane * 4]) = make_uint2(p0, p1);
  }
  __syncthreads();
  int oc_lo = tid >> 3;
  int rb = (tid & 7) * 8;
#pragma unroll
  for (int p2 = 0; p2 < 4; ++p2) {
    int bx = bxq * 4 + p2;
    char* dstT = (char*)outp + (tile_base + (size_t)bx * tmul + by) * 8192;
#pragma unroll
    for (int p = 0; p < 2; ++p) {
      int oc = p * 32 + oc_lo;
      const unsigned short* col = &Lb[rb * LBP + p2 * 64 + oc];
      unsigned short u[8];
#pragma unroll
      for (int j = 0; j < 8; ++j) u[j] = col[j * LBP];
      uint4 pk;
      pk.x = (unsigned)u[0] | ((unsigned)u[1] << 16);
      pk.y = (unsigned)u[2] | ((unsigned)u[3] << 16);
      pk.z = (unsigned)u[4] | ((unsigned)u[5] << 16);
      pk.w = (unsigned)u[6] | ((unsigned)u[7] << 16);
      *(uint4*)(dstT + p * 4096 + tid * 16) = pk;
    }
  }
}

// ======== fused prep: blocks [0,256) = gate (chunk-pipelined loads, T14);
// ========             blocks [256,8448) = W1 tiled transpose.
__global__ __launch_bounds__(256) void prep_kernel(
    const float* __restrict__ x, const float* __restrict__ Wg,
    int* __restrict__ e, float* __restrict__ v, int* __restrict__ counts,
    unsigned short* __restrict__ xb, int* __restrict__ flags,
    const float* __restrict__ W1, unsigned short* __restrict__ w1t) {
  __shared__ __align__(16) char smem[30016];
  int bid = blockIdx.x;
  int tid = threadIdx.x;
  if (bid < 256) {
    // ---------------- gate: 64 tokens/block, register-prefetched chunks -----
    float* xt = (float*)smem;                       // [64][68]  17408B
    double* lg = (double*)(smem + 17408);           // [64][16]   8192B
    float* wgt_c = (float*)(smem + 25600);          // [16][68]   4352B
    int* hcnt = (int*)(smem + 29952);               // [16]
    int t0 = bid * 64;
    if (tid < NEXP) hcnt[tid] = 0;
    if (tid < 64) flags[t0 + tid] = 0;
    int t = tid & 63, g = tid >> 6;
    double acc[4] = {0.0, 0.0, 0.0, 0.0};
    int sr = tid >> 4;
    int sc = (tid & 15) * 4;
    int wd = tid >> 2, wn = (tid & 3) * 4;
    // preload chunk 0 into registers
    float4 xr0, xr1, xr2, xr3, wgr;
    xr0 = *(const float4*)(x + (size_t)(t0 + sr +  0) * DDIM + sc);
    xr1 = *(const float4*)(x + (size_t)(t0 + sr + 16) * DDIM + sc);
    xr2 = *(const float4*)(x + (size_t)(t0 + sr + 32) * DDIM + sc);
    xr3 = *(const float4*)(x + (size_t)(t0 + sr + 48) * DDIM + sc);
    wgr = *(const float4*)(Wg + tid * 4);
    for (int ch = 0; ch < 16; ++ch) {
      __syncthreads();  // previous chunk's LDS consumers done
      // write-phase: regs -> LDS, regs -> xb
      {
        float4 xv = xr0; int r = sr;
        xt[r * 68 + sc + 0] = xv.x; xt[r * 68 + sc + 1] = xv.y;
        xt[r * 68 + sc + 2] = xv.z; xt[r * 68 + sc + 3] = xv.w;
        *(uint2*)(xb + (size_t)(t0 + r) * DDIM + ch * 64 + sc) =
            make_uint2(cvt_pk_bf16(xv.x, xv.y), cvt_pk_bf16(xv.z, xv.w));
        xv = xr1; r = sr + 16;
        xt[r * 68 + sc + 0] = xv.x; xt[r * 68 + sc + 1] = xv.y;
        xt[r * 68 + sc + 2] = xv.z; xt[r * 68 + sc + 3] = xv.w;
        *(uint2*)(xb + (size_t)(t0 + r) * DDIM + ch * 64 + sc) =
            make_uint2(cvt_pk_bf16(xv.x, xv.y), cvt_pk_bf16(xv.z, xv.w));
        xv = xr2; r = sr + 32;
        xt[r * 68 + sc + 0] = xv.x; xt[r * 68 + sc + 1] = xv.y;
        xt[r * 68 + sc + 2] = xv.z; xt[r * 68 + sc + 3] = xv.w;
        *(uint2*)(xb + (size_t)(t0 + r) * DDIM + ch * 64 + sc) =
            make_uint2(cvt_pk_bf16(xv.x, xv.y), cvt_pk_bf16(xv.z, xv.w));
        xv = xr3; r = sr + 48;
        xt[r * 68 + sc + 0] = xv.x; xt[r * 68 + sc + 1] = xv.y;
        xt[r * 68 + sc + 2] = xv.z; xt[r * 68 + sc + 3] = xv.w;
        *(uint2*)(xb + (size_t)(t0 + r) * DDIM + ch * 64 + sc) =
            make_uint2(cvt_pk_bf16(xv.x, xv.y), cvt_pk_bf16(xv.z, xv.w));
        wgt_c[(wn + 0) * 68 + wd] = wgr.x;
        wgt_c[(wn + 1) * 68 + wd] = wgr.y;
        wgt_c[(wn + 2) * 68 + wd] = wgr.z;
        wgt_c[(wn + 3) * 68 + wd] = wgr.w;
      }
      // issue next chunk's loads (latency hides under compute below)
      if (ch < 15) {
        int co = (ch + 1) * 64;
        xr0 = *(const float4*)(x + (size_t)(t0 + sr +  0) * DDIM + co + sc);
        xr1 = *(const float4*)(x + (size_t)(t0 + sr + 16) * DDIM + co + sc);
        xr2 = *(const float4*)(x + (size_t)(t0 + sr + 32) * DDIM + co + sc);
        xr3 = *(const float4*)(x + (size_t)(t0 + sr + 48) * DDIM + co + sc);
        wgr = *(const float4*)(Wg + (ch + 1) * 1024 + tid * 4);
      }
      __syncthreads();  // LDS writes visible
#pragma unroll
      for (int d4 = 0; d4 < 16; ++d4) {
        float4 xv = *(const float4*)(&xt[t * 68 + d4 * 4]);
#pragma unroll
        for (int j = 0; j < 4; ++j) {
          float4 wv = *(const float4*)(&wgt_c[(4 * g + j) * 68 + d4 * 4]);
          acc[j] += (double)xv.x * (double)wv.x + (double)xv.y * (double)wv.y +
                    (double)xv.z * (double)wv.z + (double)xv.w * (double)wv.w;
        }
      }
    }
#pragma unroll
    for (int j = 0; j < 4; ++j) lg[t * 16 + 4 * g + j] = acc[j];
    __syncthreads();
    if (tid < 64) {
      double mx = lg[tid * 16]; int bi = 0;
#pragma unroll
      for (int n = 1; n < NEXP; ++n)
        if (lg[tid * 16 + n] > mx) { mx = lg[tid * 16 + n]; bi = n; }
      double s = 0.0;
#pragma unroll
      for (int n = 0; n < NEXP; ++n) s += exp(lg[tid * 16 + n] - mx);
      e[t0 + tid] = bi;
      v[t0 + tid] = (float)(1.0 / s);
      atomicAdd(&hcnt[bi], 1);
    }
    __syncthreads();
    if (tid < NEXP && hcnt[tid] > 0) atomicAdd(&counts[tid], hcnt[tid]);
    return;
  }
  // ---------------- W1 transpose + fp32->bf16, tiled (R15 body) -------------
  float* tile = (float*)smem;  // [64][65]
  int b = bid - 256;  // 0..8191
  int n = b >> 9; int rem = b & 511; int by = rem >> 5, bx = rem & 31;
  size_t tile_off = ((size_t)n * 512 + (size_t)bx * 16 + by) * 8192;
  const float* src = W1 + (size_t)n * DDIM * HDIM;
  int r0 = by * 64, c0 = bx * 64;
  int lr = tid >> 2, lq = tid & 3;
#pragma unroll
  for (int i = 0; i < 4; ++i) {
    float4 vv = *(const float4*)(src + (size_t)(r0 + lr) * HDIM + c0 + i * 16 + lq * 4);
    *(float4*)(&tile[lr * 65 + i * 16 + lq * 4]) = vv;
  }
  __syncthreads();
  char* dstT = (char*)w1t + tile_off;
  int oc2 = tid >> 3, lq2 = tid & 7;
#pragma unroll
  for (int p = 0; p < 2; ++p) {
    int oc = p * 32 + oc2;
    int rb = lq2 * 8;
    uint4 pk;
    pk.x = cvt_pk_bf16(tile[(rb + 0) * 65 + oc], tile[(rb + 1) * 65 + oc]);
    pk.y = cvt_pk_bf16(tile[(rb + 2) * 65 + oc], tile[(rb + 3) * 65 + oc]);
    pk.z = cvt_pk_bf16(tile[(rb + 4) * 65 + oc], tile[(rb + 5) * 65 + oc]);
    pk.w = cvt_pk_bf16(tile[(rb + 6) * 65 + oc], tile[(rb + 7) * 65 + oc]);
    *(uint4*)(dstT + p * 4096 + tid * 16) = pk;
  }
}

// ---------------- select: per-expert token set under capacity ---------------
__global__ void select_kernel(const int* __restrict__ e, const float* __restrict__ v,
                              const int* __restrict__ counts, int* __restrict__ m_sel,
                              int* __restrict__ lists, int* __restrict__ flags) {
  int n = blockIdx.x;
  int tid = threadIdx.x;
  int cnt = counts[n];
  __shared__ int pos;
  if (tid == 0) pos = 0;
  __syncthreads();
  if (cnt <= CAP) {
    for (int t = tid; t < BT; t += 256) {
      if (e[t] == n) {
        int p = atomicAdd(&pos, 1);
        lists[n * CAP + p] = t;
        flags[t] = 1;
      }
    }
    __syncthreads();
    if (tid == 0) m_sel[n] = pos;
  } else {
    __shared__ int scnt;
    unsigned lo = 0u, hi = 0x7F800000u;
    while (hi - lo > 1u) {
      unsigned mid = lo + ((hi - lo) >> 1);
      if (tid == 0) scnt = 0;
      __syncthreads();
      int c = 0;
      for (int t = tid; t < BT; t += 256)
        if (e[t] == n && __float_as_uint(v[t]) >= mid) c++;
      atomicAdd(&scnt, c);
      __syncthreads();
      int tot = scnt;
      __syncthreads();
      if (tot >= CAP) lo = mid; else hi = mid;
    }
    for (int t = tid; t < BT; t += 256) {
      if (e[t] == n && __float_as_uint(v[t]) > lo) {
        int p = atomicAdd(&pos, 1);
        lists[n * CAP + p] = t;
        flags[t] = 1;
      }
    }
    __syncthreads();
    if (tid == 0) {
      int p = pos;
      for (int t = 0; t < BT && p < CAP; ++t) {
        if (e[t] == n && __float_as_uint(v[t]) == lo) {
          lists[n * CAP + p] = t; flags[t] = 1; ++p;
        }
      }
      m_sel[n] = p;
    }
  }
}

// ---------------- gate (slow path only, resident Wg table) ------------------
__global__ __launch_bounds__(256) void gate_kernel(
    const float* __restrict__ x, const float* __restrict__ Wg,
    int* __restrict__ e, float* __restrict__ v, int* __restrict__ counts,
    unsigned short* __restrict__ xb, int* __restrict__ flags) {
  __shared__ float wgt[NEXP][DDIM];
  __shared__ float xt[64][68];
  __shared__ double lg[64][NEXP];
  __shared__ int hcnt[NEXP];
  int tid = threadIdx.x;
  int t0 = blockIdx.x * 64;
  if (tid < NEXP) hcnt[tid] = 0;
  if (tid < 64) flags[t0 + tid] = 0;
  for (int i = tid; i < DDIM * NEXP / 4; i += 256) {
    int idx = i * 4;
    int d = idx >> 4, n = idx & 15;
    float4 w = *(const float4*)(Wg + idx);
    wgt[n + 0][d] = w.x; wgt[n + 1][d] = w.y;
    wgt[n + 2][d] = w.z; wgt[n + 3][d] = w.w;
  }
  int t = tid & 63, g = tid >> 6;
  double acc[4] = {0.0, 0.0, 0.0, 0.0};
  int sr = tid >> 4;
  int sc = (tid & 15) * 4;
  for (int ch = 0; ch < 16; ++ch) {
    __syncthreads();
#pragma unroll
    for (int i = 0; i < 4; ++i) {
      int r = sr + i * 16;
      float4 xv = *(const float4*)(x + (size_t)(t0 + r) * DDIM + ch * 64 + sc);
      xt[r][sc + 0] = xv.x; xt[r][sc + 1] = xv.y;
      xt[r][sc + 2] = xv.z; xt[r][sc + 3] = xv.w;
      if (xb) {
        unsigned p0 = cvt_pk_bf16(xv.x, xv.y);
        unsigned p1 = cvt_pk_bf16(xv.z, xv.w);
        *(uint2*)(xb + (size_t)(t0 + r) * DDIM + ch * 64 + sc) = make_uint2(p0, p1);
      }
    }
    __syncthreads();
#pragma unroll
    for (int d4 = 0; d4 < 16; ++d4) {
      float4 xv = *(const float4*)(&xt[t][d4 * 4]);
#pragma unroll
      for (int j = 0; j < 4; ++j) {
        float4 wv = *(const float4*)(&wgt[4 * g + j][ch * 64 + d4 * 4]);
        acc[j] += (double)xv.x * (double)wv.x + (double)xv.y * (double)wv.y +
                  (double)xv.z * (double)wv.z + (double)xv.w * (double)wv.w;
      }
    }
  }
#pragma unroll
  for (int j = 0; j < 4; ++j) lg[t][4 * g + j] = acc[j];
  __syncthreads();
  if (tid < 64) {
    double mx = lg[tid][0]; int bi = 0;
#pragma unroll
    for (int n = 1; n < NEXP; ++n)
      if (lg[tid][n] > mx) { mx = lg[tid][n]; bi = n; }
    double s = 0.0;
#pragma unroll
    for (int n = 0; n < NEXP; ++n) s += exp(lg[tid][n] - mx);
    e[t0 + tid] = bi;
    v[t0 + tid] = (float)(1.0 / s);
    atomicAdd(&hcnt[bi], 1);
  }
  __syncthreads();
  if (tid < NEXP && hcnt[tid] > 0) atomicAdd(&counts[tid], hcnt[tid]);
}

// ======================= FAST PATH (bf16 pre-converted) =====================
// R12 FFN structure. ffn1 grid = 4608 blocks with SCATTERED roles (period 9
// groups of 8: r<5 GEMM 2560, r>=5 W2 slab transpose 2048). ffn2 grid = 2304
// (r<5 GEMM 1280, r>=5 passthrough 1024). g&7 == bid&7 preserves XCD swizzle.

__global__ __launch_bounds__(256) void ffn1_fast(
    const unsigned short* __restrict__ xb, const unsigned short* __restrict__ w1t,
    const float* __restrict__ b1, const int* __restrict__ m_sel,
    const int* __restrict__ lists, unsigned short* __restrict__ H,
    const float* __restrict__ W2f, unsigned short* __restrict__ w2t) {
  __shared__ __align__(16) char smem[65536];
  unsigned short (*As)[8192] = (unsigned short(*)[8192])smem;
  unsigned short (*Bs)[8192] = (unsigned short(*)[8192])(smem + 32768);
  const int NWG = NEXP * 10 * 16;  // 2560
  const int NT = DDIM / 64;        // 16
  int bid = blockIdx.x;
  int tid = threadIdx.x;
  int grp = bid >> 3;
  int r9 = grp % 9;
  if (r9 >= 5) {
    // ---- W2 slab transpose: 32 h-tiles x 4 col-quads/expert (2048 blocks) --
    int b = ((grp / 9) * 4 + (r9 - 5)) * 8 + (bid & 7);  // 0..2047
    int n2 = b >> 7; int rem = b & 127; int by = rem >> 2, bxq = rem & 3;
    const float* src = W2f + (size_t)n2 * DDIM * HDIM + (size_t)by * 64 * DDIM + bxq * 256;
    slab_transpose((unsigned short*)smem, src, DDIM, w2t,
                   (size_t)n2 * 512, 32, by, bxq, tid);
    return;
  }
  int g = ((grp / 9) * 5 + r9) * 8 + (bid & 7);  // 0..2559, g&7 == bid&7
  int lid = (g & 7) * (NWG / 8) + (g >> 3);
  int n = lid / 160;
  int rem = lid - n * 160;
  int mt = rem >> 4, ht = rem & 15;
  int M = m_sel[n];
  if (mt * 128 >= M) return;
  int lane = tid & 63, wid = tid >> 6;
  int wr = (wid >> 1) * 64, wc = (wid & 1) * 64;
  int rbase = tid >> 3;
  int c16 = tid & 7;
  const char* xbase = (const char*)xb;
  const char* bbase = (const char*)w1t + (size_t)n * (DDIM * HDIM * 2);
  unsigned asrc[4], bsrc[4], ldsoff[4];
#pragma unroll
  for (int j = 0; j < 4; ++j) {
    int row = j * 32 + rbase;
    int gx = c16 ^ (row & 7);
    int s = mt * 128 + row;
    int tok = lists[n * CAP + (s < M ? s : 0)];
    asrc[j] = (unsigned)tok * 2048u + gx * 16;
    bsrc[j] = (unsigned)((ht * 2 + (row >> 6)) * 16) * 8192u +
              (unsigned)(row & 63) * 128u + gx * 16;
    ldsoff[j] = j * 4096 + wid * 1024;
  }
  unsigned aoff[2][4], boff[2][4];
#pragma unroll
  for (int kk = 0; kk < 2; ++kk) {
#pragma unroll
    for (int mi = 0; mi < 4; ++mi) {
      int row = wr + mi * 16 + (lane & 15);
      aoff[kk][mi] = row * 128 + (((kk * 4 + (lane >> 4)) ^ (row & 7)) * 16);
    }
#pragma unroll
    for (int ni = 0; ni < 4; ++ni) {
      int row = wc + ni * 16 + (lane & 15);
      boff[kk][ni] = row * 128 + (((kk * 4 + (lane >> 4)) ^ (row & 7)) * 16);
    }
  }
  f32x4 acc[4][4] = {};
#define STAGE1(buf, kt)                                                     \
  {                                                                         \
    unsigned koa = (unsigned)(kt) * 128u;                                   \
    unsigned kob = (unsigned)(kt) * 8192u;                                  \
    _Pragma("unroll") for (int j = 0; j < 4; ++j) {                         \
      GLD16(xbase + (size_t)(asrc[j] + koa), (char*)As[buf] + ldsoff[j]);   \
      GLD16(bbase + (size_t)(bsrc[j] + kob), (char*)Bs[buf] + ldsoff[j]);   \
    }                                                                       \
  }
  STAGE1(0, 0);
  STAGE1(1, 1);
  int cur = 0;
  for (int kt = 0; kt < NT; ++kt) {
    if (kt < NT - 1) asm volatile("s_waitcnt vmcnt(8)" ::: "memory");
    else             asm volatile("s_waitcnt vmcnt(0)" ::: "memory");
    RAW_BARRIER();
    bf16x8 af[2][4], bfv[2][4];
#pragma unroll
    for (int kk = 0; kk < 2; ++kk) {
#pragma unroll
      for (int mi = 0; mi < 4; ++mi)
        af[kk][mi] = *(const bf16x8*)((const char*)As[cur] + aoff[kk][mi]);
#pragma unroll
      for (int ni = 0; ni < 4; ++ni)
        bfv[kk][ni] = *(const bf16x8*)((const char*)Bs[cur] + boff[kk][ni]);
    }
    asm volatile("s_waitcnt lgkmcnt(0)" ::: "memory");
    RAW_BARRIER();
    if (kt + 2 < NT) STAGE1(cur, kt + 2);
    __builtin_amdgcn_s_setprio(1);
#pragma unroll
    for (int kk = 0; kk < 2; ++kk)
#pragma unroll
      for (int mi = 0; mi < 4; ++mi)
#pragma unroll
        for (int ni = 0; ni < 4; ++ni)
          acc[mi][ni] = __builtin_amdgcn_mfma_f32_16x16x32_bf16(af[kk][mi], bfv[kk][ni], acc[mi][ni], 0, 0, 0);
    __builtin_amdgcn_s_setprio(0);
    cur ^= 1;
  }
  int rq = (lane >> 4) * 4;
#pragma unroll
  for (int ni = 0; ni < 4; ++ni) {
    int h = ht * 128 + wc + ni * 16 + (lane & 15);
    float bias = b1[n * HDIM + h];
#pragma unroll
    for (int mi = 0; mi < 4; ++mi) {
#pragma unroll
      for (int q = 0; q < 4; ++q) {
        int lr = wr + mi * 16 + rq + q;
        float val = acc[mi][ni][q] + bias;
        H[((size_t)n * CAP + mt * 128 + lr) * HDIM + h] = f2bf(fast_gelu(val));
      }
    }
  }
}

__global__ __launch_bounds__(256) void ffn2_fast(
    const unsigned short* __restrict__ H, const unsigned short* __restrict__ w2t,
    const float* __restrict__ b2, const int* __restrict__ m_sel,
    const int* __restrict__ lists, float* __restrict__ out,
    const float* __restrict__ x, const int* __restrict__ flags) {
  __shared__ __align__(16) unsigned short As[2][128 * 64];
  __shared__ __align__(16) unsigned short Bs[2][128 * 64];
  const int NWG = NEXP * 10 * 8;  // 1280
  const int NT = HDIM / 64;       // 32
  int bid = blockIdx.x;
  int tid = threadIdx.x;
  int grp = bid >> 3;
  int r9 = grp % 9;
  if (r9 >= 5) {
    // ---- scattered passthrough: 1024 blocks, 16 rows each ----
    int pb = ((grp / 9) * 4 + (r9 - 5)) * 8 + (bid & 7);  // 0..1023
    int lane = tid & 63, w = tid >> 6;
    int base = pb * 16;
    for (int r = base + w; r < base + 16; r += 4) {
      if (flags[r]) continue;
      const float4* s = (const float4*)(x + (size_t)r * DDIM);
      float4* d = (float4*)(out + (size_t)r * DDIM);
#pragma unroll
      for (int i = 0; i < 4; ++i) d[lane + i * 64] = s[lane + i * 64];
    }
    return;
  }
  int g = ((grp / 9) * 5 + r9) * 8 + (bid & 7);  // 0..1279, g&7 == bid&7
  int lid = (g & 7) * (NWG / 8) + (g >> 3);
  int n = lid / 80;
  int rem = lid - n * 80;
  int mt = rem >> 3, dt = rem & 7;
  int M = m_sel[n];
  if (mt * 128 >= M) return;
  int lane = tid & 63, wid = tid >> 6;
  int wr = (wid >> 1) * 64, wc = (wid & 1) * 64;
  int rbase = tid >> 3;
  int c16 = tid & 7;
  const char* abase = (const char*)H + (((size_t)n * CAP + (size_t)mt * 128) * HDIM) * 2;
  const char* bbase = (const char*)w2t + (size_t)n * (DDIM * HDIM * 2);
  unsigned asrc[4], bsrc[4], ldsoff[4];
#pragma unroll
  for (int j = 0; j < 4; ++j) {
    int row = j * 32 + rbase;
    int gx = c16 ^ (row & 7);
    asrc[j] = (unsigned)row * 4096u + gx * 16;
    bsrc[j] = (unsigned)((dt * 2 + (row >> 6)) * 32) * 8192u +
              (unsigned)(row & 63) * 128u + gx * 16;
    ldsoff[j] = j * 4096 + wid * 1024;
  }
  unsigned aoff[2][4], boff[2][4];
#pragma unroll
  for (int kk = 0; kk < 2; ++kk) {
#pragma unroll
    for (int mi = 0; mi < 4; ++mi) {
      int row = wr + mi * 16 + (lane & 15);
      aoff[kk][mi] = row * 128 + (((kk * 4 + (lane >> 4)) ^ (row & 7)) * 16);
    }
#pragma unroll
    for (int ni = 0; ni < 4; ++ni) {
      int row = wc + ni * 16 + (lane & 15);
      boff[kk][ni] = row * 128 + (((kk * 4 + (lane >> 4)) ^ (row & 7)) * 16);
    }
  }
  f32x4 acc[4][4] = {};
#define STAGE2(buf, kt)                                                     \
  {                                                                         \
    unsigned koa = (unsigned)(kt) * 128u;                                   \
    unsigned kob = (unsigned)(kt) * 8192u;                                  \
    _Pragma("unroll") for (int j = 0; j < 4; ++j) {                         \
      GLD16(abase + (size_t)(asrc[j] + koa), (char*)As[buf] + ldsoff[j]);   \
      GLD16(bbase + (size_t)(bsrc[j] + kob), (char*)Bs[buf] + ldsoff[j]);   \
    }                                                                       \
  }
  STAGE2(0, 0);
  STAGE2(1, 1);
  int cur = 0;
  for (int kt = 0; kt < NT; ++kt) {
    if (kt < NT - 1) asm volatile("s_waitcnt vmcnt(8)" ::: "memory");
    else             asm volatile("s_waitcnt vmcnt(0)" ::: "memory");
    RAW_BARRIER();
    bf16x8 af[2][4], bfv[2][4];
#pragma unroll
    for (int kk = 0; kk < 2; ++kk) {
#pragma unroll
      for (int mi = 0; mi < 4; ++mi)
        af[kk][mi] = *(const bf16x8*)((const char*)As[cur] + aoff[kk][mi]);
#pragma unroll
      for (int ni = 0; ni < 4; ++ni)
        bfv[kk][ni] = *(const bf16x8*)((const char*)Bs[cur] + boff[kk][ni]);
    }
    asm volatile("s_waitcnt lgkmcnt(0)" ::: "memory");
    RAW_BARRIER();
    if (kt + 2 < NT) STAGE2(cur, kt + 2);
    __builtin_amdgcn_s_setprio(1);
#pragma unroll
    for (int kk = 0; kk < 2; ++kk)
#pragma unroll
      for (int mi = 0; mi < 4; ++mi)
#pragma unroll
        for (int ni = 0; ni < 4; ++ni)
          acc[mi][ni] = __builtin_amdgcn_mfma_f32_16x16x32_bf16(af[kk][mi], bfv[kk][ni], acc[mi][ni], 0, 0, 0);
    __builtin_amdgcn_s_setprio(0);
    cur ^= 1;
  }
  int rq = (lane >> 4) * 4;
  float bias[4];
#pragma unroll
  for (int ni = 0; ni < 4; ++ni)
    bias[ni] = b2[n * DDIM + dt * 128 + wc + ni * 16 + (lane & 15)];
#pragma unroll
  for (int mi = 0; mi < 4; ++mi) {
#pragma unroll
    for (int q = 0; q < 4; ++q) {
      int lr = wr + mi * 16 + rq + q;
      int s = mt * 128 + lr;
      if (s < M) {
        int tok = lists[n * CAP + s];
#pragma unroll
        for (int ni = 0; ni < 4; ++ni) {
          int dcol = dt * 128 + wc + ni * 16 + (lane & 15);
          out[(size_t)tok * DDIM + dcol] = acc[mi][ni][q] + bias[ni];
        }
      }
    }
  }
}

// ======================= SLOW PATH (ws fallback) ============================
__global__ __launch_bounds__(256) void ffn1_slow(
    const float* __restrict__ x, const float* __restrict__ W1, const float* __restrict__ b1,
    const int* __restrict__ m_sel, const int* __restrict__ lists,
    unsigned short* __restrict__ H) {
  __shared__ unsigned short Al[128 * APITCH];
  __shared__ unsigned short Bl[128 * APITCH];
  __shared__ int rows[128];
  int n = blockIdx.z, mt = blockIdx.y, ht = blockIdx.x;
  int M = m_sel[n];
  if (mt * 128 >= M) return;
  int tid = threadIdx.x;
  if (tid < 128) {
    int s = mt * 128 + tid;
    rows[tid] = lists[n * CAP + (s < M ? s : 0)];
  }
  __syncthreads();
  f32x4 acc[4][4] = {};
  int lane = tid & 63;
  int wid = tid >> 6;
  int wr = (wid >> 1) * 64, wc = (wid & 1) * 64;
  int ar = tid >> 4, ac = (tid & 15) * 4;
  int bh = tid & 127, bk8 = (tid >> 7) * 8;
  const size_t w1base = (size_t)n * DDIM * HDIM + (size_t)ht * 128;
  for (int kt = 0; kt < DDIM / 64; ++kt) {
#pragma unroll
    for (int i = 0; i < 8; ++i) {
      int r = ar + i * 16;
      float4 xv = *(const float4*)(x + (size_t)rows[r] * DDIM + kt * 64 + ac);
      unsigned plo = (unsigned)f2bf(xv.x) | ((unsigned)f2bf(xv.y) << 16);
      unsigned phi = (unsigned)f2bf(xv.z) | ((unsigned)f2bf(xv.w) << 16);
      *(uint2*)(&Al[r * APITCH + ac]) = make_uint2(plo, phi);
    }
#pragma unroll
    for (int i = 0; i < 4; ++i) {
      int k0 = bk8 + i * 16;
      const float* wp = W1 + w1base + (size_t)(kt * 64 + k0) * HDIM + bh;
      uint4 pk;
      pk.x = (unsigned)f2bf(wp[0]) | ((unsigned)f2bf(wp[HDIM]) << 16);
      pk.y = (unsigned)f2bf(wp[2 * HDIM]) | ((unsigned)f2bf(wp[3 * HDIM]) << 16);
      pk.z = (unsigned)f2bf(wp[4 * HDIM]) | ((unsigned)f2bf(wp[5 * HDIM]) << 16);
      pk.w = (unsigned)f2bf(wp[6 * HDIM]) | ((unsigned)f2bf(wp[7 * HDIM]) << 16);
      *(uint4*)(&Bl[bh * APITCH + k0]) = pk;
    }
    __syncthreads();
#pragma unroll
    for (int kk = 0; kk < 2; ++kk) {
      bf16x8 af[4], bfr[4];
#pragma unroll
      for (int mi = 0; mi < 4; ++mi)
        af[mi] = *(const bf16x8*)(&Al[(wr + mi * 16 + (lane & 15)) * APITCH + kk * 32 + (lane >> 4) * 8]);
#pragma unroll
      for (int ni = 0; ni < 4; ++ni)
        bfr[ni] = *(const bf16x8*)(&Bl[(wc + ni * 16 + (lane & 15)) * APITCH + kk * 32 + (lane >> 4) * 8]);
#pragma unroll
      for (int mi = 0; mi < 4; ++mi)
#pragma unroll
        for (int ni = 0; ni < 4; ++ni)
          acc[mi][ni] = __builtin_amdgcn_mfma_f32_16x16x32_bf16(af[mi], bfr[ni], acc[mi][ni], 0, 0, 0);
    }
    __syncthreads();
  }
  int rq = (lane >> 4) * 4;
#pragma unroll
  for (int ni = 0; ni < 4; ++ni) {
    int h = ht * 128 + wc + ni * 16 + (lane & 15);
    float bias = b1[n * HDIM + h];
#pragma unroll
    for (int mi = 0; mi < 4; ++mi) {
#pragma unroll
      for (int q = 0; q < 4; ++q) {
        int lr = wr + mi * 16 + rq + q;
        float val = acc[mi][ni][q] + bias;
        H[((size_t)n * CAP + mt * 128 + lr) * HDIM + h] = f2bf(fast_gelu(val));
      }
    }
  }
}

__global__ __launch_bounds__(256) void ffn2_slow(
    const unsigned short* __restrict__ H, const float* __restrict__ W2, const float* __restrict__ b2,
    const int* __restrict__ m_sel, const int* __restrict__ lists,
    float* __restrict__ out) {
  __shared__ unsigned short Al[128 * APITCH];
  __shared__ unsigned short Bl[128 * APITCH];
  __shared__ int rows[128];
  int n = blockIdx.z, mt = blockIdx.y, dt = blockIdx.x;
  int M = m_sel[n];
  if (mt * 128 >= M) return;
  int tid = threadIdx.x;
  if (tid < 128) {
    int s = mt * 128 + tid;
    rows[tid] = lists[n * CAP + (s < M ? s : 0)];
  }
  __syncthreads();
  f32x4 acc[4][4] = {};
  int lane = tid & 63;
  int wid = tid >> 6;
  int wr = (wid >> 1) * 64, wc = (wid & 1) * 64;
  int ar2 = tid >> 1, ak8 = (tid & 1) * 8;
  int bh = tid & 127, bk8 = (tid >> 7) * 8;
  const size_t hbase = ((size_t)n * CAP + (size_t)mt * 128) * HDIM;
  const size_t w2base = (size_t)n * HDIM * DDIM + (size_t)dt * 128;
  for (int kt = 0; kt < HDIM / 64; ++kt) {
#pragma unroll
    for (int i = 0; i < 4; ++i) {
      int k0 = ak8 + i * 16;
      uint4 hv = *(const uint4*)(H + hbase + (size_t)ar2 * HDIM + kt * 64 + k0);
      *(uint4*)(&Al[ar2 * APITCH + k0]) = hv;
    }
#pragma unroll
    for (int i = 0; i < 4; ++i) {
      int k0 = bk8 + i * 16;
      const float* wp = W2 + w2base + (size_t)(kt * 64 + k0) * DDIM + bh;
      uint4 pk;
      pk.x = (unsigned)f2bf(wp[0]) | ((unsigned)f2bf(wp[DDIM]) << 16);
      pk.y = (unsigned)f2bf(wp[2 * DDIM]) | ((unsigned)f2bf(wp[3 * DDIM]) << 16);
      pk.z = (unsigned)f2bf(wp[4 * DDIM]) | ((unsigned)f2bf(wp[5 * DDIM]) << 16);
      pk.w = (unsigned)f2bf(wp[6 * DDIM]) | ((unsigned)f2bf(wp[7 * DDIM]) << 16);
      *(uint4*)(&Bl[bh * APITCH + k0]) = pk;
    }
    __syncthreads();
#pragma unroll
    for (int kk = 0; kk < 2; ++kk) {
      bf16x8 af[4], bfr[4];
#pragma unroll
      for (int mi = 0; mi < 4; ++mi)
        af[mi] = *(const bf16x8*)(&Al[(wr + mi * 16 + (lane & 15)) * APITCH + kk * 32 + (lane >> 4) * 8]);
#pragma unroll
      for (int ni = 0; ni < 4; ++ni)
        bfr[ni] = *(const bf16x8*)(&Bl[(wc + ni * 16 + (lane & 15)) * APITCH + kk * 32 + (lane >> 4) * 8]);
#pragma unroll
      for (int mi = 0; mi < 4; ++mi)
#pragma unroll
        for (int ni = 0; ni < 4; ++ni)
          acc[mi][ni] = __builtin_amdgcn_mfma_f32_16x16x32_bf16(af[mi], bfr[ni], acc[mi][ni], 0, 0, 0);
    }
    __syncthreads();
  }
  int rq = (lane >> 4) * 4;
#pragma unroll
  for (int mi = 0; mi < 4; ++mi) {
#pragma unroll
    for (int q = 0; q < 4; ++q) {
      int lr = wr + mi * 16 + rq + q;
      int s = mt * 128 + lr;
      if (s < M) {
        int tok = rows[lr];
#pragma unroll
        for (int ni = 0; ni < 4; ++ni) {
          int dcol = dt * 128 + wc + ni * 16 + (lane & 15);
          out[(size_t)tok * DDIM + dcol] = acc[mi][ni][q] + b2[n * DDIM + dcol];
        }
      }
    }
  }
}

// ---------------- passthrough (slow path only) ------------------------------
__global__ __launch_bounds__(256) void passthrough_kernel(
    const float* __restrict__ x, const int* __restrict__ flags,
    float* __restrict__ out) {
  int lane = threadIdx.x & 63;
  int w = threadIdx.x >> 6;
  int base = blockIdx.x * 16;
  for (int r = base + w; r < base + 16; r += 4) {
    if (flags[r]) continue;
    const float4* s = (const float4*)(x + (size_t)r * DDIM);
    float4* d = (float4*)(out + (size_t)r * DDIM);
#pragma unroll
    for (int i = 0; i < 4; ++i) d[lane + i * 64] = s[lane + i * 64];
  }
}

extern "C" void kernel_launch(void* const* d_in, const int* in_sizes, int n_in,
                              void* d_out, int out_size, void* d_ws, size_t ws_size,
                              hipStream_t stream) {
  const float* x  = (const float*)d_in[0];
  const float* Wg = (const float*)d_in[1];
  const float* W1 = (const float*)d_in[2];
  const float* b1 = (const float*)d_in[3];
  const float* W2 = (const float*)d_in[4];
  const float* b2 = (const float*)d_in[5];
  float* out = (float*)d_out;
  char* ws = (char*)d_ws;
  int* counts = (int*)ws;
  int* m_sel  = (int*)(ws + 64);
  int* flags  = (int*)(ws + 128);
  int* e      = (int*)(ws + 128 + 4 * BT);
  float* v    = (float*)(ws + 128 + 8 * BT);
  int* lists  = (int*)(ws + 128 + 12 * BT);

  const size_t MB = 1024 * 1024;
  unsigned short* xb  = (unsigned short*)(ws + 1 * MB);
  unsigned short* w1t = (unsigned short*)(ws + 33 * MB);
  unsigned short* w2t = (unsigned short*)(ws + 97 * MB);
  unsigned short* Hf  = (unsigned short*)(ws + 161 * MB);
  bool fast = ws_size >= 242 * MB;

  zero_meta_kernel<<<1, 64, 0, stream>>>(counts);
  if (fast) {
    prep_kernel<<<256 + 8192, 256, 0, stream>>>(x, Wg, e, v, counts, xb, flags, W1, w1t);
    select_kernel<<<NEXP, 256, 0, stream>>>(e, v, counts, m_sel, lists, flags);
    ffn1_fast<<<4608, 256, 0, stream>>>(xb, w1t, b1, m_sel, lists, Hf, W2, w2t);
    ffn2_fast<<<2304, 256, 0, stream>>>(Hf, w2t, b2, m_sel, lists, out, x, flags);
  } else {
    unsigned short* Hs = (unsigned short*)(ws + 1 * MB);
    gate_kernel<<<BT / 64, 256, 0, stream>>>(x, Wg, e, v, counts, (unsigned short*)nullptr, flags);
    select_kernel<<<NEXP, 256, 0, stream>>>(e, v, counts, m_sel, lists, flags);
    ffn1_slow<<<dim3(HDIM / 128, CAP / 128, NEXP), 256, 0, stream>>>(x, W1, b1, m_sel, lists, Hs);
    ffn2_slow<<<dim3(DDIM / 128, CAP / 128, NEXP), 256, 0, stream>>>(Hs, W2, b2, m_sel, lists, out);
    passthrough_kernel<<<BT / 16, 256, 0, stream>>>(x, flags, out);
  }
}

// Round 22
// 321.976 us; speedup vs baseline: 1.2416x; 1.0511x over previous
//
#include <hip/hip_runtime.h>
#include <hip/hip_bf16.h>
#include <math.h>

#define BT 16384
#define DDIM 1024
#define NEXP 16
#define HDIM 2048
#define CAP 1280
#define APITCH 72
#define LBP 262  // bf16 LDS slab pitch for in-GEMM transpose tail

typedef __bf16 bf16x8 __attribute__((ext_vector_type(8)));
typedef float f32x4 __attribute__((ext_vector_type(4)));

__device__ __forceinline__ unsigned short f2bf(float f) {
  unsigned u = __float_as_uint(f);
  u += 0x7FFFu + ((u >> 16) & 1u);
  return (unsigned short)(u >> 16);
}

// HW packed fp32->bf16 (RNE, identical to f2bf): dst.lo=cvt(a), dst.hi=cvt(b)
__device__ __forceinline__ unsigned cvt_pk_bf16(float a, float b) {
  unsigned r;
  asm("v_cvt_pk_bf16_f32 %0, %1, %2" : "=v"(r) : "v"(a), "v"(b));
  return r;
}

// gelu(tanh approx) == v * sigmoid(2z); hardware v_exp_f32 path.
__device__ __forceinline__ float fast_gelu(float v) {
  float z = 0.7978845608028654f * (v + 0.044715f * v * v * v);
  return v / (1.0f + __expf(-2.0f * z));
}

#define GLD16(g, l)                                                        \
  __builtin_amdgcn_global_load_lds(                                        \
      (const __attribute__((address_space(1))) unsigned int*)(g),          \
      (__attribute__((address_space(3))) unsigned int*)(l), 16, 0, 0)

// Raw barrier without the vmcnt(0) drain __syncthreads would emit.
#define RAW_BARRIER()                          \
  {                                            \
    __builtin_amdgcn_sched_barrier(0);         \
    __builtin_amdgcn_s_barrier();              \
    __builtin_amdgcn_sched_barrier(0);         \
  }

// ---- slab transpose body: 64 rows x 256 cols fp32 -> 4 tiled 64x64 bf16
// tiles ([col][row] inside tile, 8KB each, 2x4KB contiguous bursts) ---------
__device__ __forceinline__ void slab_transpose(
    unsigned short* Lb, const float* src, int C,
    unsigned short* outp, size_t tile_base, int tmul, int by, int bxq, int tid) {
  int w = tid >> 6, lane = tid & 63;
#pragma unroll
  for (int k = 0; k < 16; ++k) {
    int row = w + k * 4;
    float4 vv = *(const float4*)(src + (size_t)row * C + lane * 4);
    unsigned p0 = cvt_pk_bf16(vv.x, vv.y);
    unsigned p1 = cvt_pk_bf16(vv.z, vv.w);
    *(uint2*)(&Lb[row * LBP + lane * 4]) = make_uint2(p0, p1);
  }
  __syncthreads();
  int oc_lo = tid >> 3;
  int rb = (tid & 7) * 8;
#pragma unroll
  for (int p2 = 0; p2 < 4; ++p2) {
    int bx = bxq * 4 + p2;
    char* dstT = (char*)outp + (tile_base + (size_t)bx * tmul + by) * 8192;
#pragma unroll
    for (int p = 0; p < 2; ++p) {
      int oc = p * 32 + oc_lo;
      const unsigned short* col = &Lb[rb * LBP + p2 * 64 + oc];
      unsigned short u[8];
#pragma unroll
      for (int j = 0; j < 8; ++j) u[j] = col[j * LBP];
      uint4 pk;
      pk.x = (unsigned)u[0] | ((unsigned)u[1] << 16);
      pk.y = (unsigned)u[2] | ((unsigned)u[3] << 16);
      pk.z = (unsigned)u[4] | ((unsigned)u[5] << 16);
      pk.w = (unsigned)u[6] | ((unsigned)u[7] << 16);
      *(uint4*)(dstT + p * 4096 + tid * 16) = pk;
    }
  }
}

// ======== fused prep: blocks [0,256) = gate (chunk-pipelined loads, T14);
// ========             blocks [256,8448) = W1 tiled transpose.
__global__ __launch_bounds__(256) void prep_kernel(
    const float* __restrict__ x, const float* __restrict__ Wg,
    int* __restrict__ e, float* __restrict__ v, int* __restrict__ counts,
    unsigned short* __restrict__ xb, int* __restrict__ flags,
    const float* __restrict__ W1, unsigned short* __restrict__ w1t) {
  __shared__ __align__(16) char smem[30016];
  int bid = blockIdx.x;
  int tid = threadIdx.x;
  if (bid < 256) {
    // ---------------- gate: 64 tokens/block, register-prefetched chunks -----
    float* xt = (float*)smem;                       // [64][68]  17408B
    double* lg = (double*)(smem + 17408);           // [64][16]   8192B
    float* wgt_c = (float*)(smem + 25600);          // [16][68]   4352B
    int* hcnt = (int*)(smem + 29952);               // [16]
    int t0 = bid * 64;
    if (tid < NEXP) hcnt[tid] = 0;
    if (tid < 64) flags[t0 + tid] = 0;
    int t = tid & 63, g = tid >> 6;
    double acc[4] = {0.0, 0.0, 0.0, 0.0};
    int sr = tid >> 4;
    int sc = (tid & 15) * 4;
    int wd = tid >> 2, wn = (tid & 3) * 4;
    // preload chunk 0 into registers
    float4 xr0, xr1, xr2, xr3, wgr;
    xr0 = *(const float4*)(x + (size_t)(t0 + sr +  0) * DDIM + sc);
    xr1 = *(const float4*)(x + (size_t)(t0 + sr + 16) * DDIM + sc);
    xr2 = *(const float4*)(x + (size_t)(t0 + sr + 32) * DDIM + sc);
    xr3 = *(const float4*)(x + (size_t)(t0 + sr + 48) * DDIM + sc);
    wgr = *(const float4*)(Wg + tid * 4);
    for (int ch = 0; ch < 16; ++ch) {
      __syncthreads();  // previous chunk's LDS consumers done
      // write-phase: regs -> LDS, regs -> xb
      {
        float4 xv = xr0; int r = sr;
        xt[r * 68 + sc + 0] = xv.x; xt[r * 68 + sc + 1] = xv.y;
        xt[r * 68 + sc + 2] = xv.z; xt[r * 68 + sc + 3] = xv.w;
        *(uint2*)(xb + (size_t)(t0 + r) * DDIM + ch * 64 + sc) =
            make_uint2(cvt_pk_bf16(xv.x, xv.y), cvt_pk_bf16(xv.z, xv.w));
        xv = xr1; r = sr + 16;
        xt[r * 68 + sc + 0] = xv.x; xt[r * 68 + sc + 1] = xv.y;
        xt[r * 68 + sc + 2] = xv.z; xt[r * 68 + sc + 3] = xv.w;
        *(uint2*)(xb + (size_t)(t0 + r) * DDIM + ch * 64 + sc) =
            make_uint2(cvt_pk_bf16(xv.x, xv.y), cvt_pk_bf16(xv.z, xv.w));
        xv = xr2; r = sr + 32;
        xt[r * 68 + sc + 0] = xv.x; xt[r * 68 + sc + 1] = xv.y;
        xt[r * 68 + sc + 2] = xv.z; xt[r * 68 + sc + 3] = xv.w;
        *(uint2*)(xb + (size_t)(t0 + r) * DDIM + ch * 64 + sc) =
            make_uint2(cvt_pk_bf16(xv.x, xv.y), cvt_pk_bf16(xv.z, xv.w));
        xv = xr3; r = sr + 48;
        xt[r * 68 + sc + 0] = xv.x; xt[r * 68 + sc + 1] = xv.y;
        xt[r * 68 + sc + 2] = xv.z; xt[r * 68 + sc + 3] = xv.w;
        *(uint2*)(xb + (size_t)(t0 + r) * DDIM + ch * 64 + sc) =
            make_uint2(cvt_pk_bf16(xv.x, xv.y), cvt_pk_bf16(xv.z, xv.w));
        wgt_c[(wn + 0) * 68 + wd] = wgr.x;
        wgt_c[(wn + 1) * 68 + wd] = wgr.y;
        wgt_c[(wn + 2) * 68 + wd] = wgr.z;
        wgt_c[(wn + 3) * 68 + wd] = wgr.w;
      }
      // issue next chunk's loads (latency hides under compute below)
      if (ch < 15) {
        int co = (ch + 1) * 64;
        xr0 = *(const float4*)(x + (size_t)(t0 + sr +  0) * DDIM + co + sc);
        xr1 = *(const float4*)(x + (size_t)(t0 + sr + 16) * DDIM + co + sc);
        xr2 = *(const float4*)(x + (size_t)(t0 + sr + 32) * DDIM + co + sc);
        xr3 = *(const float4*)(x + (size_t)(t0 + sr + 48) * DDIM + co + sc);
        wgr = *(const float4*)(Wg + (ch + 1) * 1024 + tid * 4);
      }
      __syncthreads();  // LDS writes visible
#pragma unroll
      for (int d4 = 0; d4 < 16; ++d4) {
        float4 xv = *(const float4*)(&xt[t * 68 + d4 * 4]);
#pragma unroll
        for (int j = 0; j < 4; ++j) {
          float4 wv = *(const float4*)(&wgt_c[(4 * g + j) * 68 + d4 * 4]);
          acc[j] += (double)xv.x * (double)wv.x + (double)xv.y * (double)wv.y +
                    (double)xv.z * (double)wv.z + (double)xv.w * (double)wv.w;
        }
      }
    }
#pragma unroll
    for (int j = 0; j < 4; ++j) lg[t * 16 + 4 * g + j] = acc[j];
    __syncthreads();
    if (tid < 64) {
      double mx = lg[tid * 16]; int bi = 0;
#pragma unroll
      for (int n = 1; n < NEXP; ++n)
        if (lg[tid * 16 + n] > mx) { mx = lg[tid * 16 + n]; bi = n; }
      double s = 0.0;
#pragma unroll
      for (int n = 0; n < NEXP; ++n) s += exp(lg[tid * 16 + n] - mx);
      e[t0 + tid] = bi;
      v[t0 + tid] = (float)(1.0 / s);
      atomicAdd(&hcnt[bi], 1);
    }
    __syncthreads();
    if (tid < NEXP && hcnt[tid] > 0) atomicAdd(&counts[tid], hcnt[tid]);
    return;
  }
  // ---------------- W1 transpose + fp32->bf16, tiled (R15 body) -------------
  float* tile = (float*)smem;  // [64][65]
  int b = bid - 256;  // 0..8191
  int n = b >> 9; int rem = b & 511; int by = rem >> 5, bx = rem & 31;
  size_t tile_off = ((size_t)n * 512 + (size_t)bx * 16 + by) * 8192;
  const float* src = W1 + (size_t)n * DDIM * HDIM;
  int r0 = by * 64, c0 = bx * 64;
  int lr = tid >> 2, lq = tid & 3;
#pragma unroll
  for (int i = 0; i < 4; ++i) {
    float4 vv = *(const float4*)(src + (size_t)(r0 + lr) * HDIM + c0 + i * 16 + lq * 4);
    *(float4*)(&tile[lr * 65 + i * 16 + lq * 4]) = vv;
  }
  __syncthreads();
  char* dstT = (char*)w1t + tile_off;
  int oc2 = tid >> 3, lq2 = tid & 7;
#pragma unroll
  for (int p = 0; p < 2; ++p) {
    int oc = p * 32 + oc2;
    int rb = lq2 * 8;
    uint4 pk;
    pk.x = cvt_pk_bf16(tile[(rb + 0) * 65 + oc], tile[(rb + 1) * 65 + oc]);
    pk.y = cvt_pk_bf16(tile[(rb + 2) * 65 + oc], tile[(rb + 3) * 65 + oc]);
    pk.z = cvt_pk_bf16(tile[(rb + 4) * 65 + oc], tile[(rb + 5) * 65 + oc]);
    pk.w = cvt_pk_bf16(tile[(rb + 6) * 65 + oc], tile[(rb + 7) * 65 + oc]);
    *(uint4*)(dstT + p * 4096 + tid * 16) = pk;
  }
}

// ---------------- select: per-expert token set, 1024-thread blocks ----------
__global__ __launch_bounds__(1024) void select_kernel(
    const int* __restrict__ e, const float* __restrict__ v,
    const int* __restrict__ counts, int* __restrict__ m_sel,
    int* __restrict__ lists, int* __restrict__ flags) {
  int n = blockIdx.x;
  int tid = threadIdx.x;
  int cnt = counts[n];
  __shared__ int pos;
  if (tid == 0) pos = 0;
  __syncthreads();
  if (cnt <= CAP) {
    for (int t = tid; t < BT; t += 1024) {
      if (e[t] == n) {
        int p = atomicAdd(&pos, 1);
        lists[n * CAP + p] = t;
        flags[t] = 1;
      }
    }
    __syncthreads();
    if (tid == 0) m_sel[n] = pos;
  } else {
    __shared__ int scnt;
    unsigned lo = 0u, hi = 0x7F800000u;
    while (hi - lo > 1u) {
      unsigned mid = lo + ((hi - lo) >> 1);
      if (tid == 0) scnt = 0;
      __syncthreads();
      int c = 0;
      for (int t = tid; t < BT; t += 1024)
        if (e[t] == n && __float_as_uint(v[t]) >= mid) c++;
      atomicAdd(&scnt, c);
      __syncthreads();
      int tot = scnt;
      __syncthreads();
      if (tot >= CAP) lo = mid; else hi = mid;
    }
    for (int t = tid; t < BT; t += 1024) {
      if (e[t] == n && __float_as_uint(v[t]) > lo) {
        int p = atomicAdd(&pos, 1);
        lists[n * CAP + p] = t;
        flags[t] = 1;
      }
    }
    __syncthreads();
    if (tid == 0) {
      int p = pos;
      for (int t = 0; t < BT && p < CAP; ++t) {
        if (e[t] == n && __float_as_uint(v[t]) == lo) {
          lists[n * CAP + p] = t; flags[t] = 1; ++p;
        }
      }
      m_sel[n] = p;
    }
  }
}

// ---------------- gate (slow path only, resident Wg table) ------------------
__global__ __launch_bounds__(256) void gate_kernel(
    const float* __restrict__ x, const float* __restrict__ Wg,
    int* __restrict__ e, float* __restrict__ v, int* __restrict__ counts,
    unsigned short* __restrict__ xb, int* __restrict__ flags) {
  __shared__ float wgt[NEXP][DDIM];
  __shared__ float xt[64][68];
  __shared__ double lg[64][NEXP];
  __shared__ int hcnt[NEXP];
  int tid = threadIdx.x;
  int t0 = blockIdx.x * 64;
  if (tid < NEXP) hcnt[tid] = 0;
  if (tid < 64) flags[t0 + tid] = 0;
  for (int i = tid; i < DDIM * NEXP / 4; i += 256) {
    int idx = i * 4;
    int d = idx >> 4, n = idx & 15;
    float4 w = *(const float4*)(Wg + idx);
    wgt[n + 0][d] = w.x; wgt[n + 1][d] = w.y;
    wgt[n + 2][d] = w.z; wgt[n + 3][d] = w.w;
  }
  int t = tid & 63, g = tid >> 6;
  double acc[4] = {0.0, 0.0, 0.0, 0.0};
  int sr = tid >> 4;
  int sc = (tid & 15) * 4;
  for (int ch = 0; ch < 16; ++ch) {
    __syncthreads();
#pragma unroll
    for (int i = 0; i < 4; ++i) {
      int r = sr + i * 16;
      float4 xv = *(const float4*)(x + (size_t)(t0 + r) * DDIM + ch * 64 + sc);
      xt[r][sc + 0] = xv.x; xt[r][sc + 1] = xv.y;
      xt[r][sc + 2] = xv.z; xt[r][sc + 3] = xv.w;
      if (xb) {
        unsigned p0 = cvt_pk_bf16(xv.x, xv.y);
        unsigned p1 = cvt_pk_bf16(xv.z, xv.w);
        *(uint2*)(xb + (size_t)(t0 + r) * DDIM + ch * 64 + sc) = make_uint2(p0, p1);
      }
    }
    __syncthreads();
#pragma unroll
    for (int d4 = 0; d4 < 16; ++d4) {
      float4 xv = *(const float4*)(&xt[t][d4 * 4]);
#pragma unroll
      for (int j = 0; j < 4; ++j) {
        float4 wv = *(const float4*)(&wgt[4 * g + j][ch * 64 + d4 * 4]);
        acc[j] += (double)xv.x * (double)wv.x + (double)xv.y * (double)wv.y +
                  (double)xv.z * (double)wv.z + (double)xv.w * (double)wv.w;
      }
    }
  }
#pragma unroll
  for (int j = 0; j < 4; ++j) lg[t][4 * g + j] = acc[j];
  __syncthreads();
  if (tid < 64) {
    double mx = lg[tid][0]; int bi = 0;
#pragma unroll
    for (int n = 1; n < NEXP; ++n)
      if (lg[tid][n] > mx) { mx = lg[tid][n]; bi = n; }
    double s = 0.0;
#pragma unroll
    for (int n = 0; n < NEXP; ++n) s += exp(lg[tid][n] - mx);
    e[t0 + tid] = bi;
    v[t0 + tid] = (float)(1.0 / s);
    atomicAdd(&hcnt[bi], 1);
  }
  __syncthreads();
  if (tid < NEXP && hcnt[tid] > 0) atomicAdd(&counts[tid], hcnt[tid]);
}

// ======================= FAST PATH (bf16 pre-converted) =====================
// R12 FFN structure. ffn1 grid = 4608 blocks with SCATTERED roles (period 9
// groups of 8: r<5 GEMM 2560, r>=5 W2 slab transpose 2048). ffn2 grid = 2304
// (r<5 GEMM 1280, r>=5 passthrough 1024). g&7 == bid&7 preserves XCD swizzle.

__global__ __launch_bounds__(256) void ffn1_fast(
    const unsigned short* __restrict__ xb, const unsigned short* __restrict__ w1t,
    const float* __restrict__ b1, const int* __restrict__ m_sel,
    const int* __restrict__ lists, unsigned short* __restrict__ H,
    const float* __restrict__ W2f, unsigned short* __restrict__ w2t) {
  __shared__ __align__(16) char smem[65536];
  unsigned short (*As)[8192] = (unsigned short(*)[8192])smem;
  unsigned short (*Bs)[8192] = (unsigned short(*)[8192])(smem + 32768);
  const int NWG = NEXP * 10 * 16;  // 2560
  const int NT = DDIM / 64;        // 16
  int bid = blockIdx.x;
  int tid = threadIdx.x;
  int grp = bid >> 3;
  int r9 = grp % 9;
  if (r9 >= 5) {
    // ---- W2 slab transpose: 32 h-tiles x 4 col-quads/expert (2048 blocks) --
    int b = ((grp / 9) * 4 + (r9 - 5)) * 8 + (bid & 7);  // 0..2047
    int n2 = b >> 7; int rem = b & 127; int by = rem >> 2, bxq = rem & 3;
    const float* src = W2f + (size_t)n2 * DDIM * HDIM + (size_t)by * 64 * DDIM + bxq * 256;
    slab_transpose((unsigned short*)smem, src, DDIM, w2t,
                   (size_t)n2 * 512, 32, by, bxq, tid);
    return;
  }
  int g = ((grp / 9) * 5 + r9) * 8 + (bid & 7);  // 0..2559, g&7 == bid&7
  int lid = (g & 7) * (NWG / 8) + (g >> 3);
  int n = lid / 160;
  int rem = lid - n * 160;
  int mt = rem >> 4, ht = rem & 15;
  int M = m_sel[n];
  if (mt * 128 >= M) return;
  int lane = tid & 63, wid = tid >> 6;
  int wr = (wid >> 1) * 64, wc = (wid & 1) * 64;
  int rbase = tid >> 3;
  int c16 = tid & 7;
  const char* xbase = (const char*)xb;
  const char* bbase = (const char*)w1t + (size_t)n * (DDIM * HDIM * 2);
  unsigned asrc[4], bsrc[4], ldsoff[4];
#pragma unroll
  for (int j = 0; j < 4; ++j) {
    int row = j * 32 + rbase;
    int gx = c16 ^ (row & 7);
    int s = mt * 128 + row;
    int tok = lists[n * CAP + (s < M ? s : 0)];
    asrc[j] = (unsigned)tok * 2048u + gx * 16;
    bsrc[j] = (unsigned)((ht * 2 + (row >> 6)) * 16) * 8192u +
              (unsigned)(row & 63) * 128u + gx * 16;
    ldsoff[j] = j * 4096 + wid * 1024;
  }
  unsigned aoff[2][4], boff[2][4];
#pragma unroll
  for (int kk = 0; kk < 2; ++kk) {
#pragma unroll
    for (int mi = 0; mi < 4; ++mi) {
      int row = wr + mi * 16 + (lane & 15);
      aoff[kk][mi] = row * 128 + (((kk * 4 + (lane >> 4)) ^ (row & 7)) * 16);
    }
#pragma unroll
    for (int ni = 0; ni < 4; ++ni) {
      int row = wc + ni * 16 + (lane & 15);
      boff[kk][ni] = row * 128 + (((kk * 4 + (lane >> 4)) ^ (row & 7)) * 16);
    }
  }
  f32x4 acc[4][4] = {};
#define STAGE1(buf, kt)                                                     \
  {                                                                         \
    unsigned koa = (unsigned)(kt) * 128u;                                   \
    unsigned kob = (unsigned)(kt) * 8192u;                                  \
    _Pragma("unroll") for (int j = 0; j < 4; ++j) {                         \
      GLD16(xbase + (size_t)(asrc[j] + koa), (char*)As[buf] + ldsoff[j]);   \
      GLD16(bbase + (size_t)(bsrc[j] + kob), (char*)Bs[buf] + ldsoff[j]);   \
    }                                                                       \
  }
  STAGE1(0, 0);
  STAGE1(1, 1);
  int cur = 0;
  for (int kt = 0; kt < NT; ++kt) {
    if (kt < NT - 1) asm volatile("s_waitcnt vmcnt(8)" ::: "memory");
    else             asm volatile("s_waitcnt vmcnt(0)" ::: "memory");
    RAW_BARRIER();
    bf16x8 af[2][4], bfv[2][4];
#pragma unroll
    for (int kk = 0; kk < 2; ++kk) {
#pragma unroll
      for (int mi = 0; mi < 4; ++mi)
        af[kk][mi] = *(const bf16x8*)((const char*)As[cur] + aoff[kk][mi]);
#pragma unroll
      for (int ni = 0; ni < 4; ++ni)
        bfv[kk][ni] = *(const bf16x8*)((const char*)Bs[cur] + boff[kk][ni]);
    }
    asm volatile("s_waitcnt lgkmcnt(0)" ::: "memory");
    RAW_BARRIER();
    if (kt + 2 < NT) STAGE1(cur, kt + 2);
    __builtin_amdgcn_s_setprio(1);
#pragma unroll
    for (int kk = 0; kk < 2; ++kk)
#pragma unroll
      for (int mi = 0; mi < 4; ++mi)
#pragma unroll
        for (int ni = 0; ni < 4; ++ni)
          acc[mi][ni] = __builtin_amdgcn_mfma_f32_16x16x32_bf16(af[kk][mi], bfv[kk][ni], acc[mi][ni], 0, 0, 0);
    __builtin_amdgcn_s_setprio(0);
    cur ^= 1;
  }
  int rq = (lane >> 4) * 4;
#pragma unroll
  for (int ni = 0; ni < 4; ++ni) {
    int h = ht * 128 + wc + ni * 16 + (lane & 15);
    float bias = b1[n * HDIM + h];
#pragma unroll
    for (int mi = 0; mi < 4; ++mi) {
#pragma unroll
      for (int q = 0; q < 4; ++q) {
        int lr = wr + mi * 16 + rq + q;
        float val = acc[mi][ni][q] + bias;
        H[((size_t)n * CAP + mt * 128 + lr) * HDIM + h] = f2bf(fast_gelu(val));
      }
    }
  }
}

__global__ __launch_bounds__(256) void ffn2_fast(
    const unsigned short* __restrict__ H, const unsigned short* __restrict__ w2t,
    const float* __restrict__ b2, const int* __restrict__ m_sel,
    const int* __restrict__ lists, float* __restrict__ out,
    const float* __restrict__ x, const int* __restrict__ flags) {
  __shared__ __align__(16) unsigned short As[2][128 * 64];
  __shared__ __align__(16) unsigned short Bs[2][128 * 64];
  const int NWG = NEXP * 10 * 8;  // 1280
  const int NT = HDIM / 64;       // 32
  int bid = blockIdx.x;
  int tid = threadIdx.x;
  int grp = bid >> 3;
  int r9 = grp % 9;
  if (r9 >= 5) {
    // ---- scattered passthrough: 1024 blocks, 16 rows each ----
    int pb = ((grp / 9) * 4 + (r9 - 5)) * 8 + (bid & 7);  // 0..1023
    int lane = tid & 63, w = tid >> 6;
    int base = pb * 16;
    for (int r = base + w; r < base + 16; r += 4) {
      if (flags[r]) continue;
      const float4* s = (const float4*)(x + (size_t)r * DDIM);
      float4* d = (float4*)(out + (size_t)r * DDIM);
#pragma unroll
      for (int i = 0; i < 4; ++i) d[lane + i * 64] = s[lane + i * 64];
    }
    return;
  }
  int g = ((grp / 9) * 5 + r9) * 8 + (bid & 7);  // 0..1279, g&7 == bid&7
  int lid = (g & 7) * (NWG / 8) + (g >> 3);
  int n = lid / 80;
  int rem = lid - n * 80;
  int mt = rem >> 3, dt = rem & 7;
  int M = m_sel[n];
  if (mt * 128 >= M) return;
  int lane = tid & 63, wid = tid >> 6;
  int wr = (wid >> 1) * 64, wc = (wid & 1) * 64;
  int rbase = tid >> 3;
  int c16 = tid & 7;
  const char* abase = (const char*)H + (((size_t)n * CAP + (size_t)mt * 128) * HDIM) * 2;
  const char* bbase = (const char*)w2t + (size_t)n * (DDIM * HDIM * 2);
  unsigned asrc[4], bsrc[4], ldsoff[4];
#pragma unroll
  for (int j = 0; j < 4; ++j) {
    int row = j * 32 + rbase;
    int gx = c16 ^ (row & 7);
    asrc[j] = (unsigned)row * 4096u + gx * 16;
    bsrc[j] = (unsigned)((dt * 2 + (row >> 6)) * 32) * 8192u +
              (unsigned)(row & 63) * 128u + gx * 16;
    ldsoff[j] = j * 4096 + wid * 1024;
  }
  unsigned aoff[2][4], boff[2][4];
#pragma unroll
  for (int kk = 0; kk < 2; ++kk) {
#pragma unroll
    for (int mi = 0; mi < 4; ++mi) {
      int row = wr + mi * 16 + (lane & 15);
      aoff[kk][mi] = row * 128 + (((kk * 4 + (lane >> 4)) ^ (row & 7)) * 16);
    }
#pragma unroll
    for (int ni = 0; ni < 4; ++ni) {
      int row = wc + ni * 16 + (lane & 15);
      boff[kk][ni] = row * 128 + (((kk * 4 + (lane >> 4)) ^ (row & 7)) * 16);
    }
  }
  f32x4 acc[4][4] = {};
#define STAGE2(buf, kt)                                                     \
  {                                                                         \
    unsigned koa = (unsigned)(kt) * 128u;                                   \
    unsigned kob = (unsigned)(kt) * 8192u;                                  \
    _Pragma("unroll") for (int j = 0; j < 4; ++j) {                         \
      GLD16(abase + (size_t)(asrc[j] + koa), (char*)As[buf] + ldsoff[j]);   \
      GLD16(bbase + (size_t)(bsrc[j] + kob), (char*)Bs[buf] + ldsoff[j]);   \
    }                                                                       \
  }
  STAGE2(0, 0);
  STAGE2(1, 1);
  int cur = 0;
  for (int kt = 0; kt < NT; ++kt) {
    if (kt < NT - 1) asm volatile("s_waitcnt vmcnt(8)" ::: "memory");
    else             asm volatile("s_waitcnt vmcnt(0)" ::: "memory");
    RAW_BARRIER();
    bf16x8 af[2][4], bfv[2][4];
#pragma unroll
    for (int kk = 0; kk < 2; ++kk) {
#pragma unroll
      for (int mi = 0; mi < 4; ++mi)
        af[kk][mi] = *(const bf16x8*)((const char*)As[cur] + aoff[kk][mi]);
#pragma unroll
      for (int ni = 0; ni < 4; ++ni)
        bfv[kk][ni] = *(const bf16x8*)((const char*)Bs[cur] + boff[kk][ni]);
    }
    asm volatile("s_waitcnt lgkmcnt(0)" ::: "memory");
    RAW_BARRIER();
    if (kt + 2 < NT) STAGE2(cur, kt + 2);
    __builtin_amdgcn_s_setprio(1);
#pragma unroll
    for (int kk = 0; kk < 2; ++kk)
#pragma unroll
      for (int mi = 0; mi < 4; ++mi)
#pragma unroll
        for (int ni = 0; ni < 4; ++ni)
          acc[mi][ni] = __builtin_amdgcn_mfma_f32_16x16x32_bf16(af[kk][mi], bfv[kk][ni], acc[mi][ni], 0, 0, 0);
    __builtin_amdgcn_s_setprio(0);
    cur ^= 1;
  }
  int rq = (lane >> 4) * 4;
  float bias[4];
#pragma unroll
  for (int ni = 0; ni < 4; ++ni)
    bias[ni] = b2[n * DDIM + dt * 128 + wc + ni * 16 + (lane & 15)];
#pragma unroll
  for (int mi = 0; mi < 4; ++mi) {
#pragma unroll
    for (int q = 0; q < 4; ++q) {
      int lr = wr + mi * 16 + rq + q;
      int s = mt * 128 + lr;
      if (s < M) {
        int tok = lists[n * CAP + s];
#pragma unroll
        for (int ni = 0; ni < 4; ++ni) {
          int dcol = dt * 128 + wc + ni * 16 + (lane & 15);
          out[(size_t)tok * DDIM + dcol] = acc[mi][ni][q] + bias[ni];
        }
      }
    }
  }
}

// ======================= SLOW PATH (ws fallback) ============================
__global__ __launch_bounds__(256) void ffn1_slow(
    const float* __restrict__ x, const float* __restrict__ W1, const float* __restrict__ b1,
    const int* __restrict__ m_sel, const int* __restrict__ lists,
    unsigned short* __restrict__ H) {
  __shared__ unsigned short Al[128 * APITCH];
  __shared__ unsigned short Bl[128 * APITCH];
  __shared__ int rows[128];
  int n = blockIdx.z, mt = blockIdx.y, ht = blockIdx.x;
  int M = m_sel[n];
  if (mt * 128 >= M) return;
  int tid = threadIdx.x;
  if (tid < 128) {
    int s = mt * 128 + tid;
    rows[tid] = lists[n * CAP + (s < M ? s : 0)];
  }
  __syncthreads();
  f32x4 acc[4][4] = {};
  int lane = tid & 63;
  int wid = tid >> 6;
  int wr = (wid >> 1) * 64, wc = (wid & 1) * 64;
  int ar = tid >> 4, ac = (tid & 15) * 4;
  int bh = tid & 127, bk8 = (tid >> 7) * 8;
  const size_t w1base = (size_t)n * DDIM * HDIM + (size_t)ht * 128;
  for (int kt = 0; kt < DDIM / 64; ++kt) {
#pragma unroll
    for (int i = 0; i < 8; ++i) {
      int r = ar + i * 16;
      float4 xv = *(const float4*)(x + (size_t)rows[r] * DDIM + kt * 64 + ac);
      unsigned plo = (unsigned)f2bf(xv.x) | ((unsigned)f2bf(xv.y) << 16);
      unsigned phi = (unsigned)f2bf(xv.z) | ((unsigned)f2bf(xv.w) << 16);
      *(uint2*)(&Al[r * APITCH + ac]) = make_uint2(plo, phi);
    }
#pragma unroll
    for (int i = 0; i < 4; ++i) {
      int k0 = bk8 + i * 16;
      const float* wp = W1 + w1base + (size_t)(kt * 64 + k0) * HDIM + bh;
      uint4 pk;
      pk.x = (unsigned)f2bf(wp[0]) | ((unsigned)f2bf(wp[HDIM]) << 16);
      pk.y = (unsigned)f2bf(wp[2 * HDIM]) | ((unsigned)f2bf(wp[3 * HDIM]) << 16);
      pk.z = (unsigned)f2bf(wp[4 * HDIM]) | ((unsigned)f2bf(wp[5 * HDIM]) << 16);
      pk.w = (unsigned)f2bf(wp[6 * HDIM]) | ((unsigned)f2bf(wp[7 * HDIM]) << 16);
      *(uint4*)(&Bl[bh * APITCH + k0]) = pk;
    }
    __syncthreads();
#pragma unroll
    for (int kk = 0; kk < 2; ++kk) {
      bf16x8 af[4], bfr[4];
#pragma unroll
      for (int mi = 0; mi < 4; ++mi)
        af[mi] = *(const bf16x8*)(&Al[(wr + mi * 16 + (lane & 15)) * APITCH + kk * 32 + (lane >> 4) * 8]);
#pragma unroll
      for (int ni = 0; ni < 4; ++ni)
        bfr[ni] = *(const bf16x8*)(&Bl[(wc + ni * 16 + (lane & 15)) * APITCH + kk * 32 + (lane >> 4) * 8]);
#pragma unroll
      for (int mi = 0; mi < 4; ++mi)
#pragma unroll
        for (int ni = 0; ni < 4; ++ni)
          acc[mi][ni] = __builtin_amdgcn_mfma_f32_16x16x32_bf16(af[mi], bfr[ni], acc[mi][ni], 0, 0, 0);
    }
    __syncthreads();
  }
  int rq = (lane >> 4) * 4;
#pragma unroll
  for (int ni = 0; ni < 4; ++ni) {
    int h = ht * 128 + wc + ni * 16 + (lane & 15);
    float bias = b1[n * HDIM + h];
#pragma unroll
    for (int mi = 0; mi < 4; ++mi) {
#pragma unroll
      for (int q = 0; q < 4; ++q) {
        int lr = wr + mi * 16 + rq + q;
        float val = acc[mi][ni][q] + bias;
        H[((size_t)n * CAP + mt * 128 + lr) * HDIM + h] = f2bf(fast_gelu(val));
      }
    }
  }
}

__global__ __launch_bounds__(256) void ffn2_slow(
    const unsigned short* __restrict__ H, const float* __restrict__ W2, const float* __restrict__ b2,
    const int* __restrict__ m_sel, const int* __restrict__ lists,
    float* __restrict__ out) {
  __shared__ unsigned short Al[128 * APITCH];
  __shared__ unsigned short Bl[128 * APITCH];
  __shared__ int rows[128];
  int n = blockIdx.z, mt = blockIdx.y, dt = blockIdx.x;
  int M = m_sel[n];
  if (mt * 128 >= M) return;
  int tid = threadIdx.x;
  if (tid < 128) {
    int s = mt * 128 + tid;
    rows[tid] = lists[n * CAP + (s < M ? s : 0)];
  }
  __syncthreads();
  f32x4 acc[4][4] = {};
  int lane = tid & 63;
  int wid = tid >> 6;
  int wr = (wid >> 1) * 64, wc = (wid & 1) * 64;
  int ar2 = tid >> 1, ak8 = (tid & 1) * 8;
  int bh = tid & 127, bk8 = (tid >> 7) * 8;
  const size_t hbase = ((size_t)n * CAP + (size_t)mt * 128) * HDIM;
  const size_t w2base = (size_t)n * HDIM * DDIM + (size_t)dt * 128;
  for (int kt = 0; kt < HDIM / 64; ++kt) {
#pragma unroll
    for (int i = 0; i < 4; ++i) {
      int k0 = ak8 + i * 16;
      uint4 hv = *(const uint4*)(H + hbase + (size_t)ar2 * HDIM + kt * 64 + k0);
      *(uint4*)(&Al[ar2 * APITCH + k0]) = hv;
    }
#pragma unroll
    for (int i = 0; i < 4; ++i) {
      int k0 = bk8 + i * 16;
      const float* wp = W2 + w2base + (size_t)(kt * 64 + k0) * DDIM + bh;
      uint4 pk;
      pk.x = (unsigned)f2bf(wp[0]) | ((unsigned)f2bf(wp[DDIM]) << 16);
      pk.y = (unsigned)f2bf(wp[2 * DDIM]) | ((unsigned)f2bf(wp[3 * DDIM]) << 16);
      pk.z = (unsigned)f2bf(wp[4 * DDIM]) | ((unsigned)f2bf(wp[5 * DDIM]) << 16);
      pk.w = (unsigned)f2bf(wp[6 * DDIM]) | ((unsigned)f2bf(wp[7 * DDIM]) << 16);
      *(uint4*)(&Bl[bh * APITCH + k0]) = pk;
    }
    __syncthreads();
#pragma unroll
    for (int kk = 0; kk < 2; ++kk) {
      bf16x8 af[4], bfr[4];
#pragma unroll
      for (int mi = 0; mi < 4; ++mi)
        af[mi] = *(const bf16x8*)(&Al[(wr + mi * 16 + (lane & 15)) * APITCH + kk * 32 + (lane >> 4) * 8]);
#pragma unroll
      for (int ni = 0; ni < 4; ++ni)
        bfr[ni] = *(const bf16x8*)(&Bl[(wc + ni * 16 + (lane & 15)) * APITCH + kk * 32 + (lane >> 4) * 8]);
#pragma unroll
      for (int mi = 0; mi < 4; ++mi)
#pragma unroll
        for (int ni = 0; ni < 4; ++ni)
          acc[mi][ni] = __builtin_amdgcn_mfma_f32_16x16x32_bf16(af[mi], bfr[ni], acc[mi][ni], 0, 0, 0);
    }
    __syncthreads();
  }
  int rq = (lane >> 4) * 4;
#pragma unroll
  for (int mi = 0; mi < 4; ++mi) {
#pragma unroll
    for (int q = 0; q < 4; ++q) {
      int lr = wr + mi * 16 + rq + q;
      int s = mt * 128 + lr;
      if (s < M) {
        int tok = rows[lr];
#pragma unroll
        for (int ni = 0; ni < 4; ++ni) {
          int dcol = dt * 128 + wc + ni * 16 + (lane & 15);
          out[(size_t)tok * DDIM + dcol] = acc[mi][ni][q] + b2[n * DDIM + dcol];
        }
      }
    }
  }
}

// ---------------- passthrough (slow path only) ------------------------------
__global__ __launch_bounds__(256) void passthrough_kernel(
    const float* __restrict__ x, const int* __restrict__ flags,
    float* __restrict__ out) {
  int lane = threadIdx.x & 63;
  int w = threadIdx.x >> 6;
  int base = blockIdx.x * 16;
  for (int r = base + w; r < base + 16; r += 4) {
    if (flags[r]) continue;
    const float4* s = (const float4*)(x + (size_t)r * DDIM);
    float4* d = (float4*)(out + (size_t)r * DDIM);
#pragma unroll
    for (int i = 0; i < 4; ++i) d[lane + i * 64] = s[lane + i * 64];
  }
}

extern "C" void kernel_launch(void* const* d_in, const int* in_sizes, int n_in,
                              void* d_out, int out_size, void* d_ws, size_t ws_size,
                              hipStream_t stream) {
  const float* x  = (const float*)d_in[0];
  const float* Wg = (const float*)d_in[1];
  const float* W1 = (const float*)d_in[2];
  const float* b1 = (const float*)d_in[3];
  const float* W2 = (const float*)d_in[4];
  const float* b2 = (const float*)d_in[5];
  float* out = (float*)d_out;
  char* ws = (char*)d_ws;
  int* counts = (int*)ws;
  int* m_sel  = (int*)(ws + 64);
  int* flags  = (int*)(ws + 128);
  int* e      = (int*)(ws + 128 + 4 * BT);
  float* v    = (float*)(ws + 128 + 8 * BT);
  int* lists  = (int*)(ws + 128 + 12 * BT);

  const size_t MB = 1024 * 1024;
  unsigned short* xb  = (unsigned short*)(ws + 1 * MB);
  unsigned short* w1t = (unsigned short*)(ws + 33 * MB);
  unsigned short* w2t = (unsigned short*)(ws + 97 * MB);
  unsigned short* Hf  = (unsigned short*)(ws + 161 * MB);
  bool fast = ws_size >= 242 * MB;

  hipMemsetAsync(ws, 0, 128, stream);  // counts[16] + m_sel[16]
  if (fast) {
    prep_kernel<<<256 + 8192, 256, 0, stream>>>(x, Wg, e, v, counts, xb, flags, W1, w1t);
    select_kernel<<<NEXP, 1024, 0, stream>>>(e, v, counts, m_sel, lists, flags);
    ffn1_fast<<<4608, 256, 0, stream>>>(xb, w1t, b1, m_sel, lists, Hf, W2, w2t);
    ffn2_fast<<<2304, 256, 0, stream>>>(Hf, w2t, b2, m_sel, lists, out, x, flags);
  } else {
    unsigned short* Hs = (unsigned short*)(ws + 1 * MB);
    gate_kernel<<<BT / 64, 256, 0, stream>>>(x, Wg, e, v, counts, (unsigned short*)nullptr, flags);
    select_kernel<<<NEXP, 1024, 0, stream>>>(e, v, counts, m_sel, lists, flags);
    ffn1_slow<<<dim3(HDIM / 128, CAP / 128, NEXP), 256, 0, stream>>>(x, W1, b1, m_sel, lists, Hs);
    ffn2_slow<<<dim3(DDIM / 128, CAP / 128, NEXP), 256, 0, stream>>>(Hs, W2, b2, m_sel, lists, out);
    passthrough_kernel<<<BT / 16, 256, 0, stream>>>(x, flags, out);
  }
}

// Round 23
// 293.284 us; speedup vs baseline: 1.3631x; 1.0978x over previous
//
#include <hip/hip_runtime.h>
#include <hip/hip_bf16.h>
#include <math.h>

#define BT 16384
#define DDIM 1024
#define NEXP 16
#define HDIM 2048
#define CAP 1280
#define APITCH 72
#define LBP 262  // bf16 LDS slab pitch for in-GEMM transpose tail

typedef __bf16 bf16x8 __attribute__((ext_vector_type(8)));
typedef float f32x4 __attribute__((ext_vector_type(4)));
typedef float f4v __attribute__((ext_vector_type(4)));  // for nontemporal ld/st

__device__ __forceinline__ unsigned short f2bf(float f) {
  unsigned u = __float_as_uint(f);
  u += 0x7FFFu + ((u >> 16) & 1u);
  return (unsigned short)(u >> 16);
}

// HW packed fp32->bf16 (RNE, identical to f2bf): dst.lo=cvt(a), dst.hi=cvt(b)
__device__ __forceinline__ unsigned cvt_pk_bf16(float a, float b) {
  unsigned r;
  asm("v_cvt_pk_bf16_f32 %0, %1, %2" : "=v"(r) : "v"(a), "v"(b));
  return r;
}

// gelu(tanh approx) == v * sigmoid(2z); hardware v_exp_f32 path.
__device__ __forceinline__ float fast_gelu(float v) {
  float z = 0.7978845608028654f * (v + 0.044715f * v * v * v);
  return v / (1.0f + __expf(-2.0f * z));
}

#define GLD16(g, l)                                                        \
  __builtin_amdgcn_global_load_lds(                                        \
      (const __attribute__((address_space(1))) unsigned int*)(g),          \
      (__attribute__((address_space(3))) unsigned int*)(l), 16, 0, 0)

// Raw barrier without the vmcnt(0) drain __syncthreads would emit.
#define RAW_BARRIER()                          \
  {                                            \
    __builtin_amdgcn_sched_barrier(0);         \
    __builtin_amdgcn_s_barrier();              \
    __builtin_amdgcn_sched_barrier(0);         \
  }

// ---- slab transpose body: 64 rows x 256 cols fp32 -> 4 tiled 64x64 bf16
// tiles. Source reads are NONTEMPORAL (single-use stream; don't evict the
// GEMM's hot xb/w1t panels from L2/L3 -- R22 diagnosis: ffn1 working set
// 372MB > 256MB L3, streaming W2f was the polluter). -----------------------
__device__ __forceinline__ void slab_transpose(
    unsigned short* Lb, const float* src, int C,
    unsigned short* outp, size_t tile_base, int tmul, int by, int bxq, int tid) {
  int w = tid >> 6, lane = tid & 63;
#pragma unroll
  for (int k = 0; k < 16; ++k) {
    int row = w + k * 4;
    f4v vv = __builtin_nontemporal_load((const f4v*)(src + (size_t)row * C + lane * 4));
    unsigned p0 = cvt_pk_bf16(vv[0], vv[1]);
    unsigned p1 = cvt_pk_bf16(vv[2], vv[3]);
    *(uint2*)(&Lb[row * LBP + lane * 4]) = make_uint2(p0, p1);
  }
  __syncthreads();
  int oc_lo = tid >> 3;
  int rb = (tid & 7) * 8;
#pragma unroll
  for (int p2 = 0; p2 < 4; ++p2) {
    int bx = bxq * 4 + p2;
    char* dstT = (char*)outp + (tile_base + (size_t)bx * tmul + by) * 8192;
#pragma unroll
    for (int p = 0; p < 2; ++p) {
      int oc = p * 32 + oc_lo;
      const unsigned short* col = &Lb[rb * LBP + p2 * 64 + oc];
      unsigned short u[8];
#pragma unroll
      for (int j = 0; j < 8; ++j) u[j] = col[j * LBP];
      uint4 pk;
      pk.x = (unsigned)u[0] | ((unsigned)u[1] << 16);
      pk.y = (unsigned)u[2] | ((unsigned)u[3] << 16);
      pk.z = (unsigned)u[4] | ((unsigned)u[5] << 16);
      pk.w = (unsigned)u[6] | ((unsigned)u[7] << 16);
      *(uint4*)(dstT + p * 4096 + tid * 16) = pk;
    }
  }
}

// ======== fused prep: blocks [0,256) = gate (chunk-pipelined loads, T14);
// ========             blocks [256,8448) = W1 tiled transpose (NT reads).
__global__ __launch_bounds__(256) void prep_kernel(
    const float* __restrict__ x, const float* __restrict__ Wg,
    int* __restrict__ e, float* __restrict__ v, int* __restrict__ counts,
    unsigned short* __restrict__ xb, int* __restrict__ flags,
    const float* __restrict__ W1, unsigned short* __restrict__ w1t) {
  __shared__ __align__(16) char smem[30016];
  int bid = blockIdx.x;
  int tid = threadIdx.x;
  if (bid < 256) {
    // ---------------- gate: 64 tokens/block, register-prefetched chunks -----
    float* xt = (float*)smem;                       // [64][68]  17408B
    double* lg = (double*)(smem + 17408);           // [64][16]   8192B
    float* wgt_c = (float*)(smem + 25600);          // [16][68]   4352B
    int* hcnt = (int*)(smem + 29952);               // [16]
    int t0 = bid * 64;
    if (tid < NEXP) hcnt[tid] = 0;
    if (tid < 64) flags[t0 + tid] = 0;
    int t = tid & 63, g = tid >> 6;
    double acc[4] = {0.0, 0.0, 0.0, 0.0};
    int sr = tid >> 4;
    int sc = (tid & 15) * 4;
    int wd = tid >> 2, wn = (tid & 3) * 4;
    // preload chunk 0 into registers
    float4 xr0, xr1, xr2, xr3, wgr;
    xr0 = *(const float4*)(x + (size_t)(t0 + sr +  0) * DDIM + sc);
    xr1 = *(const float4*)(x + (size_t)(t0 + sr + 16) * DDIM + sc);
    xr2 = *(const float4*)(x + (size_t)(t0 + sr + 32) * DDIM + sc);
    xr3 = *(const float4*)(x + (size_t)(t0 + sr + 48) * DDIM + sc);
    wgr = *(const float4*)(Wg + tid * 4);
    for (int ch = 0; ch < 16; ++ch) {
      __syncthreads();  // previous chunk's LDS consumers done
      // write-phase: regs -> LDS, regs -> xb
      {
        float4 xv = xr0; int r = sr;
        xt[r * 68 + sc + 0] = xv.x; xt[r * 68 + sc + 1] = xv.y;
        xt[r * 68 + sc + 2] = xv.z; xt[r * 68 + sc + 3] = xv.w;
        *(uint2*)(xb + (size_t)(t0 + r) * DDIM + ch * 64 + sc) =
            make_uint2(cvt_pk_bf16(xv.x, xv.y), cvt_pk_bf16(xv.z, xv.w));
        xv = xr1; r = sr + 16;
        xt[r * 68 + sc + 0] = xv.x; xt[r * 68 + sc + 1] = xv.y;
        xt[r * 68 + sc + 2] = xv.z; xt[r * 68 + sc + 3] = xv.w;
        *(uint2*)(xb + (size_t)(t0 + r) * DDIM + ch * 64 + sc) =
            make_uint2(cvt_pk_bf16(xv.x, xv.y), cvt_pk_bf16(xv.z, xv.w));
        xv = xr2; r = sr + 32;
        xt[r * 68 + sc + 0] = xv.x; xt[r * 68 + sc + 1] = xv.y;
        xt[r * 68 + sc + 2] = xv.z; xt[r * 68 + sc + 3] = xv.w;
        *(uint2*)(xb + (size_t)(t0 + r) * DDIM + ch * 64 + sc) =
            make_uint2(cvt_pk_bf16(xv.x, xv.y), cvt_pk_bf16(xv.z, xv.w));
        xv = xr3; r = sr + 48;
        xt[r * 68 + sc + 0] = xv.x; xt[r * 68 + sc + 1] = xv.y;
        xt[r * 68 + sc + 2] = xv.z; xt[r * 68 + sc + 3] = xv.w;
        *(uint2*)(xb + (size_t)(t0 + r) * DDIM + ch * 64 + sc) =
            make_uint2(cvt_pk_bf16(xv.x, xv.y), cvt_pk_bf16(xv.z, xv.w));
        wgt_c[(wn + 0) * 68 + wd] = wgr.x;
        wgt_c[(wn + 1) * 68 + wd] = wgr.y;
        wgt_c[(wn + 2) * 68 + wd] = wgr.z;
        wgt_c[(wn + 3) * 68 + wd] = wgr.w;
      }
      // issue next chunk's loads (latency hides under compute below)
      if (ch < 15) {
        int co = (ch + 1) * 64;
        xr0 = *(const float4*)(x + (size_t)(t0 + sr +  0) * DDIM + co + sc);
        xr1 = *(const float4*)(x + (size_t)(t0 + sr + 16) * DDIM + co + sc);
        xr2 = *(const float4*)(x + (size_t)(t0 + sr + 32) * DDIM + co + sc);
        xr3 = *(const float4*)(x + (size_t)(t0 + sr + 48) * DDIM + co + sc);
        wgr = *(const float4*)(Wg + (ch + 1) * 1024 + tid * 4);
      }
      __syncthreads();  // LDS writes visible
#pragma unroll
      for (int d4 = 0; d4 < 16; ++d4) {
        float4 xv = *(const float4*)(&xt[t * 68 + d4 * 4]);
#pragma unroll
        for (int j = 0; j < 4; ++j) {
          float4 wv = *(const float4*)(&wgt_c[(4 * g + j) * 68 + d4 * 4]);
          acc[j] += (double)xv.x * (double)wv.x + (double)xv.y * (double)wv.y +
                    (double)xv.z * (double)wv.z + (double)xv.w * (double)wv.w;
        }
      }
    }
#pragma unroll
    for (int j = 0; j < 4; ++j) lg[t * 16 + 4 * g + j] = acc[j];
    __syncthreads();
    if (tid < 64) {
      double mx = lg[tid * 16]; int bi = 0;
#pragma unroll
      for (int n = 1; n < NEXP; ++n)
        if (lg[tid * 16 + n] > mx) { mx = lg[tid * 16 + n]; bi = n; }
      double s = 0.0;
#pragma unroll
      for (int n = 0; n < NEXP; ++n) s += exp(lg[tid * 16 + n] - mx);
      e[t0 + tid] = bi;
      v[t0 + tid] = (float)(1.0 / s);
      atomicAdd(&hcnt[bi], 1);
    }
    __syncthreads();
    if (tid < NEXP && hcnt[tid] > 0) atomicAdd(&counts[tid], hcnt[tid]);
    return;
  }
  // ---------------- W1 transpose + fp32->bf16, tiled (NT source reads) ------
  float* tile = (float*)smem;  // [64][65]
  int b = bid - 256;  // 0..8191
  int n = b >> 9; int rem = b & 511; int by = rem >> 5, bx = rem & 31;
  size_t tile_off = ((size_t)n * 512 + (size_t)bx * 16 + by) * 8192;
  const float* src = W1 + (size_t)n * DDIM * HDIM;
  int r0 = by * 64, c0 = bx * 64;
  int lr = tid >> 2, lq = tid & 3;
#pragma unroll
  for (int i = 0; i < 4; ++i) {
    f4v vv = __builtin_nontemporal_load(
        (const f4v*)(src + (size_t)(r0 + lr) * HDIM + c0 + i * 16 + lq * 4));
    *(f4v*)(&tile[lr * 65 + i * 16 + lq * 4]) = vv;
  }
  __syncthreads();
  char* dstT = (char*)w1t + tile_off;
  int oc2 = tid >> 3, lq2 = tid & 7;
#pragma unroll
  for (int p = 0; p < 2; ++p) {
    int oc = p * 32 + oc2;
    int rb = lq2 * 8;
    uint4 pk;
    pk.x = cvt_pk_bf16(tile[(rb + 0) * 65 + oc], tile[(rb + 1) * 65 + oc]);
    pk.y = cvt_pk_bf16(tile[(rb + 2) * 65 + oc], tile[(rb + 3) * 65 + oc]);
    pk.z = cvt_pk_bf16(tile[(rb + 4) * 65 + oc], tile[(rb + 5) * 65 + oc]);
    pk.w = cvt_pk_bf16(tile[(rb + 6) * 65 + oc], tile[(rb + 7) * 65 + oc]);
    *(uint4*)(dstT + p * 4096 + tid * 16) = pk;
  }
}

// ---------------- select: per-expert token set, 1024-thread blocks ----------
__global__ __launch_bounds__(1024) void select_kernel(
    const int* __restrict__ e, const float* __restrict__ v,
    const int* __restrict__ counts, int* __restrict__ m_sel,
    int* __restrict__ lists, int* __restrict__ flags) {
  int n = blockIdx.x;
  int tid = threadIdx.x;
  int cnt = counts[n];
  __shared__ int pos;
  if (tid == 0) pos = 0;
  __syncthreads();
  if (cnt <= CAP) {
    for (int t = tid; t < BT; t += 1024) {
      if (e[t] == n) {
        int p = atomicAdd(&pos, 1);
        lists[n * CAP + p] = t;
        flags[t] = 1;
      }
    }
    __syncthreads();
    if (tid == 0) m_sel[n] = pos;
  } else {
    __shared__ int scnt;
    unsigned lo = 0u, hi = 0x7F800000u;
    while (hi - lo > 1u) {
      unsigned mid = lo + ((hi - lo) >> 1);
      if (tid == 0) scnt = 0;
      __syncthreads();
      int c = 0;
      for (int t = tid; t < BT; t += 1024)
        if (e[t] == n && __float_as_uint(v[t]) >= mid) c++;
      atomicAdd(&scnt, c);
      __syncthreads();
      int tot = scnt;
      __syncthreads();
      if (tot >= CAP) lo = mid; else hi = mid;
    }
    for (int t = tid; t < BT; t += 1024) {
      if (e[t] == n && __float_as_uint(v[t]) > lo) {
        int p = atomicAdd(&pos, 1);
        lists[n * CAP + p] = t;
        flags[t] = 1;
      }
    }
    __syncthreads();
    if (tid == 0) {
      int p = pos;
      for (int t = 0; t < BT && p < CAP; ++t) {
        if (e[t] == n && __float_as_uint(v[t]) == lo) {
          lists[n * CAP + p] = t; flags[t] = 1; ++p;
        }
      }
      m_sel[n] = p;
    }
  }
}

// ---------------- gate (slow path only, resident Wg table) ------------------
__global__ __launch_bounds__(256) void gate_kernel(
    const float* __restrict__ x, const float* __restrict__ Wg,
    int* __restrict__ e, float* __restrict__ v, int* __restrict__ counts,
    unsigned short* __restrict__ xb, int* __restrict__ flags) {
  __shared__ float wgt[NEXP][DDIM];
  __shared__ float xt[64][68];
  __shared__ double lg[64][NEXP];
  __shared__ int hcnt[NEXP];
  int tid = threadIdx.x;
  int t0 = blockIdx.x * 64;
  if (tid < NEXP) hcnt[tid] = 0;
  if (tid < 64) flags[t0 + tid] = 0;
  for (int i = tid; i < DDIM * NEXP / 4; i += 256) {
    int idx = i * 4;
    int d = idx >> 4, n = idx & 15;
    float4 w = *(const float4*)(Wg + idx);
    wgt[n + 0][d] = w.x; wgt[n + 1][d] = w.y;
    wgt[n + 2][d] = w.z; wgt[n + 3][d] = w.w;
  }
  int t = tid & 63, g = tid >> 6;
  double acc[4] = {0.0, 0.0, 0.0, 0.0};
  int sr = tid >> 4;
  int sc = (tid & 15) * 4;
  for (int ch = 0; ch < 16; ++ch) {
    __syncthreads();
#pragma unroll
    for (int i = 0; i < 4; ++i) {
      int r = sr + i * 16;
      float4 xv = *(const float4*)(x + (size_t)(t0 + r) * DDIM + ch * 64 + sc);
      xt[r][sc + 0] = xv.x; xt[r][sc + 1] = xv.y;
      xt[r][sc + 2] = xv.z; xt[r][sc + 3] = xv.w;
      if (xb) {
        unsigned p0 = cvt_pk_bf16(xv.x, xv.y);
        unsigned p1 = cvt_pk_bf16(xv.z, xv.w);
        *(uint2*)(xb + (size_t)(t0 + r) * DDIM + ch * 64 + sc) = make_uint2(p0, p1);
      }
    }
    __syncthreads();
#pragma unroll
    for (int d4 = 0; d4 < 16; ++d4) {
      float4 xv = *(const float4*)(&xt[t][d4 * 4]);
#pragma unroll
      for (int j = 0; j < 4; ++j) {
        float4 wv = *(const float4*)(&wgt[4 * g + j][ch * 64 + d4 * 4]);
        acc[j] += (double)xv.x * (double)wv.x + (double)xv.y * (double)wv.y +
                  (double)xv.z * (double)wv.z + (double)xv.w * (double)wv.w;
      }
    }
  }
#pragma unroll
  for (int j = 0; j < 4; ++j) lg[t][4 * g + j] = acc[j];
  __syncthreads();
  if (tid < 64) {
    double mx = lg[tid][0]; int bi = 0;
#pragma unroll
    for (int n = 1; n < NEXP; ++n)
      if (lg[tid][n] > mx) { mx = lg[tid][n]; bi = n; }
    double s = 0.0;
#pragma unroll
    for (int n = 0; n < NEXP; ++n) s += exp(lg[tid][n] - mx);
    e[t0 + tid] = bi;
    v[t0 + tid] = (float)(1.0 / s);
    atomicAdd(&hcnt[bi], 1);
  }
  __syncthreads();
  if (tid < NEXP && hcnt[tid] > 0) atomicAdd(&counts[tid], hcnt[tid]);
}

// ======================= FAST PATH (bf16 pre-converted) =====================
// R12 FFN structure. ffn1 grid = 4608 blocks with SCATTERED roles (period 9
// groups of 8: r<5 GEMM 2560, r>=5 W2 slab transpose 2048). ffn2 grid = 2304
// (r<5 GEMM 1280, r>=5 passthrough 1024). g&7 == bid&7 preserves XCD swizzle.

__global__ __launch_bounds__(256) void ffn1_fast(
    const unsigned short* __restrict__ xb, const unsigned short* __restrict__ w1t,
    const float* __restrict__ b1, const int* __restrict__ m_sel,
    const int* __restrict__ lists, unsigned short* __restrict__ H,
    const float* __restrict__ W2f, unsigned short* __restrict__ w2t) {
  __shared__ __align__(16) char smem[65536];
  unsigned short (*As)[8192] = (unsigned short(*)[8192])smem;
  unsigned short (*Bs)[8192] = (unsigned short(*)[8192])(smem + 32768);
  const int NWG = NEXP * 10 * 16;  // 2560
  const int NT = DDIM / 64;        // 16
  int bid = blockIdx.x;
  int tid = threadIdx.x;
  int grp = bid >> 3;
  int r9 = grp % 9;
  if (r9 >= 5) {
    // ---- W2 slab transpose: 32 h-tiles x 4 col-quads/expert (2048 blocks) --
    int b = ((grp / 9) * 4 + (r9 - 5)) * 8 + (bid & 7);  // 0..2047
    int n2 = b >> 7; int rem = b & 127; int by = rem >> 2, bxq = rem & 3;
    const float* src = W2f + (size_t)n2 * DDIM * HDIM + (size_t)by * 64 * DDIM + bxq * 256;
    slab_transpose((unsigned short*)smem, src, DDIM, w2t,
                   (size_t)n2 * 512, 32, by, bxq, tid);
    return;
  }
  int g = ((grp / 9) * 5 + r9) * 8 + (bid & 7);  // 0..2559, g&7 == bid&7
  int lid = (g & 7) * (NWG / 8) + (g >> 3);
  int n = lid / 160;
  int rem = lid - n * 160;
  int mt = rem >> 4, ht = rem & 15;
  int M = m_sel[n];
  if (mt * 128 >= M) return;
  int lane = tid & 63, wid = tid >> 6;
  int wr = (wid >> 1) * 64, wc = (wid & 1) * 64;
  int rbase = tid >> 3;
  int c16 = tid & 7;
  const char* xbase = (const char*)xb;
  const char* bbase = (const char*)w1t + (size_t)n * (DDIM * HDIM * 2);
  unsigned asrc[4], bsrc[4], ldsoff[4];
#pragma unroll
  for (int j = 0; j < 4; ++j) {
    int row = j * 32 + rbase;
    int gx = c16 ^ (row & 7);
    int s = mt * 128 + row;
    int tok = lists[n * CAP + (s < M ? s : 0)];
    asrc[j] = (unsigned)tok * 2048u + gx * 16;
    bsrc[j] = (unsigned)((ht * 2 + (row >> 6)) * 16) * 8192u +
              (unsigned)(row & 63) * 128u + gx * 16;
    ldsoff[j] = j * 4096 + wid * 1024;
  }
  unsigned aoff[2][4], boff[2][4];
#pragma unroll
  for (int kk = 0; kk < 2; ++kk) {
#pragma unroll
    for (int mi = 0; mi < 4; ++mi) {
      int row = wr + mi * 16 + (lane & 15);
      aoff[kk][mi] = row * 128 + (((kk * 4 + (lane >> 4)) ^ (row & 7)) * 16);
    }
#pragma unroll
    for (int ni = 0; ni < 4; ++ni) {
      int row = wc + ni * 16 + (lane & 15);
      boff[kk][ni] = row * 128 + (((kk * 4 + (lane >> 4)) ^ (row & 7)) * 16);
    }
  }
  f32x4 acc[4][4] = {};
#define STAGE1(buf, kt)                                                     \
  {                                                                         \
    unsigned koa = (unsigned)(kt) * 128u;                                   \
    unsigned kob = (unsigned)(kt) * 8192u;                                  \
    _Pragma("unroll") for (int j = 0; j < 4; ++j) {                         \
      GLD16(xbase + (size_t)(asrc[j] + koa), (char*)As[buf] + ldsoff[j]);   \
      GLD16(bbase + (size_t)(bsrc[j] + kob), (char*)Bs[buf] + ldsoff[j]);   \
    }                                                                       \
  }
  STAGE1(0, 0);
  STAGE1(1, 1);
  int cur = 0;
  for (int kt = 0; kt < NT; ++kt) {
    if (kt < NT - 1) asm volatile("s_waitcnt vmcnt(8)" ::: "memory");
    else             asm volatile("s_waitcnt vmcnt(0)" ::: "memory");
    RAW_BARRIER();
    bf16x8 af[2][4], bfv[2][4];
#pragma unroll
    for (int kk = 0; kk < 2; ++kk) {
#pragma unroll
      for (int mi = 0; mi < 4; ++mi)
        af[kk][mi] = *(const bf16x8*)((const char*)As[cur] + aoff[kk][mi]);
#pragma unroll
      for (int ni = 0; ni < 4; ++ni)
        bfv[kk][ni] = *(const bf16x8*)((const char*)Bs[cur] + boff[kk][ni]);
    }
    asm volatile("s_waitcnt lgkmcnt(0)" ::: "memory");
    RAW_BARRIER();
    if (kt + 2 < NT) STAGE1(cur, kt + 2);
    __builtin_amdgcn_s_setprio(1);
#pragma unroll
    for (int kk = 0; kk < 2; ++kk)
#pragma unroll
      for (int mi = 0; mi < 4; ++mi)
#pragma unroll
        for (int ni = 0; ni < 4; ++ni)
          acc[mi][ni] = __builtin_amdgcn_mfma_f32_16x16x32_bf16(af[kk][mi], bfv[kk][ni], acc[mi][ni], 0, 0, 0);
    __builtin_amdgcn_s_setprio(0);
    cur ^= 1;
  }
  int rq = (lane >> 4) * 4;
#pragma unroll
  for (int ni = 0; ni < 4; ++ni) {
    int h = ht * 128 + wc + ni * 16 + (lane & 15);
    float bias = b1[n * HDIM + h];
#pragma unroll
    for (int mi = 0; mi < 4; ++mi) {
#pragma unroll
      for (int q = 0; q < 4; ++q) {
        int lr = wr + mi * 16 + rq + q;
        float val = acc[mi][ni][q] + bias;
        H[((size_t)n * CAP + mt * 128 + lr) * HDIM + h] = f2bf(fast_gelu(val));
      }
    }
  }
}

__global__ __launch_bounds__(256) void ffn2_fast(
    const unsigned short* __restrict__ H, const unsigned short* __restrict__ w2t,
    const float* __restrict__ b2, const int* __restrict__ m_sel,
    const int* __restrict__ lists, float* __restrict__ out,
    const float* __restrict__ x, const int* __restrict__ flags) {
  __shared__ __align__(16) unsigned short As[2][128 * 64];
  __shared__ __align__(16) unsigned short Bs[2][128 * 64];
  const int NWG = NEXP * 10 * 8;  // 1280
  const int NT = HDIM / 64;       // 32
  int bid = blockIdx.x;
  int tid = threadIdx.x;
  int grp = bid >> 3;
  int r9 = grp % 9;
  if (r9 >= 5) {
    // ---- scattered passthrough: 1024 blocks, 16 rows each (NT ld/st) ----
    int pb = ((grp / 9) * 4 + (r9 - 5)) * 8 + (bid & 7);  // 0..1023
    int lane = tid & 63, w = tid >> 6;
    int base = pb * 16;
    for (int r = base + w; r < base + 16; r += 4) {
      if (flags[r]) continue;
      const f4v* s = (const f4v*)(x + (size_t)r * DDIM);
      f4v* d = (f4v*)(out + (size_t)r * DDIM);
#pragma unroll
      for (int i = 0; i < 4; ++i) {
        f4v t = __builtin_nontemporal_load(&s[lane + i * 64]);
        __builtin_nontemporal_store(t, &d[lane + i * 64]);
      }
    }
    return;
  }
  int g = ((grp / 9) * 5 + r9) * 8 + (bid & 7);  // 0..1279, g&7 == bid&7
  int lid = (g & 7) * (NWG / 8) + (g >> 3);
  int n = lid / 80;
  int rem = lid - n * 80;
  int mt = rem >> 3, dt = rem & 7;
  int M = m_sel[n];
  if (mt * 128 >= M) return;
  int lane = tid & 63, wid = tid >> 6;
  int wr = (wid >> 1) * 64, wc = (wid & 1) * 64;
  int rbase = tid >> 3;
  int c16 = tid & 7;
  const char* abase = (const char*)H + (((size_t)n * CAP + (size_t)mt * 128) * HDIM) * 2;
  const char* bbase = (const char*)w2t + (size_t)n * (DDIM * HDIM * 2);
  unsigned asrc[4], bsrc[4], ldsoff[4];
#pragma unroll
  for (int j = 0; j < 4; ++j) {
    int row = j * 32 + rbase;
    int gx = c16 ^ (row & 7);
    asrc[j] = (unsigned)row * 4096u + gx * 16;
    bsrc[j] = (unsigned)((dt * 2 + (row >> 6)) * 32) * 8192u +
              (unsigned)(row & 63) * 128u + gx * 16;
    ldsoff[j] = j * 4096 + wid * 1024;
  }
  unsigned aoff[2][4], boff[2][4];
#pragma unroll
  for (int kk = 0; kk < 2; ++kk) {
#pragma unroll
    for (int mi = 0; mi < 4; ++mi) {
      int row = wr + mi * 16 + (lane & 15);
      aoff[kk][mi] = row * 128 + (((kk * 4 + (lane >> 4)) ^ (row & 7)) * 16);
    }
#pragma unroll
    for (int ni = 0; ni < 4; ++ni) {
      int row = wc + ni * 16 + (lane & 15);
      boff[kk][ni] = row * 128 + (((kk * 4 + (lane >> 4)) ^ (row & 7)) * 16);
    }
  }
  f32x4 acc[4][4] = {};
#define STAGE2(buf, kt)                                                     \
  {                                                                         \
    unsigned koa = (unsigned)(kt) * 128u;                                   \
    unsigned kob = (unsigned)(kt) * 8192u;                                  \
    _Pragma("unroll") for (int j = 0; j < 4; ++j) {                         \
      GLD16(abase + (size_t)(asrc[j] + koa), (char*)As[buf] + ldsoff[j]);   \
      GLD16(bbase + (size_t)(bsrc[j] + kob), (char*)Bs[buf] + ldsoff[j]);   \
    }                                                                       \
  }
  STAGE2(0, 0);
  STAGE2(1, 1);
  int cur = 0;
  for (int kt = 0; kt < NT; ++kt) {
    if (kt < NT - 1) asm volatile("s_waitcnt vmcnt(8)" ::: "memory");
    else             asm volatile("s_waitcnt vmcnt(0)" ::: "memory");
    RAW_BARRIER();
    bf16x8 af[2][4], bfv[2][4];
#pragma unroll
    for (int kk = 0; kk < 2; ++kk) {
#pragma unroll
      for (int mi = 0; mi < 4; ++mi)
        af[kk][mi] = *(const bf16x8*)((const char*)As[cur] + aoff[kk][mi]);
#pragma unroll
      for (int ni = 0; ni < 4; ++ni)
        bfv[kk][ni] = *(const bf16x8*)((const char*)Bs[cur] + boff[kk][ni]);
    }
    asm volatile("s_waitcnt lgkmcnt(0)" ::: "memory");
    RAW_BARRIER();
    if (kt + 2 < NT) STAGE2(cur, kt + 2);
    __builtin_amdgcn_s_setprio(1);
#pragma unroll
    for (int kk = 0; kk < 2; ++kk)
#pragma unroll
      for (int mi = 0; mi < 4; ++mi)
#pragma unroll
        for (int ni = 0; ni < 4; ++ni)
          acc[mi][ni] = __builtin_amdgcn_mfma_f32_16x16x32_bf16(af[kk][mi], bfv[kk][ni], acc[mi][ni], 0, 0, 0);
    __builtin_amdgcn_s_setprio(0);
    cur ^= 1;
  }
  int rq = (lane >> 4) * 4;
  float bias[4];
#pragma unroll
  for (int ni = 0; ni < 4; ++ni)
    bias[ni] = b2[n * DDIM + dt * 128 + wc + ni * 16 + (lane & 15)];
#pragma unroll
  for (int mi = 0; mi < 4; ++mi) {
#pragma unroll
    for (int q = 0; q < 4; ++q) {
      int lr = wr + mi * 16 + rq + q;
      int s = mt * 128 + lr;
      if (s < M) {
        int tok = lists[n * CAP + s];
#pragma unroll
        for (int ni = 0; ni < 4; ++ni) {
          int dcol = dt * 128 + wc + ni * 16 + (lane & 15);
          __builtin_nontemporal_store(acc[mi][ni][q] + bias[ni],
                                      &out[(size_t)tok * DDIM + dcol]);
        }
      }
    }
  }
}

// ======================= SLOW PATH (ws fallback) ============================
__global__ __launch_bounds__(256) void ffn1_slow(
    const float* __restrict__ x, const float* __restrict__ W1, const float* __restrict__ b1,
    const int* __restrict__ m_sel, const int* __restrict__ lists,
    unsigned short* __restrict__ H) {
  __shared__ unsigned short Al[128 * APITCH];
  __shared__ unsigned short Bl[128 * APITCH];
  __shared__ int rows[128];
  int n = blockIdx.z, mt = blockIdx.y, ht = blockIdx.x;
  int M = m_sel[n];
  if (mt * 128 >= M) return;
  int tid = threadIdx.x;
  if (tid < 128) {
    int s = mt * 128 + tid;
    rows[tid] = lists[n * CAP + (s < M ? s : 0)];
  }
  __syncthreads();
  f32x4 acc[4][4] = {};
  int lane = tid & 63;
  int wid = tid >> 6;
  int wr = (wid >> 1) * 64, wc = (wid & 1) * 64;
  int ar = tid >> 4, ac = (tid & 15) * 4;
  int bh = tid & 127, bk8 = (tid >> 7) * 8;
  const size_t w1base = (size_t)n * DDIM * HDIM + (size_t)ht * 128;
  for (int kt = 0; kt < DDIM / 64; ++kt) {
#pragma unroll
    for (int i = 0; i < 8; ++i) {
      int r = ar + i * 16;
      float4 xv = *(const float4*)(x + (size_t)rows[r] * DDIM + kt * 64 + ac);
      unsigned plo = (unsigned)f2bf(xv.x) | ((unsigned)f2bf(xv.y) << 16);
      unsigned phi = (unsigned)f2bf(xv.z) | ((unsigned)f2bf(xv.w) << 16);
      *(uint2*)(&Al[r * APITCH + ac]) = make_uint2(plo, phi);
    }
#pragma unroll
    for (int i = 0; i < 4; ++i) {
      int k0 = bk8 + i * 16;
      const float* wp = W1 + w1base + (size_t)(kt * 64 + k0) * HDIM + bh;
      uint4 pk;
      pk.x = (unsigned)f2bf(wp[0]) | ((unsigned)f2bf(wp[HDIM]) << 16);
      pk.y = (unsigned)f2bf(wp[2 * HDIM]) | ((unsigned)f2bf(wp[3 * HDIM]) << 16);
      pk.z = (unsigned)f2bf(wp[4 * HDIM]) | ((unsigned)f2bf(wp[5 * HDIM]) << 16);
      pk.w = (unsigned)f2bf(wp[6 * HDIM]) | ((unsigned)f2bf(wp[7 * HDIM]) << 16);
      *(uint4*)(&Bl[bh * APITCH + k0]) = pk;
    }
    __syncthreads();
#pragma unroll
    for (int kk = 0; kk < 2; ++kk) {
      bf16x8 af[4], bfr[4];
#pragma unroll
      for (int mi = 0; mi < 4; ++mi)
        af[mi] = *(const bf16x8*)(&Al[(wr + mi * 16 + (lane & 15)) * APITCH + kk * 32 + (lane >> 4) * 8]);
#pragma unroll
      for (int ni = 0; ni < 4; ++ni)
        bfr[ni] = *(const bf16x8*)(&Bl[(wc + ni * 16 + (lane & 15)) * APITCH + kk * 32 + (lane >> 4) * 8]);
#pragma unroll
      for (int mi = 0; mi < 4; ++mi)
#pragma unroll
        for (int ni = 0; ni < 4; ++ni)
          acc[mi][ni] = __builtin_amdgcn_mfma_f32_16x16x32_bf16(af[mi], bfr[ni], acc[mi][ni], 0, 0, 0);
    }
    __syncthreads();
  }
  int rq = (lane >> 4) * 4;
#pragma unroll
  for (int ni = 0; ni < 4; ++ni) {
    int h = ht * 128 + wc + ni * 16 + (lane & 15);
    float bias = b1[n * HDIM + h];
#pragma unroll
    for (int mi = 0; mi < 4; ++mi) {
#pragma unroll
      for (int q = 0; q < 4; ++q) {
        int lr = wr + mi * 16 + rq + q;
        float val = acc[mi][ni][q] + bias;
        H[((size_t)n * CAP + mt * 128 + lr) * HDIM + h] = f2bf(fast_gelu(val));
      }
    }
  }
}

__global__ __launch_bounds__(256) void ffn2_slow(
    const unsigned short* __restrict__ H, const float* __restrict__ W2, const float* __restrict__ b2,
    const int* __restrict__ m_sel, const int* __restrict__ lists,
    float* __restrict__ out) {
  __shared__ unsigned short Al[128 * APITCH];
  __shared__ unsigned short Bl[128 * APITCH];
  __shared__ int rows[128];
  int n = blockIdx.z, mt = blockIdx.y, dt = blockIdx.x;
  int M = m_sel[n];
  if (mt * 128 >= M) return;
  int tid = threadIdx.x;
  if (tid < 128) {
    int s = mt * 128 + tid;
    rows[tid] = lists[n * CAP + (s < M ? s : 0)];
  }
  __syncthreads();
  f32x4 acc[4][4] = {};
  int lane = tid & 63;
  int wid = tid >> 6;
  int wr = (wid >> 1) * 64, wc = (wid & 1) * 64;
  int ar2 = tid >> 1, ak8 = (tid & 1) * 8;
  int bh = tid & 127, bk8 = (tid >> 7) * 8;
  const size_t hbase = ((size_t)n * CAP + (size_t)mt * 128) * HDIM;
  const size_t w2base = (size_t)n * HDIM * DDIM + (size_t)dt * 128;
  for (int kt = 0; kt < HDIM / 64; ++kt) {
#pragma unroll
    for (int i = 0; i < 4; ++i) {
      int k0 = ak8 + i * 16;
      uint4 hv = *(const uint4*)(H + hbase + (size_t)ar2 * HDIM + kt * 64 + k0);
      *(uint4*)(&Al[ar2 * APITCH + k0]) = hv;
    }
#pragma unroll
    for (int i = 0; i < 4; ++i) {
      int k0 = bk8 + i * 16;
      const float* wp = W2 + w2base + (size_t)(kt * 64 + k0) * DDIM + bh;
      uint4 pk;
      pk.x = (unsigned)f2bf(wp[0]) | ((unsigned)f2bf(wp[DDIM]) << 16);
      pk.y = (unsigned)f2bf(wp[2 * DDIM]) | ((unsigned)f2bf(wp[3 * DDIM]) << 16);
      pk.z = (unsigned)f2bf(wp[4 * DDIM]) | ((unsigned)f2bf(wp[5 * DDIM]) << 16);
      pk.w = (unsigned)f2bf(wp[6 * DDIM]) | ((unsigned)f2bf(wp[7 * DDIM]) << 16);
      *(uint4*)(&Bl[bh * APITCH + k0]) = pk;
    }
    __syncthreads();
#pragma unroll
    for (int kk = 0; kk < 2; ++kk) {
      bf16x8 af[4], bfr[4];
#pragma unroll
      for (int mi = 0; mi < 4; ++mi)
        af[mi] = *(const bf16x8*)(&Al[(wr + mi * 16 + (lane & 15)) * APITCH + kk * 32 + (lane >> 4) * 8]);
#pragma unroll
      for (int ni = 0; ni < 4; ++ni)
        bfr[ni] = *(const bf16x8*)(&Bl[(wc + ni * 16 + (lane & 15)) * APITCH + kk * 32 + (lane >> 4) * 8]);
#pragma unroll
      for (int mi = 0; mi < 4; ++mi)
#pragma unroll
        for (int ni = 0; ni < 4; ++ni)
          acc[mi][ni] = __builtin_amdgcn_mfma_f32_16x16x32_bf16(af[mi], bfr[ni], acc[mi][ni], 0, 0, 0);
    }
    __syncthreads();
  }
  int rq = (lane >> 4) * 4;
#pragma unroll
  for (int mi = 0; mi < 4; ++mi) {
#pragma unroll
    for (int q = 0; q < 4; ++q) {
      int lr = wr + mi * 16 + rq + q;
      int s = mt * 128 + lr;
      if (s < M) {
        int tok = rows[lr];
#pragma unroll
        for (int ni = 0; ni < 4; ++ni) {
          int dcol = dt * 128 + wc + ni * 16 + (lane & 15);
          out[(size_t)tok * DDIM + dcol] = acc[mi][ni][q] + b2[n * DDIM + dcol];
        }
      }
    }
  }
}

// ---------------- passthrough (slow path only) ------------------------------
__global__ __launch_bounds__(256) void passthrough_kernel(
    const float* __restrict__ x, const int* __restrict__ flags,
    float* __restrict__ out) {
  int lane = threadIdx.x & 63;
  int w = threadIdx.x >> 6;
  int base = blockIdx.x * 16;
  for (int r = base + w; r < base + 16; r += 4) {
    if (flags[r]) continue;
    const float4* s = (const float4*)(x + (size_t)r * DDIM);
    float4* d = (float4*)(out + (size_t)r * DDIM);
#pragma unroll
    for (int i = 0; i < 4; ++i) d[lane + i * 64] = s[lane + i * 64];
  }
}

extern "C" void kernel_launch(void* const* d_in, const int* in_sizes, int n_in,
                              void* d_out, int out_size, void* d_ws, size_t ws_size,
                              hipStream_t stream) {
  const float* x  = (const float*)d_in[0];
  const float* Wg = (const float*)d_in[1];
  const float* W1 = (const float*)d_in[2];
  const float* b1 = (const float*)d_in[3];
  const float* W2 = (const float*)d_in[4];
  const float* b2 = (const float*)d_in[5];
  float* out = (float*)d_out;
  char* ws = (char*)d_ws;
  int* counts = (int*)ws;
  int* m_sel  = (int*)(ws + 64);
  int* flags  = (int*)(ws + 128);
  int* e      = (int*)(ws + 128 + 4 * BT);
  float* v    = (float*)(ws + 128 + 8 * BT);
  int* lists  = (int*)(ws + 128 + 12 * BT);

  const size_t MB = 1024 * 1024;
  unsigned short* xb  = (unsigned short*)(ws + 1 * MB);
  unsigned short* w1t = (unsigned short*)(ws + 33 * MB);
  unsigned short* w2t = (unsigned short*)(ws + 97 * MB);
  unsigned short* Hf  = (unsigned short*)(ws + 161 * MB);
  bool fast = ws_size >= 242 * MB;

  hipMemsetAsync(ws, 0, 128, stream);  // counts[16] + m_sel[16]
  if (fast) {
    prep_kernel<<<256 + 8192, 256, 0, stream>>>(x, Wg, e, v, counts, xb, flags, W1, w1t);
    select_kernel<<<NEXP, 1024, 0, stream>>>(e, v, counts, m_sel, lists, flags);
    ffn1_fast<<<4608, 256, 0, stream>>>(xb, w1t, b1, m_sel, lists, Hf, W2, w2t);
    ffn2_fast<<<2304, 256, 0, stream>>>(Hf, w2t, b2, m_sel, lists, out, x, flags);
  } else {
    unsigned short* Hs = (unsigned short*)(ws + 1 * MB);
    gate_kernel<<<BT / 64, 256, 0, stream>>>(x, Wg, e, v, counts, (unsigned short*)nullptr, flags);
    select_kernel<<<NEXP, 1024, 0, stream>>>(e, v, counts, m_sel, lists, flags);
    ffn1_slow<<<dim3(HDIM / 128, CAP / 128, NEXP), 256, 0, stream>>>(x, W1, b1, m_sel, lists, Hs);
    ffn2_slow<<<dim3(DDIM / 128, CAP / 128, NEXP), 256, 0, stream>>>(Hs, W2, b2, m_sel, lists, out);
    passthrough_kernel<<<BT / 16, 256, 0, stream>>>(x, flags, out);
  }
}

// Round 24
// 292.504 us; speedup vs baseline: 1.3667x; 1.0027x over previous
//
#include <hip/hip_runtime.h>
#include <hip/hip_bf16.h>
#include <math.h>

#define BT 16384
#define DDIM 1024
#define NEXP 16
#define HDIM 2048
#define CAP 1280
#define APITCH 72
#define LBP 262  // bf16 LDS slab pitch for in-GEMM transpose tail

typedef __bf16 bf16x8 __attribute__((ext_vector_type(8)));
typedef float f32x4 __attribute__((ext_vector_type(4)));
typedef float f4v __attribute__((ext_vector_type(4)));  // for nontemporal ld/st

__device__ __forceinline__ unsigned short f2bf(float f) {
  unsigned u = __float_as_uint(f);
  u += 0x7FFFu + ((u >> 16) & 1u);
  return (unsigned short)(u >> 16);
}

// HW packed fp32->bf16 (RNE, identical to f2bf): dst.lo=cvt(a), dst.hi=cvt(b)
__device__ __forceinline__ unsigned cvt_pk_bf16(float a, float b) {
  unsigned r;
  asm("v_cvt_pk_bf16_f32 %0, %1, %2" : "=v"(r) : "v"(a), "v"(b));
  return r;
}

// gelu(tanh approx) == v * sigmoid(2z); hardware v_exp_f32 path.
__device__ __forceinline__ float fast_gelu(float v) {
  float z = 0.7978845608028654f * (v + 0.044715f * v * v * v);
  return v / (1.0f + __expf(-2.0f * z));
}

#define GLD16(g, l)                                                        \
  __builtin_amdgcn_global_load_lds(                                        \
      (const __attribute__((address_space(1))) unsigned int*)(g),          \
      (__attribute__((address_space(3))) unsigned int*)(l), 16, 0, 0)

// Raw barrier without the vmcnt(0) drain __syncthreads would emit.
#define RAW_BARRIER()                          \
  {                                            \
    __builtin_amdgcn_sched_barrier(0);         \
    __builtin_amdgcn_s_barrier();              \
    __builtin_amdgcn_sched_barrier(0);         \
  }

// ---- slab transpose body: 64 rows x 256 cols fp32 -> 4 tiled 64x64 bf16
// tiles. Source reads are NONTEMPORAL (single-use stream; don't evict the
// GEMM's hot xb/w1t panels from L2/L3). ------------------------------------
__device__ __forceinline__ void slab_transpose(
    unsigned short* Lb, const float* src, int C,
    unsigned short* outp, size_t tile_base, int tmul, int by, int bxq, int tid) {
  int w = tid >> 6, lane = tid & 63;
#pragma unroll
  for (int k = 0; k < 16; ++k) {
    int row = w + k * 4;
    f4v vv = __builtin_nontemporal_load((const f4v*)(src + (size_t)row * C + lane * 4));
    unsigned p0 = cvt_pk_bf16(vv[0], vv[1]);
    unsigned p1 = cvt_pk_bf16(vv[2], vv[3]);
    *(uint2*)(&Lb[row * LBP + lane * 4]) = make_uint2(p0, p1);
  }
  __syncthreads();
  int oc_lo = tid >> 3;
  int rb = (tid & 7) * 8;
#pragma unroll
  for (int p2 = 0; p2 < 4; ++p2) {
    int bx = bxq * 4 + p2;
    char* dstT = (char*)outp + (tile_base + (size_t)bx * tmul + by) * 8192;
#pragma unroll
    for (int p = 0; p < 2; ++p) {
      int oc = p * 32 + oc_lo;
      const unsigned short* col = &Lb[rb * LBP + p2 * 64 + oc];
      unsigned short u[8];
#pragma unroll
      for (int j = 0; j < 8; ++j) u[j] = col[j * LBP];
      uint4 pk;
      pk.x = (unsigned)u[0] | ((unsigned)u[1] << 16);
      pk.y = (unsigned)u[2] | ((unsigned)u[3] << 16);
      pk.z = (unsigned)u[4] | ((unsigned)u[5] << 16);
      pk.w = (unsigned)u[6] | ((unsigned)u[7] << 16);
      *(uint4*)(dstT + p * 4096 + tid * 16) = pk;
    }
  }
}

// ======== fused prep: blocks [0,256) = gate (chunk-pipelined loads, T14,
// NT x-reads: x is single-use within prep); [256,8448) = W1 tiled transpose.
__global__ __launch_bounds__(256) void prep_kernel(
    const float* __restrict__ x, const float* __restrict__ Wg,
    int* __restrict__ e, float* __restrict__ v, int* __restrict__ counts,
    unsigned short* __restrict__ xb, int* __restrict__ flags,
    const float* __restrict__ W1, unsigned short* __restrict__ w1t) {
  __shared__ __align__(16) char smem[30016];
  int bid = blockIdx.x;
  int tid = threadIdx.x;
  if (bid < 256) {
    // ---------------- gate: 64 tokens/block, register-prefetched chunks -----
    float* xt = (float*)smem;                       // [64][68]  17408B
    double* lg = (double*)(smem + 17408);           // [64][16]   8192B
    float* wgt_c = (float*)(smem + 25600);          // [16][68]   4352B
    int* hcnt = (int*)(smem + 29952);               // [16]
    int t0 = bid * 64;
    if (tid < NEXP) hcnt[tid] = 0;
    if (tid < 64) flags[t0 + tid] = 0;
    int t = tid & 63, g = tid >> 6;
    double acc[4] = {0.0, 0.0, 0.0, 0.0};
    int sr = tid >> 4;
    int sc = (tid & 15) * 4;
    int wd = tid >> 2, wn = (tid & 3) * 4;
    // preload chunk 0 into registers (NT: single-use stream)
    f4v xr0, xr1, xr2, xr3;
    float4 wgr;
    xr0 = __builtin_nontemporal_load((const f4v*)(x + (size_t)(t0 + sr +  0) * DDIM + sc));
    xr1 = __builtin_nontemporal_load((const f4v*)(x + (size_t)(t0 + sr + 16) * DDIM + sc));
    xr2 = __builtin_nontemporal_load((const f4v*)(x + (size_t)(t0 + sr + 32) * DDIM + sc));
    xr3 = __builtin_nontemporal_load((const f4v*)(x + (size_t)(t0 + sr + 48) * DDIM + sc));
    wgr = *(const float4*)(Wg + tid * 4);
    for (int ch = 0; ch < 16; ++ch) {
      __syncthreads();  // previous chunk's LDS consumers done
      // write-phase: regs -> LDS, regs -> xb
      {
        f4v xv = xr0; int r = sr;
        xt[r * 68 + sc + 0] = xv[0]; xt[r * 68 + sc + 1] = xv[1];
        xt[r * 68 + sc + 2] = xv[2]; xt[r * 68 + sc + 3] = xv[3];
        *(uint2*)(xb + (size_t)(t0 + r) * DDIM + ch * 64 + sc) =
            make_uint2(cvt_pk_bf16(xv[0], xv[1]), cvt_pk_bf16(xv[2], xv[3]));
        xv = xr1; r = sr + 16;
        xt[r * 68 + sc + 0] = xv[0]; xt[r * 68 + sc + 1] = xv[1];
        xt[r * 68 + sc + 2] = xv[2]; xt[r * 68 + sc + 3] = xv[3];
        *(uint2*)(xb + (size_t)(t0 + r) * DDIM + ch * 64 + sc) =
            make_uint2(cvt_pk_bf16(xv[0], xv[1]), cvt_pk_bf16(xv[2], xv[3]));
        xv = xr2; r = sr + 32;
        xt[r * 68 + sc + 0] = xv[0]; xt[r * 68 + sc + 1] = xv[1];
        xt[r * 68 + sc + 2] = xv[2]; xt[r * 68 + sc + 3] = xv[3];
        *(uint2*)(xb + (size_t)(t0 + r) * DDIM + ch * 64 + sc) =
            make_uint2(cvt_pk_bf16(xv[0], xv[1]), cvt_pk_bf16(xv[2], xv[3]));
        xv = xr3; r = sr + 48;
        xt[r * 68 + sc + 0] = xv[0]; xt[r * 68 + sc + 1] = xv[1];
        xt[r * 68 + sc + 2] = xv[2]; xt[r * 68 + sc + 3] = xv[3];
        *(uint2*)(xb + (size_t)(t0 + r) * DDIM + ch * 64 + sc) =
            make_uint2(cvt_pk_bf16(xv[0], xv[1]), cvt_pk_bf16(xv[2], xv[3]));
        wgt_c[(wn + 0) * 68 + wd] = wgr.x;
        wgt_c[(wn + 1) * 68 + wd] = wgr.y;
        wgt_c[(wn + 2) * 68 + wd] = wgr.z;
        wgt_c[(wn + 3) * 68 + wd] = wgr.w;
      }
      // issue next chunk's loads (latency hides under compute below)
      if (ch < 15) {
        int co = (ch + 1) * 64;
        xr0 = __builtin_nontemporal_load((const f4v*)(x + (size_t)(t0 + sr +  0) * DDIM + co + sc));
        xr1 = __builtin_nontemporal_load((const f4v*)(x + (size_t)(t0 + sr + 16) * DDIM + co + sc));
        xr2 = __builtin_nontemporal_load((const f4v*)(x + (size_t)(t0 + sr + 32) * DDIM + co + sc));
        xr3 = __builtin_nontemporal_load((const f4v*)(x + (size_t)(t0 + sr + 48) * DDIM + co + sc));
        wgr = *(const float4*)(Wg + (ch + 1) * 1024 + tid * 4);
      }
      __syncthreads();  // LDS writes visible
#pragma unroll
      for (int d4 = 0; d4 < 16; ++d4) {
        float4 xv = *(const float4*)(&xt[t * 68 + d4 * 4]);
#pragma unroll
        for (int j = 0; j < 4; ++j) {
          float4 wv = *(const float4*)(&wgt_c[(4 * g + j) * 68 + d4 * 4]);
          acc[j] += (double)xv.x * (double)wv.x + (double)xv.y * (double)wv.y +
                    (double)xv.z * (double)wv.z + (double)xv.w * (double)wv.w;
        }
      }
    }
#pragma unroll
    for (int j = 0; j < 4; ++j) lg[t * 16 + 4 * g + j] = acc[j];
    __syncthreads();
    if (tid < 64) {
      double mx = lg[tid * 16]; int bi = 0;
#pragma unroll
      for (int n = 1; n < NEXP; ++n)
        if (lg[tid * 16 + n] > mx) { mx = lg[tid * 16 + n]; bi = n; }
      double s = 0.0;
#pragma unroll
      for (int n = 0; n < NEXP; ++n) s += exp(lg[tid * 16 + n] - mx);
      e[t0 + tid] = bi;
      v[t0 + tid] = (float)(1.0 / s);
      atomicAdd(&hcnt[bi], 1);
    }
    __syncthreads();
    if (tid < NEXP && hcnt[tid] > 0) atomicAdd(&counts[tid], hcnt[tid]);
    return;
  }
  // ---------------- W1 transpose + fp32->bf16, tiled (NT source reads) ------
  float* tile = (float*)smem;  // [64][65]
  int b = bid - 256;  // 0..8191
  int n = b >> 9; int rem = b & 511; int by = rem >> 5, bx = rem & 31;
  size_t tile_off = ((size_t)n * 512 + (size_t)bx * 16 + by) * 8192;
  const float* src = W1 + (size_t)n * DDIM * HDIM;
  int r0 = by * 64, c0 = bx * 64;
  int lr = tid >> 2, lq = tid & 3;
#pragma unroll
  for (int i = 0; i < 4; ++i) {
    f4v vv = __builtin_nontemporal_load(
        (const f4v*)(src + (size_t)(r0 + lr) * HDIM + c0 + i * 16 + lq * 4));
    *(f4v*)(&tile[lr * 65 + i * 16 + lq * 4]) = vv;
  }
  __syncthreads();
  char* dstT = (char*)w1t + tile_off;
  int oc2 = tid >> 3, lq2 = tid & 7;
#pragma unroll
  for (int p = 0; p < 2; ++p) {
    int oc = p * 32 + oc2;
    int rb = lq2 * 8;
    uint4 pk;
    pk.x = cvt_pk_bf16(tile[(rb + 0) * 65 + oc], tile[(rb + 1) * 65 + oc]);
    pk.y = cvt_pk_bf16(tile[(rb + 2) * 65 + oc], tile[(rb + 3) * 65 + oc]);
    pk.z = cvt_pk_bf16(tile[(rb + 4) * 65 + oc], tile[(rb + 5) * 65 + oc]);
    pk.w = cvt_pk_bf16(tile[(rb + 6) * 65 + oc], tile[(rb + 7) * 65 + oc]);
    *(uint4*)(dstT + p * 4096 + tid * 16) = pk;
  }
}

// ---------------- select: per-expert token set, 1024-thread blocks ----------
__global__ __launch_bounds__(1024) void select_kernel(
    const int* __restrict__ e, const float* __restrict__ v,
    const int* __restrict__ counts, int* __restrict__ m_sel,
    int* __restrict__ lists, int* __restrict__ flags) {
  int n = blockIdx.x;
  int tid = threadIdx.x;
  int cnt = counts[n];
  __shared__ int pos;
  if (tid == 0) pos = 0;
  __syncthreads();
  if (cnt <= CAP) {
    for (int t = tid; t < BT; t += 1024) {
      if (e[t] == n) {
        int p = atomicAdd(&pos, 1);
        lists[n * CAP + p] = t;
        flags[t] = 1;
      }
    }
    __syncthreads();
    if (tid == 0) m_sel[n] = pos;
  } else {
    __shared__ int scnt;
    unsigned lo = 0u, hi = 0x7F800000u;
    while (hi - lo > 1u) {
      unsigned mid = lo + ((hi - lo) >> 1);
      if (tid == 0) scnt = 0;
      __syncthreads();
      int c = 0;
      for (int t = tid; t < BT; t += 1024)
        if (e[t] == n && __float_as_uint(v[t]) >= mid) c++;
      atomicAdd(&scnt, c);
      __syncthreads();
      int tot = scnt;
      __syncthreads();
      if (tot >= CAP) lo = mid; else hi = mid;
    }
    for (int t = tid; t < BT; t += 1024) {
      if (e[t] == n && __float_as_uint(v[t]) > lo) {
        int p = atomicAdd(&pos, 1);
        lists[n * CAP + p] = t;
        flags[t] = 1;
      }
    }
    __syncthreads();
    if (tid == 0) {
      int p = pos;
      for (int t = 0; t < BT && p < CAP; ++t) {
        if (e[t] == n && __float_as_uint(v[t]) == lo) {
          lists[n * CAP + p] = t; flags[t] = 1; ++p;
        }
      }
      m_sel[n] = p;
    }
  }
}

// ---------------- gate (slow path only, resident Wg table) ------------------
__global__ __launch_bounds__(256) void gate_kernel(
    const float* __restrict__ x, const float* __restrict__ Wg,
    int* __restrict__ e, float* __restrict__ v, int* __restrict__ counts,
    unsigned short* __restrict__ xb, int* __restrict__ flags) {
  __shared__ float wgt[NEXP][DDIM];
  __shared__ float xt[64][68];
  __shared__ double lg[64][NEXP];
  __shared__ int hcnt[NEXP];
  int tid = threadIdx.x;
  int t0 = blockIdx.x * 64;
  if (tid < NEXP) hcnt[tid] = 0;
  if (tid < 64) flags[t0 + tid] = 0;
  for (int i = tid; i < DDIM * NEXP / 4; i += 256) {
    int idx = i * 4;
    int d = idx >> 4, n = idx & 15;
    float4 w = *(const float4*)(Wg + idx);
    wgt[n + 0][d] = w.x; wgt[n + 1][d] = w.y;
    wgt[n + 2][d] = w.z; wgt[n + 3][d] = w.w;
  }
  int t = tid & 63, g = tid >> 6;
  double acc[4] = {0.0, 0.0, 0.0, 0.0};
  int sr = tid >> 4;
  int sc = (tid & 15) * 4;
  for (int ch = 0; ch < 16; ++ch) {
    __syncthreads();
#pragma unroll
    for (int i = 0; i < 4; ++i) {
      int r = sr + i * 16;
      float4 xv = *(const float4*)(x + (size_t)(t0 + r) * DDIM + ch * 64 + sc);
      xt[r][sc + 0] = xv.x; xt[r][sc + 1] = xv.y;
      xt[r][sc + 2] = xv.z; xt[r][sc + 3] = xv.w;
      if (xb) {
        unsigned p0 = cvt_pk_bf16(xv.x, xv.y);
        unsigned p1 = cvt_pk_bf16(xv.z, xv.w);
        *(uint2*)(xb + (size_t)(t0 + r) * DDIM + ch * 64 + sc) = make_uint2(p0, p1);
      }
    }
    __syncthreads();
#pragma unroll
    for (int d4 = 0; d4 < 16; ++d4) {
      float4 xv = *(const float4*)(&xt[t][d4 * 4]);
#pragma unroll
      for (int j = 0; j < 4; ++j) {
        float4 wv = *(const float4*)(&wgt[4 * g + j][ch * 64 + d4 * 4]);
        acc[j] += (double)xv.x * (double)wv.x + (double)xv.y * (double)wv.y +
                  (double)xv.z * (double)wv.z + (double)xv.w * (double)wv.w;
      }
    }
  }
#pragma unroll
  for (int j = 0; j < 4; ++j) lg[t][4 * g + j] = acc[j];
  __syncthreads();
  if (tid < 64) {
    double mx = lg[tid][0]; int bi = 0;
#pragma unroll
    for (int n = 1; n < NEXP; ++n)
      if (lg[tid][n] > mx) { mx = lg[tid][n]; bi = n; }
    double s = 0.0;
#pragma unroll
    for (int n = 0; n < NEXP; ++n) s += exp(lg[tid][n] - mx);
    e[t0 + tid] = bi;
    v[t0 + tid] = (float)(1.0 / s);
    atomicAdd(&hcnt[bi], 1);
  }
  __syncthreads();
  if (tid < NEXP && hcnt[tid] > 0) atomicAdd(&counts[tid], hcnt[tid]);
}

// ======================= FAST PATH (bf16 pre-converted) =====================
// R12 FFN structure. ffn1 grid = 4608 blocks with SCATTERED roles (period 9
// groups of 8: r<5 GEMM 2560, r>=5 W2 slab transpose 2048). ffn2 grid = 2304
// (r<5 GEMM 1280, r>=5 passthrough 1024). g&7 == bid&7 preserves XCD swizzle.

__global__ __launch_bounds__(256) void ffn1_fast(
    const unsigned short* __restrict__ xb, const unsigned short* __restrict__ w1t,
    const float* __restrict__ b1, const int* __restrict__ m_sel,
    const int* __restrict__ lists, unsigned short* __restrict__ H,
    const float* __restrict__ W2f, unsigned short* __restrict__ w2t) {
  __shared__ __align__(16) char smem[65536];
  unsigned short (*As)[8192] = (unsigned short(*)[8192])smem;
  unsigned short (*Bs)[8192] = (unsigned short(*)[8192])(smem + 32768);
  const int NWG = NEXP * 10 * 16;  // 2560
  const int NT = DDIM / 64;        // 16
  int bid = blockIdx.x;
  int tid = threadIdx.x;
  int grp = bid >> 3;
  int r9 = grp % 9;
  if (r9 >= 5) {
    // ---- W2 slab transpose: 32 h-tiles x 4 col-quads/expert (2048 blocks) --
    int b = ((grp / 9) * 4 + (r9 - 5)) * 8 + (bid & 7);  // 0..2047
    int n2 = b >> 7; int rem = b & 127; int by = rem >> 2, bxq = rem & 3;
    const float* src = W2f + (size_t)n2 * DDIM * HDIM + (size_t)by * 64 * DDIM + bxq * 256;
    slab_transpose((unsigned short*)smem, src, DDIM, w2t,
                   (size_t)n2 * 512, 32, by, bxq, tid);
    return;
  }
  int g = ((grp / 9) * 5 + r9) * 8 + (bid & 7);  // 0..2559, g&7 == bid&7
  int lid = (g & 7) * (NWG / 8) + (g >> 3);
  int n = lid / 160;
  int rem = lid - n * 160;
  int mt = rem >> 4, ht = rem & 15;
  int M = m_sel[n];
  if (mt * 128 >= M) return;
  int lane = tid & 63, wid = tid >> 6;
  int wr = (wid >> 1) * 64, wc = (wid & 1) * 64;
  int rbase = tid >> 3;
  int c16 = tid & 7;
  const char* xbase = (const char*)xb;
  const char* bbase = (const char*)w1t + (size_t)n * (DDIM * HDIM * 2);
  unsigned asrc[4], bsrc[4], ldsoff[4];
#pragma unroll
  for (int j = 0; j < 4; ++j) {
    int row = j * 32 + rbase;
    int gx = c16 ^ (row & 7);
    int s = mt * 128 + row;
    int tok = lists[n * CAP + (s < M ? s : 0)];
    asrc[j] = (unsigned)tok * 2048u + gx * 16;
    bsrc[j] = (unsigned)((ht * 2 + (row >> 6)) * 16) * 8192u +
              (unsigned)(row & 63) * 128u + gx * 16;
    ldsoff[j] = j * 4096 + wid * 1024;
  }
  unsigned aoff[2][4], boff[2][4];
#pragma unroll
  for (int kk = 0; kk < 2; ++kk) {
#pragma unroll
    for (int mi = 0; mi < 4; ++mi) {
      int row = wr + mi * 16 + (lane & 15);
      aoff[kk][mi] = row * 128 + (((kk * 4 + (lane >> 4)) ^ (row & 7)) * 16);
    }
#pragma unroll
    for (int ni = 0; ni < 4; ++ni) {
      int row = wc + ni * 16 + (lane & 15);
      boff[kk][ni] = row * 128 + (((kk * 4 + (lane >> 4)) ^ (row & 7)) * 16);
    }
  }
  f32x4 acc[4][4] = {};
#define STAGE1(buf, kt)                                                     \
  {                                                                         \
    unsigned koa = (unsigned)(kt) * 128u;                                   \
    unsigned kob = (unsigned)(kt) * 8192u;                                  \
    _Pragma("unroll") for (int j = 0; j < 4; ++j) {                         \
      GLD16(xbase + (size_t)(asrc[j] + koa), (char*)As[buf] + ldsoff[j]);   \
      GLD16(bbase + (size_t)(bsrc[j] + kob), (char*)Bs[buf] + ldsoff[j]);   \
    }                                                                       \
  }
  STAGE1(0, 0);
  STAGE1(1, 1);
  int cur = 0;
  for (int kt = 0; kt < NT; ++kt) {
    if (kt < NT - 1) asm volatile("s_waitcnt vmcnt(8)" ::: "memory");
    else             asm volatile("s_waitcnt vmcnt(0)" ::: "memory");
    RAW_BARRIER();
    bf16x8 af[2][4], bfv[2][4];
#pragma unroll
    for (int kk = 0; kk < 2; ++kk) {
#pragma unroll
      for (int mi = 0; mi < 4; ++mi)
        af[kk][mi] = *(const bf16x8*)((const char*)As[cur] + aoff[kk][mi]);
#pragma unroll
      for (int ni = 0; ni < 4; ++ni)
        bfv[kk][ni] = *(const bf16x8*)((const char*)Bs[cur] + boff[kk][ni]);
    }
    asm volatile("s_waitcnt lgkmcnt(0)" ::: "memory");
    RAW_BARRIER();
    if (kt + 2 < NT) STAGE1(cur, kt + 2);
    __builtin_amdgcn_s_setprio(1);
#pragma unroll
    for (int kk = 0; kk < 2; ++kk)
#pragma unroll
      for (int mi = 0; mi < 4; ++mi)
#pragma unroll
        for (int ni = 0; ni < 4; ++ni)
          acc[mi][ni] = __builtin_amdgcn_mfma_f32_16x16x32_bf16(af[kk][mi], bfv[kk][ni], acc[mi][ni], 0, 0, 0);
    __builtin_amdgcn_s_setprio(0);
    cur ^= 1;
  }
  int rq = (lane >> 4) * 4;
#pragma unroll
  for (int ni = 0; ni < 4; ++ni) {
    int h = ht * 128 + wc + ni * 16 + (lane & 15);
    float bias = b1[n * HDIM + h];
#pragma unroll
    for (int mi = 0; mi < 4; ++mi) {
#pragma unroll
      for (int q = 0; q < 4; ++q) {
        int lr = wr + mi * 16 + rq + q;
        float val = acc[mi][ni][q] + bias;
        H[((size_t)n * CAP + mt * 128 + lr) * HDIM + h] = f2bf(fast_gelu(val));
      }
    }
  }
}

__global__ __launch_bounds__(256) void ffn2_fast(
    const unsigned short* __restrict__ H, const unsigned short* __restrict__ w2t,
    const float* __restrict__ b2, const int* __restrict__ m_sel,
    const int* __restrict__ lists, float* __restrict__ out,
    const float* __restrict__ x, const int* __restrict__ flags) {
  __shared__ __align__(16) unsigned short As[2][128 * 64];
  __shared__ __align__(16) unsigned short Bs[2][128 * 64];
  const int NWG = NEXP * 10 * 8;  // 1280
  const int NT = HDIM / 64;       // 32
  int bid = blockIdx.x;
  int tid = threadIdx.x;
  int grp = bid >> 3;
  int r9 = grp % 9;
  if (r9 >= 5) {
    // ---- scattered passthrough: 1024 blocks, 16 rows each (NT ld/st) ----
    int pb = ((grp / 9) * 4 + (r9 - 5)) * 8 + (bid & 7);  // 0..1023
    int lane = tid & 63, w = tid >> 6;
    int base = pb * 16;
    for (int r = base + w; r < base + 16; r += 4) {
      if (flags[r]) continue;
      const f4v* s = (const f4v*)(x + (size_t)r * DDIM);
      f4v* d = (f4v*)(out + (size_t)r * DDIM);
#pragma unroll
      for (int i = 0; i < 4; ++i) {
        f4v t = __builtin_nontemporal_load(&s[lane + i * 64]);
        __builtin_nontemporal_store(t, &d[lane + i * 64]);
      }
    }
    return;
  }
  int g = ((grp / 9) * 5 + r9) * 8 + (bid & 7);  // 0..1279, g&7 == bid&7
  int lid = (g & 7) * (NWG / 8) + (g >> 3);
  int n = lid / 80;
  int rem = lid - n * 80;
  int mt = rem >> 3, dt = rem & 7;
  int M = m_sel[n];
  if (mt * 128 >= M) return;
  int lane = tid & 63, wid = tid >> 6;
  int wr = (wid >> 1) * 64, wc = (wid & 1) * 64;
  int rbase = tid >> 3;
  int c16 = tid & 7;
  const char* abase = (const char*)H + (((size_t)n * CAP + (size_t)mt * 128) * HDIM) * 2;
  const char* bbase = (const char*)w2t + (size_t)n * (DDIM * HDIM * 2);
  unsigned asrc[4], bsrc[4], ldsoff[4];
#pragma unroll
  for (int j = 0; j < 4; ++j) {
    int row = j * 32 + rbase;
    int gx = c16 ^ (row & 7);
    asrc[j] = (unsigned)row * 4096u + gx * 16;
    bsrc[j] = (unsigned)((dt * 2 + (row >> 6)) * 32) * 8192u +
              (unsigned)(row & 63) * 128u + gx * 16;
    ldsoff[j] = j * 4096 + wid * 1024;
  }
  unsigned aoff[2][4], boff[2][4];
#pragma unroll
  for (int kk = 0; kk < 2; ++kk) {
#pragma unroll
    for (int mi = 0; mi < 4; ++mi) {
      int row = wr + mi * 16 + (lane & 15);
      aoff[kk][mi] = row * 128 + (((kk * 4 + (lane >> 4)) ^ (row & 7)) * 16);
    }
#pragma unroll
    for (int ni = 0; ni < 4; ++ni) {
      int row = wc + ni * 16 + (lane & 15);
      boff[kk][ni] = row * 128 + (((kk * 4 + (lane >> 4)) ^ (row & 7)) * 16);
    }
  }
  f32x4 acc[4][4] = {};
#define STAGE2(buf, kt)                                                     \
  {                                                                         \
    unsigned koa = (unsigned)(kt) * 128u;                                   \
    unsigned kob = (unsigned)(kt) * 8192u;                                  \
    _Pragma("unroll") for (int j = 0; j < 4; ++j) {                         \
      GLD16(abase + (size_t)(asrc[j] + koa), (char*)As[buf] + ldsoff[j]);   \
      GLD16(bbase + (size_t)(bsrc[j] + kob), (char*)Bs[buf] + ldsoff[j]);   \
    }                                                                       \
  }
  STAGE2(0, 0);
  STAGE2(1, 1);
  int cur = 0;
  for (int kt = 0; kt < NT; ++kt) {
    if (kt < NT - 1) asm volatile("s_waitcnt vmcnt(8)" ::: "memory");
    else             asm volatile("s_waitcnt vmcnt(0)" ::: "memory");
    RAW_BARRIER();
    bf16x8 af[2][4], bfv[2][4];
#pragma unroll
    for (int kk = 0; kk < 2; ++kk) {
#pragma unroll
      for (int mi = 0; mi < 4; ++mi)
        af[kk][mi] = *(const bf16x8*)((const char*)As[cur] + aoff[kk][mi]);
#pragma unroll
      for (int ni = 0; ni < 4; ++ni)
        bfv[kk][ni] = *(const bf16x8*)((const char*)Bs[cur] + boff[kk][ni]);
    }
    asm volatile("s_waitcnt lgkmcnt(0)" ::: "memory");
    RAW_BARRIER();
    if (kt + 2 < NT) STAGE2(cur, kt + 2);
    __builtin_amdgcn_s_setprio(1);
#pragma unroll
    for (int kk = 0; kk < 2; ++kk)
#pragma unroll
      for (int mi = 0; mi < 4; ++mi)
#pragma unroll
        for (int ni = 0; ni < 4; ++ni)
          acc[mi][ni] = __builtin_amdgcn_mfma_f32_16x16x32_bf16(af[kk][mi], bfv[kk][ni], acc[mi][ni], 0, 0, 0);
    __builtin_amdgcn_s_setprio(0);
    cur ^= 1;
  }
  int rq = (lane >> 4) * 4;
  float bias[4];
#pragma unroll
  for (int ni = 0; ni < 4; ++ni)
    bias[ni] = b2[n * DDIM + dt * 128 + wc + ni * 16 + (lane & 15)];
#pragma unroll
  for (int mi = 0; mi < 4; ++mi) {
#pragma unroll
    for (int q = 0; q < 4; ++q) {
      int lr = wr + mi * 16 + rq + q;
      int s = mt * 128 + lr;
      if (s < M) {
        int tok = lists[n * CAP + s];
#pragma unroll
        for (int ni = 0; ni < 4; ++ni) {
          int dcol = dt * 128 + wc + ni * 16 + (lane & 15);
          __builtin_nontemporal_store(acc[mi][ni][q] + bias[ni],
                                      &out[(size_t)tok * DDIM + dcol]);
        }
      }
    }
  }
}

// ======================= SLOW PATH (ws fallback) ============================
__global__ __launch_bounds__(256) void ffn1_slow(
    const float* __restrict__ x, const float* __restrict__ W1, const float* __restrict__ b1,
    const int* __restrict__ m_sel, const int* __restrict__ lists,
    unsigned short* __restrict__ H) {
  __shared__ unsigned short Al[128 * APITCH];
  __shared__ unsigned short Bl[128 * APITCH];
  __shared__ int rows[128];
  int n = blockIdx.z, mt = blockIdx.y, ht = blockIdx.x;
  int M = m_sel[n];
  if (mt * 128 >= M) return;
  int tid = threadIdx.x;
  if (tid < 128) {
    int s = mt * 128 + tid;
    rows[tid] = lists[n * CAP + (s < M ? s : 0)];
  }
  __syncthreads();
  f32x4 acc[4][4] = {};
  int lane = tid & 63;
  int wid = tid >> 6;
  int wr = (wid >> 1) * 64, wc = (wid & 1) * 64;
  int ar = tid >> 4, ac = (tid & 15) * 4;
  int bh = tid & 127, bk8 = (tid >> 7) * 8;
  const size_t w1base = (size_t)n * DDIM * HDIM + (size_t)ht * 128;
  for (int kt = 0; kt < DDIM / 64; ++kt) {
#pragma unroll
    for (int i = 0; i < 8; ++i) {
      int r = ar + i * 16;
      float4 xv = *(const float4*)(x + (size_t)rows[r] * DDIM + kt * 64 + ac);
      unsigned plo = (unsigned)f2bf(xv.x) | ((unsigned)f2bf(xv.y) << 16);
      unsigned phi = (unsigned)f2bf(xv.z) | ((unsigned)f2bf(xv.w) << 16);
      *(uint2*)(&Al[r * APITCH + ac]) = make_uint2(plo, phi);
    }
#pragma unroll
    for (int i = 0; i < 4; ++i) {
      int k0 = bk8 + i * 16;
      const float* wp = W1 + w1base + (size_t)(kt * 64 + k0) * HDIM + bh;
      uint4 pk;
      pk.x = (unsigned)f2bf(wp[0]) | ((unsigned)f2bf(wp[HDIM]) << 16);
      pk.y = (unsigned)f2bf(wp[2 * HDIM]) | ((unsigned)f2bf(wp[3 * HDIM]) << 16);
      pk.z = (unsigned)f2bf(wp[4 * HDIM]) | ((unsigned)f2bf(wp[5 * HDIM]) << 16);
      pk.w = (unsigned)f2bf(wp[6 * HDIM]) | ((unsigned)f2bf(wp[7 * HDIM]) << 16);
      *(uint4*)(&Bl[bh * APITCH + k0]) = pk;
    }
    __syncthreads();
#pragma unroll
    for (int kk = 0; kk < 2; ++kk) {
      bf16x8 af[4], bfr[4];
#pragma unroll
      for (int mi = 0; mi < 4; ++mi)
        af[mi] = *(const bf16x8*)(&Al[(wr + mi * 16 + (lane & 15)) * APITCH + kk * 32 + (lane >> 4) * 8]);
#pragma unroll
      for (int ni = 0; ni < 4; ++ni)
        bfr[ni] = *(const bf16x8*)(&Bl[(wc + ni * 16 + (lane & 15)) * APITCH + kk * 32 + (lane >> 4) * 8]);
#pragma unroll
      for (int mi = 0; mi < 4; ++mi)
#pragma unroll
        for (int ni = 0; ni < 4; ++ni)
          acc[mi][ni] = __builtin_amdgcn_mfma_f32_16x16x32_bf16(af[mi], bfr[ni], acc[mi][ni], 0, 0, 0);
    }
    __syncthreads();
  }
  int rq = (lane >> 4) * 4;
#pragma unroll
  for (int ni = 0; ni < 4; ++ni) {
    int h = ht * 128 + wc + ni * 16 + (lane & 15);
    float bias = b1[n * HDIM + h];
#pragma unroll
    for (int mi = 0; mi < 4; ++mi) {
#pragma unroll
      for (int q = 0; q < 4; ++q) {
        int lr = wr + mi * 16 + rq + q;
        float val = acc[mi][ni][q] + bias;
        H[((size_t)n * CAP + mt * 128 + lr) * HDIM + h] = f2bf(fast_gelu(val));
      }
    }
  }
}

__global__ __launch_bounds__(256) void ffn2_slow(
    const unsigned short* __restrict__ H, const float* __restrict__ W2, const float* __restrict__ b2,
    const int* __restrict__ m_sel, const int* __restrict__ lists,
    float* __restrict__ out) {
  __shared__ unsigned short Al[128 * APITCH];
  __shared__ unsigned short Bl[128 * APITCH];
  __shared__ int rows[128];
  int n = blockIdx.z, mt = blockIdx.y, dt = blockIdx.x;
  int M = m_sel[n];
  if (mt * 128 >= M) return;
  int tid = threadIdx.x;
  if (tid < 128) {
    int s = mt * 128 + tid;
    rows[tid] = lists[n * CAP + (s < M ? s : 0)];
  }
  __syncthreads();
  f32x4 acc[4][4] = {};
  int lane = tid & 63;
  int wid = tid >> 6;
  int wr = (wid >> 1) * 64, wc = (wid & 1) * 64;
  int ar2 = tid >> 1, ak8 = (tid & 1) * 8;
  int bh = tid & 127, bk8 = (tid >> 7) * 8;
  const size_t hbase = ((size_t)n * CAP + (size_t)mt * 128) * HDIM;
  const size_t w2base = (size_t)n * HDIM * DDIM + (size_t)dt * 128;
  for (int kt = 0; kt < HDIM / 64; ++kt) {
#pragma unroll
    for (int i = 0; i < 4; ++i) {
      int k0 = ak8 + i * 16;
      uint4 hv = *(const uint4*)(H + hbase + (size_t)ar2 * HDIM + kt * 64 + k0);
      *(uint4*)(&Al[ar2 * APITCH + k0]) = hv;
    }
#pragma unroll
    for (int i = 0; i < 4; ++i) {
      int k0 = bk8 + i * 16;
      const float* wp = W2 + w2base + (size_t)(kt * 64 + k0) * DDIM + bh;
      uint4 pk;
      pk.x = (unsigned)f2bf(wp[0]) | ((unsigned)f2bf(wp[DDIM]) << 16);
      pk.y = (unsigned)f2bf(wp[2 * DDIM]) | ((unsigned)f2bf(wp[3 * DDIM]) << 16);
      pk.z = (unsigned)f2bf(wp[4 * DDIM]) | ((unsigned)f2bf(wp[5 * DDIM]) << 16);
      pk.w = (unsigned)f2bf(wp[6 * DDIM]) | ((unsigned)f2bf(wp[7 * DDIM]) << 16);
      *(uint4*)(&Bl[bh * APITCH + k0]) = pk;
    }
    __syncthreads();
#pragma unroll
    for (int kk = 0; kk < 2; ++kk) {
      bf16x8 af[4], bfr[4];
#pragma unroll
      for (int mi = 0; mi < 4; ++mi)
        af[mi] = *(const bf16x8*)(&Al[(wr + mi * 16 + (lane & 15)) * APITCH + kk * 32 + (lane >> 4) * 8]);
#pragma unroll
      for (int ni = 0; ni < 4; ++ni)
        bfr[ni] = *(const bf16x8*)(&Bl[(wc + ni * 16 + (lane & 15)) * APITCH + kk * 32 + (lane >> 4) * 8]);
#pragma unroll
      for (int mi = 0; mi < 4; ++mi)
#pragma unroll
        for (int ni = 0; ni < 4; ++ni)
          acc[mi][ni] = __builtin_amdgcn_mfma_f32_16x16x32_bf16(af[mi], bfr[ni], acc[mi][ni], 0, 0, 0);
    }
    __syncthreads();
  }
  int rq = (lane >> 4) * 4;
#pragma unroll
  for (int mi = 0; mi < 4; ++mi) {
#pragma unroll
    for (int q = 0; q < 4; ++q) {
      int lr = wr + mi * 16 + rq + q;
      int s = mt * 128 + lr;
      if (s < M) {
        int tok = rows[lr];
#pragma unroll
        for (int ni = 0; ni < 4; ++ni) {
          int dcol = dt * 128 + wc + ni * 16 + (lane & 15);
          out[(size_t)tok * DDIM + dcol] = acc[mi][ni][q] + b2[n * DDIM + dcol];
        }
      }
    }
  }
}

// ---------------- passthrough (slow path only) ------------------------------
__global__ __launch_bounds__(256) void passthrough_kernel(
    const float* __restrict__ x, const int* __restrict__ flags,
    float* __restrict__ out) {
  int lane = threadIdx.x & 63;
  int w = threadIdx.x >> 6;
  int base = blockIdx.x * 16;
  for (int r = base + w; r < base + 16; r += 4) {
    if (flags[r]) continue;
    const float4* s = (const float4*)(x + (size_t)r * DDIM);
    float4* d = (float4*)(out + (size_t)r * DDIM);
#pragma unroll
    for (int i = 0; i < 4; ++i) d[lane + i * 64] = s[lane + i * 64];
  }
}

extern "C" void kernel_launch(void* const* d_in, const int* in_sizes, int n_in,
                              void* d_out, int out_size, void* d_ws, size_t ws_size,
                              hipStream_t stream) {
  const float* x  = (const float*)d_in[0];
  const float* Wg = (const float*)d_in[1];
  const float* W1 = (const float*)d_in[2];
  const float* b1 = (const float*)d_in[3];
  const float* W2 = (const float*)d_in[4];
  const float* b2 = (const float*)d_in[5];
  float* out = (float*)d_out;
  char* ws = (char*)d_ws;
  int* counts = (int*)ws;
  int* m_sel  = (int*)(ws + 64);
  int* flags  = (int*)(ws + 128);
  int* e      = (int*)(ws + 128 + 4 * BT);
  float* v    = (float*)(ws + 128 + 8 * BT);
  int* lists  = (int*)(ws + 128 + 12 * BT);

  const size_t MB = 1024 * 1024;
  unsigned short* xb  = (unsigned short*)(ws + 1 * MB);
  unsigned short* w1t = (unsigned short*)(ws + 33 * MB);
  unsigned short* w2t = (unsigned short*)(ws + 97 * MB);
  unsigned short* Hf  = (unsigned short*)(ws + 161 * MB);
  bool fast = ws_size >= 242 * MB;

  hipMemsetAsync(ws, 0, 128, stream);  // counts[16] + m_sel[16]
  if (fast) {
    prep_kernel<<<256 + 8192, 256, 0, stream>>>(x, Wg, e, v, counts, xb, flags, W1, w1t);
    select_kernel<<<NEXP, 1024, 0, stream>>>(e, v, counts, m_sel, lists, flags);
    ffn1_fast<<<4608, 256, 0, stream>>>(xb, w1t, b1, m_sel, lists, Hf, W2, w2t);
    ffn2_fast<<<2304, 256, 0, stream>>>(Hf, w2t, b2, m_sel, lists, out, x, flags);
  } else {
    unsigned short* Hs = (unsigned short*)(ws + 1 * MB);
    gate_kernel<<<BT / 64, 256, 0, stream>>>(x, Wg, e, v, counts, (unsigned short*)nullptr, flags);
    select_kernel<<<NEXP, 1024, 0, stream>>>(e, v, counts, m_sel, lists, flags);
    ffn1_slow<<<dim3(HDIM / 128, CAP / 128, NEXP), 256, 0, stream>>>(x, W1, b1, m_sel, lists, Hs);
    ffn2_slow<<<dim3(DDIM / 128, CAP / 128, NEXP), 256, 0, stream>>>(Hs, W2, b2, m_sel, lists, out);
    passthrough_kernel<<<BT / 16, 256, 0, stream>>>(x, flags, out);
  }
}